// Round 1
// baseline (575.263 us; speedup 1.0000x reference)
//
#include <hip/hip_runtime.h>
#include <math.h>

typedef __bf16 bf16;
typedef __bf16 bf16x8 __attribute__((ext_vector_type(8)));
typedef __bf16 bf16x4 __attribute__((ext_vector_type(4)));
typedef float f32x4 __attribute__((ext_vector_type(4)));
typedef unsigned int u32;

#define S_LEN 2048
#define D_MODEL 512

// async global->LDS, 16B per lane. LDS dest must be wave-uniform base + lane*16.
__device__ __forceinline__ void gload_lds16(const void* g, void* l) {
  __builtin_amdgcn_global_load_lds((const __attribute__((address_space(1))) u32*)g,
                                   (__attribute__((address_space(3))) u32*)l, 16, 0, 0);
}

// ---------------- embedding + sinusoidal PE ----------------
__global__ __launch_bounds__(256) void embed_pe(const int* __restrict__ x,
    const float* __restrict__ emb, float* __restrict__ zf, bf16* __restrict__ zb)
{
  const int row = blockIdx.x;           // b*S + s
  const int s = row & (S_LEN - 1);
  const int tok = x[row];
  const float* e = emb + (size_t)tok * D_MODEL;
  float* zr = zf + (size_t)row * D_MODEL;
  bf16* zbr = zb + (size_t)row * D_MODEL;
  for (int i = threadIdx.x; i < D_MODEL; i += 256) {
    float invf = __expf((float)i * (-9.210340371976184f / 512.0f)); // 10000^(-i/512)
    float ang = (float)s * invf;
    float pe = (i & 1) ? cosf(ang) : sinf(ang);
    float v = e[i] + pe;
    zr[i] = v;
    zbr[i] = (bf16)v;
  }
}

// ---------------- weight fp32 [H][R][C] -> bf16 [H][C][R] ----------------
__global__ __launch_bounds__(256) void conv_t(const float* __restrict__ in,
    bf16* __restrict__ out, int Hn, int R, int C)
{
  int gid = blockIdx.x * 256 + threadIdx.x;
  if (gid >= Hn * R * C) return;
  int r = gid % R;
  int t = gid / R;
  int c = t % C;
  int h = t / C;
  out[gid] = (bf16)in[((size_t)(h * R + r)) * C + c];
}

// ---------------- GEMM: C[M,N] = A[M,K] (bf16) * Bt[N,K]^T (bf16) ----------------
// epilogue: + bias[col] (+ res fp32) (relu) -> outf fp32 and/or outb bf16
__global__ __launch_bounds__(256) void gemm_bt(
    const bf16* __restrict__ A, const bf16* __restrict__ Bt,
    const float* __restrict__ bias, const float* __restrict__ res,
    float* __restrict__ outf, bf16* __restrict__ outb,
    int M, int N, int K, int relu)
{
  __shared__ bf16 As[128 * 32];
  __shared__ bf16 Bs[128 * 32];
  const int tid = threadIdx.x;
  const int wave = tid >> 6, lane = tid & 63, quad = lane >> 4, l16 = lane & 15;
  const int row0 = blockIdx.x * 128, col0 = blockIdx.y * 128;
  const int wm = wave >> 1, wn = wave & 1;   // 2x2 waves of 64x64
  f32x4 acc[4][4] = {};

  for (int kk = 0; kk < K; kk += 32) {
    __syncthreads();   // previous iter's LDS readers done
    #pragma unroll
    for (int r = 0; r < 2; r++) {
      int c = r * 256 + tid;   // 512 chunks of 16B; row=c>>2, 64B/row
      gload_lds16(A + (size_t)(row0 + (c >> 2)) * K + kk + (c & 3) * 8, As + c * 8);
    }
    #pragma unroll
    for (int r = 0; r < 2; r++) {
      int c = r * 256 + tid;
      gload_lds16(Bt + (size_t)(col0 + (c >> 2)) * K + kk + (c & 3) * 8, Bs + c * 8);
    }
    __syncthreads();   // barrier drains vmcnt -> LDS valid
    bf16x8 af[4], bfr[4];
    #pragma unroll
    for (int i = 0; i < 4; i++)
      af[i] = *(const bf16x8*)(As + (wm * 64 + i * 16 + l16) * 32 + quad * 8);
    #pragma unroll
    for (int i = 0; i < 4; i++)
      bfr[i] = *(const bf16x8*)(Bs + (wn * 64 + i * 16 + l16) * 32 + quad * 8);
    #pragma unroll
    for (int mt = 0; mt < 4; mt++)
      #pragma unroll
      for (int nt = 0; nt < 4; nt++)
        acc[mt][nt] = __builtin_amdgcn_mfma_f32_16x16x32_bf16(af[mt], bfr[nt], acc[mt][nt], 0, 0, 0);
  }

  #pragma unroll
  for (int nt = 0; nt < 4; nt++) {
    int col = col0 + wn * 64 + nt * 16 + l16;
    float bv = bias ? bias[col] : 0.f;
    #pragma unroll
    for (int mt = 0; mt < 4; mt++) {
      int rowb = row0 + wm * 64 + mt * 16 + quad * 4;  // C/D: row = quad*4+reg, col = lane&15
      #pragma unroll
      for (int i = 0; i < 4; i++) {
        size_t idx = (size_t)(rowb + i) * N + col;
        float v = acc[mt][nt][i] + bv;
        if (res) v += res[idx];
        if (relu) v = fmaxf(v, 0.f);
        if (outf) outf[idx] = v;
        if (outb) outb[idx] = (bf16)v;
      }
    }
  }
}

// ---------------- flash attention ----------------
// Qh/Kh/Vh layout: [(b*S+s)*512 + h*64 + d], DK=DV=64, full (non-causal) softmax
__global__ __launch_bounds__(256) void flash_attn(
    const bf16* __restrict__ Qh, const bf16* __restrict__ Kh,
    const bf16* __restrict__ Vh, bf16* __restrict__ outc)
{
  __shared__ bf16 Ks[64 * 64];     // [key][dk]
  __shared__ bf16 Vts[64 * 64];    // [dv][key]  (transposed for B-operand)
  __shared__ bf16 Ps[4 * 32 * 64]; // per-wave P round-trip (C-layout -> A-layout)
  const int bh = blockIdx.x;
  const int b = bh >> 3, h = bh & 7;
  const int q0 = blockIdx.y * 128;
  const int tid = threadIdx.x;
  const int wave = tid >> 6, lane = tid & 63, quad = lane >> 4, l16 = lane & 15;

  const bf16* Qb = Qh + ((size_t)b * S_LEN) * D_MODEL + h * 64;
  const bf16* Kb = Kh + ((size_t)b * S_LEN) * D_MODEL + h * 64;
  const bf16* Vb = Vh + ((size_t)b * S_LEN) * D_MODEL + h * 64;

  bf16x8 qf[2][2];  // 2 m-tiles x 2 k-halves; A[m=lane&15][k=quad*8+j]
  #pragma unroll
  for (int mt = 0; mt < 2; mt++) {
    int qr = q0 + wave * 32 + mt * 16 + l16;
    #pragma unroll
    for (int kh = 0; kh < 2; kh++)
      qf[mt][kh] = *(const bf16x8*)(Qb + (size_t)qr * D_MODEL + kh * 32 + quad * 8);
  }

  f32x4 O[2][4] = {};
  float mrow[2][4], lrow[2][4];
  #pragma unroll
  for (int mt = 0; mt < 2; mt++)
    for (int i = 0; i < 4; i++) { mrow[mt][i] = -3.0e38f; lrow[mt][i] = 0.f; }

  for (int kc = 0; kc < S_LEN; kc += 64) {
    #pragma unroll
    for (int r = 0; r < 2; r++) {       // K chunk: 64 rows x 128B
      int c = r * 256 + tid;
      gload_lds16(Kb + (size_t)(kc + (c >> 3)) * D_MODEL + (c & 7) * 8, Ks + c * 8);
    }
    {   // V^T staging (per-thread transpose)
      int key = tid & 63, dvb = (tid >> 6) * 16;
      const bf16* vp = Vb + (size_t)(kc + key) * D_MODEL + dvb;
      bf16x8 v0 = *(const bf16x8*)vp;
      bf16x8 v1 = *(const bf16x8*)(vp + 8);
      #pragma unroll
      for (int i = 0; i < 8; i++) {
        Vts[(dvb + i) * 64 + key] = v0[i];
        Vts[(dvb + 8 + i) * 64 + key] = v1[i];
      }
    }
    __syncthreads();

    // S = Q K^T
    bf16x8 kf[4][2];
    #pragma unroll
    for (int nt = 0; nt < 4; nt++)
      #pragma unroll
      for (int kh = 0; kh < 2; kh++)
        kf[nt][kh] = *(const bf16x8*)(Ks + (nt * 16 + l16) * 64 + kh * 32 + quad * 8);

    f32x4 sc[2][4];
    #pragma unroll
    for (int mt = 0; mt < 2; mt++)
      #pragma unroll
      for (int nt = 0; nt < 4; nt++) {
        f32x4 a = {};
        a = __builtin_amdgcn_mfma_f32_16x16x32_bf16(qf[mt][0], kf[nt][0], a, 0, 0, 0);
        a = __builtin_amdgcn_mfma_f32_16x16x32_bf16(qf[mt][1], kf[nt][1], a, 0, 0, 0);
        sc[mt][nt] = a;
      }

    // online softmax (row = quad*4+i, col = lane&15 within each 16x16 tile)
    #pragma unroll
    for (int mt = 0; mt < 2; mt++) {
      float alpha[4], rsum[4];
      #pragma unroll
      for (int nt = 0; nt < 4; nt++)
        #pragma unroll
        for (int i = 0; i < 4; i++) sc[mt][nt][i] *= 0.125f;  // 1/sqrt(64)
      #pragma unroll
      for (int i = 0; i < 4; i++) {
        float m = fmaxf(fmaxf(sc[mt][0][i], sc[mt][1][i]), fmaxf(sc[mt][2][i], sc[mt][3][i]));
        #pragma unroll
        for (int msk = 1; msk < 16; msk <<= 1) m = fmaxf(m, __shfl_xor(m, msk, 64));
        float mn = fmaxf(mrow[mt][i], m);
        alpha[i] = __expf(mrow[mt][i] - mn);
        mrow[mt][i] = mn;
        rsum[i] = 0.f;
      }
      #pragma unroll
      for (int nt = 0; nt < 4; nt++)
        #pragma unroll
        for (int i = 0; i < 4; i++) {
          float p = __expf(sc[mt][nt][i] - mrow[mt][i]);
          Ps[wave * 2048 + (mt * 16 + quad * 4 + i) * 64 + nt * 16 + l16] = (bf16)p;
          rsum[i] += p;
        }
      #pragma unroll
      for (int i = 0; i < 4; i++) {
        float r = rsum[i];
        #pragma unroll
        for (int msk = 1; msk < 16; msk <<= 1) r += __shfl_xor(r, msk, 64);
        lrow[mt][i] = lrow[mt][i] * alpha[i] + r;
      }
      #pragma unroll
      for (int nv = 0; nv < 4; nv++)
        #pragma unroll
        for (int i = 0; i < 4; i++) O[mt][nv][i] *= alpha[i];
    }

    asm volatile("s_waitcnt lgkmcnt(0)" ::: "memory");  // P writes visible to own wave

    // O += P V
    #pragma unroll
    for (int kh2 = 0; kh2 < 2; kh2++) {
      bf16x8 vf[4];
      #pragma unroll
      for (int nv = 0; nv < 4; nv++)
        vf[nv] = *(const bf16x8*)(Vts + (nv * 16 + l16) * 64 + kh2 * 32 + quad * 8);
      #pragma unroll
      for (int mt = 0; mt < 2; mt++) {
        bf16x8 pf = *(const bf16x8*)(Ps + wave * 2048 + (mt * 16 + l16) * 64 + kh2 * 32 + quad * 8);
        #pragma unroll
        for (int nv = 0; nv < 4; nv++)
          O[mt][nv] = __builtin_amdgcn_mfma_f32_16x16x32_bf16(pf, vf[nv], O[mt][nv], 0, 0, 0);
      }
    }
    __syncthreads();
  }

  // normalize + store concat layout [b,s, h*64+dv]
  #pragma unroll
  for (int mt = 0; mt < 2; mt++) {
    float invl[4];
    #pragma unroll
    for (int i = 0; i < 4; i++) invl[i] = 1.f / lrow[mt][i];
    #pragma unroll
    for (int nv = 0; nv < 4; nv++)
      #pragma unroll
      for (int i = 0; i < 4; i++) {
        int row = b * S_LEN + q0 + wave * 32 + mt * 16 + quad * 4 + i;
        int col = h * 64 + nv * 16 + l16;
        outc[(size_t)row * D_MODEL + col] = (bf16)(O[mt][nv][i] * invl[i]);
      }
  }
}

// ---------------- LayerNorm (wave per row, D=512) ----------------
__global__ __launch_bounds__(256) void ln_kernel(const float* __restrict__ in,
    const float* __restrict__ gamma, const float* __restrict__ beta,
    float* __restrict__ outf, bf16* __restrict__ outb, int relu)
{
  const int row = blockIdx.x * 4 + (threadIdx.x >> 6);
  const int lane = threadIdx.x & 63;
  const float4* p = (const float4*)(in + (size_t)row * 512);
  float4 v0 = p[lane];
  float4 v1 = p[lane + 64];
  float s = v0.x + v0.y + v0.z + v0.w + v1.x + v1.y + v1.z + v1.w;
  #pragma unroll
  for (int m = 1; m < 64; m <<= 1) s += __shfl_xor(s, m, 64);
  float mu = s * (1.f / 512.f);
  float d0 = v0.x - mu, d1 = v0.y - mu, d2 = v0.z - mu, d3 = v0.w - mu;
  float d4 = v1.x - mu, d5 = v1.y - mu, d6 = v1.z - mu, d7 = v1.w - mu;
  float q = d0*d0 + d1*d1 + d2*d2 + d3*d3 + d4*d4 + d5*d5 + d6*d6 + d7*d7;
  #pragma unroll
  for (int m = 1; m < 64; m <<= 1) q += __shfl_xor(q, m, 64);
  float rs = rsqrtf(q * (1.f / 512.f) + 1e-5f);
  const float4* gp = (const float4*)gamma;
  const float4* bp = (const float4*)beta;
  float4 g0 = gp[lane], g1 = gp[lane + 64];
  float4 b0 = bp[lane], b1 = bp[lane + 64];
  float y0 = d0 * rs * g0.x + b0.x, y1 = d1 * rs * g0.y + b0.y;
  float y2 = d2 * rs * g0.z + b0.z, y3 = d3 * rs * g0.w + b0.w;
  float y4 = d4 * rs * g1.x + b1.x, y5 = d5 * rs * g1.y + b1.y;
  float y6 = d6 * rs * g1.z + b1.z, y7 = d7 * rs * g1.w + b1.w;
  if (relu) {
    y0 = fmaxf(y0, 0.f); y1 = fmaxf(y1, 0.f); y2 = fmaxf(y2, 0.f); y3 = fmaxf(y3, 0.f);
    y4 = fmaxf(y4, 0.f); y5 = fmaxf(y5, 0.f); y6 = fmaxf(y6, 0.f); y7 = fmaxf(y7, 0.f);
  }
  float4* op = (float4*)(outf + (size_t)row * 512);
  float4 o0 = {y0, y1, y2, y3}, o1 = {y4, y5, y6, y7};
  op[lane] = o0;
  op[lane + 64] = o1;
  if (outb) {
    bf16x4 c0 = {(bf16)y0, (bf16)y1, (bf16)y2, (bf16)y3};
    bf16x4 c1 = {(bf16)y4, (bf16)y5, (bf16)y6, (bf16)y7};
    *(bf16x4*)(outb + (size_t)row * 512 + lane * 4) = c0;
    *(bf16x4*)(outb + (size_t)row * 512 + 256 + lane * 4) = c1;
  }
}

extern "C" void kernel_launch(void* const* d_in, const int* in_sizes, int n_in,
                              void* d_out, int out_size, void* d_ws, size_t ws_size,
                              hipStream_t stream)
{
  const int*   x    = (const int*)  d_in[0];
  const float* emb  = (const float*)d_in[1];
  const float* WfQ  = (const float*)d_in[2];
  const float* bfQv = (const float*)d_in[3];
  const float* WfK  = (const float*)d_in[4];
  const float* bfKv = (const float*)d_in[5];
  const float* WfV  = (const float*)d_in[6];
  const float* bfVv = (const float*)d_in[7];
  const float* WQ   = (const float*)d_in[8];
  const float* bQ   = (const float*)d_in[9];
  const float* WK   = (const float*)d_in[10];
  const float* bK   = (const float*)d_in[11];
  const float* WV   = (const float*)d_in[12];
  const float* bV   = (const float*)d_in[13];
  const float* Wo   = (const float*)d_in[14];
  const float* bo   = (const float*)d_in[15];
  const float* W1   = (const float*)d_in[16];
  const float* b1   = (const float*)d_in[17];
  const float* W2   = (const float*)d_in[18];
  const float* b2   = (const float*)d_in[19];
  const float* gamma= (const float*)d_in[20];
  const float* beta = (const float*)d_in[21];
  float* out = (float*)d_out;

  char* ws = (char*)d_ws;
  const size_t SZF = 8192ull * 512 * 4;   // 16 MiB fp32 activation
  const size_t SZB = 8192ull * 512 * 2;   // 8 MiB bf16 activation
  float* zf   = (float*)(ws);             // z, later a (fp32)
  float* resf = (float*)(ws + SZF);       // attn_out+z, later ffn2+a
  bf16* bz  = (bf16*)(ws + 2 * SZF);      // z bf16, later a bf16
  bf16* bQb = (bf16*)(ws + 2 * SZF + 1 * SZB);  // Q, later concat
  bf16* bKb = (bf16*)(ws + 2 * SZF + 2 * SZB);  // K; ffn1 spans bKb..bKh (32 MiB)
  bf16* bVb = (bf16*)(ws + 2 * SZF + 3 * SZB);  // V
  bf16* bQh = (bf16*)(ws + 2 * SZF + 4 * SZB);
  bf16* bKh = (bf16*)(ws + 2 * SZF + 5 * SZB);
  bf16* bVh = (bf16*)(ws + 2 * SZF + 6 * SZB);
  bf16* ffn1 = bKb;
  char* wp = ws + 2 * SZF + 7 * SZB;
  const size_t W512 = 512ull * 512 * 2;
  bf16* wfqt = (bf16*)(wp);
  bf16* wfkt = (bf16*)(wp + 1 * W512);
  bf16* wfvt = (bf16*)(wp + 2 * W512);
  bf16* wqt  = (bf16*)(wp + 3 * W512);
  bf16* wkt  = (bf16*)(wp + 4 * W512);
  bf16* wvt  = (bf16*)(wp + 5 * W512);
  bf16* wot  = (bf16*)(wp + 6 * W512);
  bf16* w1t  = (bf16*)(wp + 7 * W512);
  bf16* w2t  = (bf16*)(wp + 7 * W512 + 2097152);

  conv_t<<<1024, 256, 0, stream>>>(WfQ, wfqt, 1, 512, 512);
  conv_t<<<1024, 256, 0, stream>>>(WfK, wfkt, 1, 512, 512);
  conv_t<<<1024, 256, 0, stream>>>(WfV, wfvt, 1, 512, 512);
  conv_t<<<1024, 256, 0, stream>>>(WQ,  wqt,  8, 512, 64);
  conv_t<<<1024, 256, 0, stream>>>(WK,  wkt,  8, 512, 64);
  conv_t<<<1024, 256, 0, stream>>>(WV,  wvt,  8, 512, 64);
  conv_t<<<1024, 256, 0, stream>>>(Wo,  wot,  1, 512, 512);
  conv_t<<<4096, 256, 0, stream>>>(W1,  w1t,  1, 512, 2048);
  conv_t<<<4096, 256, 0, stream>>>(W2,  w2t,  1, 2048, 512);

  embed_pe<<<8192, 256, 0, stream>>>(x, emb, zf, bz);

  dim3 g512(64, 4), g2048(64, 16);
  gemm_bt<<<g512, 256, 0, stream>>>(bz,  wfqt, bfQv, nullptr, nullptr, bQb, 8192, 512, 512, 0);
  gemm_bt<<<g512, 256, 0, stream>>>(bz,  wfkt, bfKv, nullptr, nullptr, bKb, 8192, 512, 512, 0);
  gemm_bt<<<g512, 256, 0, stream>>>(bz,  wfvt, bfVv, nullptr, nullptr, bVb, 8192, 512, 512, 0);
  gemm_bt<<<g512, 256, 0, stream>>>(bQb, wqt,  bQ,   nullptr, nullptr, bQh, 8192, 512, 512, 0);
  gemm_bt<<<g512, 256, 0, stream>>>(bKb, wkt,  bK,   nullptr, nullptr, bKh, 8192, 512, 512, 0);
  gemm_bt<<<g512, 256, 0, stream>>>(bVb, wvt,  bV,   nullptr, nullptr, bVh, 8192, 512, 512, 0);

  flash_attn<<<dim3(32, 16), 256, 0, stream>>>(bQh, bKh, bVh, bQb);

  gemm_bt<<<g512, 256, 0, stream>>>(bQb, wot, bo, zf, resf, nullptr, 8192, 512, 512, 0);
  ln_kernel<<<2048, 256, 0, stream>>>(resf, gamma, beta, zf, bz, 0);
  gemm_bt<<<g2048, 256, 0, stream>>>(bz, w1t, b1, nullptr, nullptr, ffn1, 8192, 2048, 512, 1);
  gemm_bt<<<g512, 256, 0, stream>>>(ffn1, w2t, b2, zf, resf, nullptr, 8192, 512, 2048, 0);
  ln_kernel<<<2048, 256, 0, stream>>>(resf, gamma, beta, out, nullptr, 1);
}

// Round 2
// 459.678 us; speedup vs baseline: 1.2514x; 1.2514x over previous
//
#include <hip/hip_runtime.h>
#include <math.h>

typedef __bf16 bf16;
typedef __bf16 bf16x8 __attribute__((ext_vector_type(8)));
typedef __bf16 bf16x4 __attribute__((ext_vector_type(4)));
typedef _Float16 f16;
typedef _Float16 f16x8 __attribute__((ext_vector_type(8)));
typedef _Float16 f16x4 __attribute__((ext_vector_type(4)));
typedef float f32x4 __attribute__((ext_vector_type(4)));
typedef unsigned int u32;

#define S_LEN 2048
#define QKV_N 1536
// 0.125 (1/sqrt(DK)) * log2(e), folded into combined Q weights+bias so softmax uses exp2
#define QSCALE 0.18033688011112042f

__device__ __forceinline__ void gload_lds16(const void* g, void* l) {
  __builtin_amdgcn_global_load_lds((const __attribute__((address_space(1))) u32*)g,
                                   (__attribute__((address_space(3))) u32*)l, 16, 0, 0);
}

// ---------------- embedding + sinusoidal PE ----------------
__global__ __launch_bounds__(256) void embed_pe(const int* __restrict__ x,
    const float* __restrict__ emb, float* __restrict__ zf, bf16* __restrict__ zb)
{
  const int row = blockIdx.x;
  const int s = row & (S_LEN - 1);
  const int tok = x[row];
  const float* e = emb + (size_t)tok * 512;
  float* zr = zf + (size_t)row * 512;
  bf16* zbr = zb + (size_t)row * 512;
  for (int i = threadIdx.x; i < 512; i += 256) {
    float invf = __expf((float)i * (-9.210340371976184f / 512.0f));
    float ang = (float)s * invf;
    float pe = (i & 1) ? __cosf(ang) : __sinf(ang);
    float v = e[i] + pe;
    zr[i] = v;
    zbr[i] = (bf16)v;
  }
}

// ---------------- fp32 -> bf16 plain convert (3 tensors) ----------------
__global__ __launch_bounds__(256) void conv_plain3(const float* __restrict__ i0,
    const float* __restrict__ i1, const float* __restrict__ i2,
    bf16* __restrict__ o0, bf16* __restrict__ o1, bf16* __restrict__ o2)
{
  int gid = blockIdx.x * 256 + threadIdx.x;
  const float* in = blockIdx.y == 0 ? i0 : (blockIdx.y == 1 ? i1 : i2);
  bf16* out = blockIdx.y == 0 ? o0 : (blockIdx.y == 1 ? o1 : o2);
  out[gid] = (bf16)in[gid];
}

// ---------------- fp32 [H][R][C] -> bf16 [H][C][R] (transpose, x scale) ----------------
__global__ __launch_bounds__(256) void conv_t(const float* __restrict__ in,
    bf16* __restrict__ out, int Hn, int R, int C, float scale)
{
  int gid = blockIdx.x * 256 + threadIdx.x;
  if (gid >= Hn * R * C) return;
  int r = gid % R;
  int t = gid / R;
  int c = t % C;
  int h = t / C;
  out[gid] = (bf16)(in[((size_t)(h * R + r)) * C + c] * scale);
}

// heads version: 3 tensors of [8][512][64], Q scaled by QSCALE
__global__ __launch_bounds__(256) void conv_t_heads(const float* __restrict__ i0,
    const float* __restrict__ i1, const float* __restrict__ i2,
    bf16* __restrict__ o0, bf16* __restrict__ o1, bf16* __restrict__ o2)
{
  int gid = blockIdx.x * 256 + threadIdx.x;
  const float* in = blockIdx.y == 0 ? i0 : (blockIdx.y == 1 ? i1 : i2);
  bf16* out = blockIdx.y == 0 ? o0 : (blockIdx.y == 1 ? o1 : o2);
  float scale = blockIdx.y == 0 ? QSCALE : 1.0f;
  int r = gid & 511;           // R=512
  int t = gid >> 9;
  int c = t & 63;              // C=64
  int h = t >> 6;
  out[gid] = (bf16)(in[((size_t)(h * 512 + r)) * 64 + c] * scale);
}

// ---------------- combined bias: bc[n] = s*(sum_e bf[e]*W[h,e,k] + bHead[h,k]) ----------------
__global__ __launch_bounds__(256) void bias_comb(
    const float* __restrict__ bfQ, const float* __restrict__ bfK, const float* __restrict__ bfV,
    const float* __restrict__ WQ, const float* __restrict__ WK, const float* __restrict__ WV,
    const float* __restrict__ bQ, const float* __restrict__ bK, const float* __restrict__ bV,
    float* __restrict__ bc)
{
  int n = blockIdx.x * 4 + (threadIdx.x >> 6);   // 0..1535
  int lane = threadIdx.x & 63;
  int z = n >> 9, hk = n & 511, h = hk >> 6, k = hk & 63;
  const float* bf = z == 0 ? bfQ : (z == 1 ? bfK : bfV);
  const float* W  = z == 0 ? WQ  : (z == 1 ? WK  : WV);
  const float* bH = z == 0 ? bQ  : (z == 1 ? bK  : bV);
  float s = 0.f;
  for (int e = lane; e < 512; e += 64)
    s += bf[e] * W[((size_t)h * 512 + e) * 64 + k];
  #pragma unroll
  for (int m = 1; m < 64; m <<= 1) s += __shfl_xor(s, m, 64);
  if (lane == 0) {
    float v = s + bH[h * 64 + k];
    if (z == 0) v *= QSCALE;
    bc[n] = v;
  }
}

// ---------------- GEMM 128x128 tile: C[M,N] = A[M,K](bf16) * Bt[N,K]^T(bf16) ----------------
__global__ __launch_bounds__(256) void gemm_bt(
    const bf16* __restrict__ A, const bf16* __restrict__ Bt,
    const float* __restrict__ bias, const float* __restrict__ res,
    float* __restrict__ outf, bf16* __restrict__ outb, f16* __restrict__ outh,
    int M, int N, int K, int relu)
{
  __shared__ bf16 As[128 * 32];
  __shared__ bf16 Bs[128 * 32];
  const int tid = threadIdx.x;
  const int wave = tid >> 6, lane = tid & 63, quad = lane >> 4, l16 = lane & 15;
  const int row0 = blockIdx.x * 128, col0 = blockIdx.y * 128;
  const int wm = wave >> 1, wn = wave & 1;
  f32x4 acc[4][4] = {};

  for (int kk = 0; kk < K; kk += 32) {
    __syncthreads();
    #pragma unroll
    for (int r = 0; r < 2; r++) {
      int c = r * 256 + tid;
      gload_lds16(A + (size_t)(row0 + (c >> 2)) * K + kk + (c & 3) * 8, As + c * 8);
    }
    #pragma unroll
    for (int r = 0; r < 2; r++) {
      int c = r * 256 + tid;
      gload_lds16(Bt + (size_t)(col0 + (c >> 2)) * K + kk + (c & 3) * 8, Bs + c * 8);
    }
    __syncthreads();
    bf16x8 af[4], bfr[4];
    #pragma unroll
    for (int i = 0; i < 4; i++)
      af[i] = *(const bf16x8*)(As + (wm * 64 + i * 16 + l16) * 32 + quad * 8);
    #pragma unroll
    for (int i = 0; i < 4; i++)
      bfr[i] = *(const bf16x8*)(Bs + (wn * 64 + i * 16 + l16) * 32 + quad * 8);
    #pragma unroll
    for (int mt = 0; mt < 4; mt++)
      #pragma unroll
      for (int nt = 0; nt < 4; nt++)
        acc[mt][nt] = __builtin_amdgcn_mfma_f32_16x16x32_bf16(af[mt], bfr[nt], acc[mt][nt], 0, 0, 0);
  }

  #pragma unroll
  for (int nt = 0; nt < 4; nt++) {
    int col = col0 + wn * 64 + nt * 16 + l16;
    float bv = bias ? bias[col] : 0.f;
    #pragma unroll
    for (int mt = 0; mt < 4; mt++) {
      int rowb = row0 + wm * 64 + mt * 16 + quad * 4;
      #pragma unroll
      for (int i = 0; i < 4; i++) {
        size_t idx = (size_t)(rowb + i) * N + col;
        float v = acc[mt][nt][i] + bv;
        if (res) v += res[idx];
        if (relu) v = fmaxf(v, 0.f);
        if (outf) outf[idx] = v;
        if (outb) outb[idx] = (bf16)v;
        if (outh) outh[idx] = (f16)v;
      }
    }
  }
}

// ---------------- GEMM 128x64 tile (for N=512 shapes: 512 blocks = 2/CU) ----------------
__global__ __launch_bounds__(256) void gemm_bt64(
    const bf16* __restrict__ A, const bf16* __restrict__ Bt,
    const float* __restrict__ bias, const float* __restrict__ res,
    float* __restrict__ outf, bf16* __restrict__ outb,
    int M, int N, int K, int relu)
{
  __shared__ bf16 As[128 * 32];
  __shared__ bf16 Bs[64 * 32];
  const int tid = threadIdx.x;
  const int wave = tid >> 6, lane = tid & 63, quad = lane >> 4, l16 = lane & 15;
  const int row0 = blockIdx.x * 128, col0 = blockIdx.y * 64;
  const int wm = wave >> 1, wn = wave & 1;   // 2x2 waves: 64 rows x 32 cols each
  f32x4 acc[4][2] = {};

  for (int kk = 0; kk < K; kk += 32) {
    __syncthreads();
    #pragma unroll
    for (int r = 0; r < 2; r++) {
      int c = r * 256 + tid;
      gload_lds16(A + (size_t)(row0 + (c >> 2)) * K + kk + (c & 3) * 8, As + c * 8);
    }
    {
      int c = tid;
      gload_lds16(Bt + (size_t)(col0 + (c >> 2)) * K + kk + (c & 3) * 8, Bs + c * 8);
    }
    __syncthreads();
    bf16x8 af[4], bfr[2];
    #pragma unroll
    for (int i = 0; i < 4; i++)
      af[i] = *(const bf16x8*)(As + (wm * 64 + i * 16 + l16) * 32 + quad * 8);
    #pragma unroll
    for (int i = 0; i < 2; i++)
      bfr[i] = *(const bf16x8*)(Bs + (wn * 32 + i * 16 + l16) * 32 + quad * 8);
    #pragma unroll
    for (int mt = 0; mt < 4; mt++)
      #pragma unroll
      for (int nt = 0; nt < 2; nt++)
        acc[mt][nt] = __builtin_amdgcn_mfma_f32_16x16x32_bf16(af[mt], bfr[nt], acc[mt][nt], 0, 0, 0);
  }

  #pragma unroll
  for (int nt = 0; nt < 2; nt++) {
    int col = col0 + wn * 32 + nt * 16 + l16;
    float bv = bias ? bias[col] : 0.f;
    #pragma unroll
    for (int mt = 0; mt < 4; mt++) {
      int rowb = row0 + wm * 64 + mt * 16 + quad * 4;
      #pragma unroll
      for (int i = 0; i < 4; i++) {
        size_t idx = (size_t)(rowb + i) * N + col;
        float v = acc[mt][nt][i] + bv;
        if (res) v += res[idx];
        if (relu) v = fmaxf(v, 0.f);
        if (outf) outf[idx] = v;
        if (outb) outb[idx] = (bf16)v;
      }
    }
  }
}

// ---------------- flash attention, transposed (S^T = K Q^T) ----------------
// qkv: [b*S+s][1536] f16, cols 0..511=Qh (pre-scaled by QSCALE), 512..1023=Kh, 1024..1535=Vh
// wave handles 16 queries; block = 4 waves = 64 q. Grid (qtile=32, bh=32).
__global__ __launch_bounds__(256) void flash_attn(
    const f16* __restrict__ qkv, bf16* __restrict__ outc)
{
  __shared__ f16 Ks[64 * 72];    // [key][dk], padded 72 -> 2-way bank alias (free)
  __shared__ f16 Vts[64 * 72];   // [dv][key], padded
  const int bh = blockIdx.y;
  const int b = bh >> 3, h = bh & 7;
  const int q0 = blockIdx.x * 64;
  const int tid = threadIdx.x;
  const int wave = tid >> 6, lane = tid & 63, quad = lane >> 4, l16 = lane & 15;

  const f16* Qb = qkv + (size_t)b * S_LEN * QKV_N + h * 64;
  const f16* Kb = Qb + 512;
  const f16* Vb = Qb + 1024;

  // Q fragment: B-operand of S^T matmul. B[n=q=l16][k=dk=quad*8+j (+32*kh)]
  const int qrow = q0 + wave * 16 + l16;
  f16x8 qf[2];
  #pragma unroll
  for (int kh = 0; kh < 2; kh++)
    qf[kh] = *(const f16x8*)(Qb + (size_t)qrow * QKV_N + kh * 32 + quad * 8);

  f32x4 O[4] = {};          // O^T: row=dv=mt*16+quad*4+reg, col=q=l16
  float mrow = -1e30f, lrow = 0.f;   // per-lane scalars (col=q fixed per lane)

  for (int kc = 0; kc < S_LEN; kc += 64) {
    // stage K chunk [64 keys][64 dk] with row pad 72
    #pragma unroll
    for (int r = 0; r < 2; r++) {
      int c = r * 256 + tid;
      int krow = c >> 3, koff = (c & 7) * 8;
      *(f16x8*)(Ks + krow * 72 + koff) =
          *(const f16x8*)(Kb + (size_t)(kc + krow) * QKV_N + koff);
    }
    // stage V^T [dv][key]
    {
      int key = tid & 63, dvb = (tid >> 6) * 16;
      const f16* vp = Vb + (size_t)(kc + key) * QKV_N + dvb;
      f16x8 v0 = *(const f16x8*)vp;
      f16x8 v1 = *(const f16x8*)(vp + 8);
      #pragma unroll
      for (int i = 0; i < 8; i++) {
        Vts[(dvb + i) * 72 + key] = v0[i];
        Vts[(dvb + 8 + i) * 72 + key] = v1[i];
      }
    }
    __syncthreads();

    // S^T = K * Q^T : A[m=key][k=dk] from Ks, tile nt covers keys nt*16..
    f32x4 sc[4];
    #pragma unroll
    for (int nt = 0; nt < 4; nt++) {
      f16x8 kf0 = *(const f16x8*)(Ks + (nt * 16 + l16) * 72 + quad * 8);
      f16x8 kf1 = *(const f16x8*)(Ks + (nt * 16 + l16) * 72 + 32 + quad * 8);
      f32x4 a = {};
      a = __builtin_amdgcn_mfma_f32_16x16x32_f16(kf0, qf[0], a, 0, 0, 0);
      a = __builtin_amdgcn_mfma_f32_16x16x32_f16(kf1, qf[1], a, 0, 0, 0);
      sc[nt] = a;
    }

    // online softmax in exp2 domain (scores pre-scaled by 0.125*log2e)
    float m = sc[0][0];
    #pragma unroll
    for (int nt = 0; nt < 4; nt++)
      #pragma unroll
      for (int i = 0; i < 4; i++) m = fmaxf(m, sc[nt][i]);
    m = fmaxf(m, __shfl_xor(m, 16, 64));
    m = fmaxf(m, __shfl_xor(m, 32, 64));
    float mn = fmaxf(mrow, m);
    float alpha = exp2f(mrow - mn);
    mrow = mn;
    float rsum = 0.f;
    f16x4 pf[4];   // P^T B-frag for 16x16x16: B[k=key=quad*4+j][n=q=l16]
    #pragma unroll
    for (int nt = 0; nt < 4; nt++)
      #pragma unroll
      for (int i = 0; i < 4; i++) {
        float p = exp2f(sc[nt][i] - mn);
        rsum += p;
        pf[nt][i] = (f16)p;
      }
    rsum += __shfl_xor(rsum, 16, 64);
    rsum += __shfl_xor(rsum, 32, 64);
    lrow = lrow * alpha + rsum;
    #pragma unroll
    for (int mt = 0; mt < 4; mt++)
      #pragma unroll
      for (int i = 0; i < 4; i++) O[mt][i] *= alpha;

    // O^T += V^T * P^T  (16x16x16 f16: A 4 halves, B 4 halves)
    #pragma unroll
    for (int nt = 0; nt < 4; nt++)
      #pragma unroll
      for (int mt = 0; mt < 4; mt++) {
        f16x4 vf = *(const f16x4*)(Vts + (mt * 16 + l16) * 72 + nt * 16 + quad * 4);
        O[mt] = __builtin_amdgcn_mfma_f32_16x16x16f16(vf, pf[nt], O[mt], 0, 0, 0);
      }
    __syncthreads();
  }

  // epilogue: normalize, transpose via LDS (per-wave region), coalesced store
  float invl = 1.f / lrow;
  bf16* ob = (bf16*)Ks + wave * 1024;   // [16 q][64 dv]
  #pragma unroll
  for (int mt = 0; mt < 4; mt++)
    #pragma unroll
    for (int i = 0; i < 4; i++)
      ob[l16 * 64 + mt * 16 + quad * 4 + i] = (bf16)(O[mt][i] * invl);
  asm volatile("s_waitcnt lgkmcnt(0)" ::: "memory");
  int row = lane >> 2, dvb = (lane & 3) * 16;
  bf16x8 o0 = *(const bf16x8*)(ob + row * 64 + dvb);
  bf16x8 o1 = *(const bf16x8*)(ob + row * 64 + dvb + 8);
  size_t g = ((size_t)b * S_LEN + q0 + wave * 16 + row) * 512 + h * 64 + dvb;
  *(bf16x8*)(outc + g) = o0;
  *(bf16x8*)(outc + g + 8) = o1;
}

// ---------------- LayerNorm (wave per row, D=512) ----------------
__global__ __launch_bounds__(256) void ln_kernel(const float* __restrict__ in,
    const float* __restrict__ gamma, const float* __restrict__ beta,
    float* __restrict__ outf, bf16* __restrict__ outb, int relu)
{
  const int row = blockIdx.x * 4 + (threadIdx.x >> 6);
  const int lane = threadIdx.x & 63;
  const float4* p = (const float4*)(in + (size_t)row * 512);
  float4 v0 = p[lane];
  float4 v1 = p[lane + 64];
  float s = v0.x + v0.y + v0.z + v0.w + v1.x + v1.y + v1.z + v1.w;
  #pragma unroll
  for (int m = 1; m < 64; m <<= 1) s += __shfl_xor(s, m, 64);
  float mu = s * (1.f / 512.f);
  float d0 = v0.x - mu, d1 = v0.y - mu, d2 = v0.z - mu, d3 = v0.w - mu;
  float d4 = v1.x - mu, d5 = v1.y - mu, d6 = v1.z - mu, d7 = v1.w - mu;
  float q = d0*d0 + d1*d1 + d2*d2 + d3*d3 + d4*d4 + d5*d5 + d6*d6 + d7*d7;
  #pragma unroll
  for (int m = 1; m < 64; m <<= 1) q += __shfl_xor(q, m, 64);
  float rs = rsqrtf(q * (1.f / 512.f) + 1e-5f);
  const float4* gp = (const float4*)gamma;
  const float4* bp = (const float4*)beta;
  float4 g0 = gp[lane], g1 = gp[lane + 64];
  float4 b0 = bp[lane], b1 = bp[lane + 64];
  float y0 = d0 * rs * g0.x + b0.x, y1 = d1 * rs * g0.y + b0.y;
  float y2 = d2 * rs * g0.z + b0.z, y3 = d3 * rs * g0.w + b0.w;
  float y4 = d4 * rs * g1.x + b1.x, y5 = d5 * rs * g1.y + b1.y;
  float y6 = d6 * rs * g1.z + b1.z, y7 = d7 * rs * g1.w + b1.w;
  if (relu) {
    y0 = fmaxf(y0, 0.f); y1 = fmaxf(y1, 0.f); y2 = fmaxf(y2, 0.f); y3 = fmaxf(y3, 0.f);
    y4 = fmaxf(y4, 0.f); y5 = fmaxf(y5, 0.f); y6 = fmaxf(y6, 0.f); y7 = fmaxf(y7, 0.f);
  }
  float4* op = (float4*)(outf + (size_t)row * 512);
  float4 o0 = {y0, y1, y2, y3}, o1 = {y4, y5, y6, y7};
  op[lane] = o0;
  op[lane + 64] = o1;
  if (outb) {
    bf16x4 c0 = {(bf16)y0, (bf16)y1, (bf16)y2, (bf16)y3};
    bf16x4 c1 = {(bf16)y4, (bf16)y5, (bf16)y6, (bf16)y7};
    *(bf16x4*)(outb + (size_t)row * 512 + lane * 4) = c0;
    *(bf16x4*)(outb + (size_t)row * 512 + 256 + lane * 4) = c1;
  }
}

extern "C" void kernel_launch(void* const* d_in, const int* in_sizes, int n_in,
                              void* d_out, int out_size, void* d_ws, size_t ws_size,
                              hipStream_t stream)
{
  const int*   x    = (const int*)  d_in[0];
  const float* emb  = (const float*)d_in[1];
  const float* WfQ  = (const float*)d_in[2];
  const float* bfQv = (const float*)d_in[3];
  const float* WfK  = (const float*)d_in[4];
  const float* bfKv = (const float*)d_in[5];
  const float* WfV  = (const float*)d_in[6];
  const float* bfVv = (const float*)d_in[7];
  const float* WQ   = (const float*)d_in[8];
  const float* bQ   = (const float*)d_in[9];
  const float* WK   = (const float*)d_in[10];
  const float* bK   = (const float*)d_in[11];
  const float* WV   = (const float*)d_in[12];
  const float* bV   = (const float*)d_in[13];
  const float* Wo   = (const float*)d_in[14];
  const float* bo   = (const float*)d_in[15];
  const float* W1   = (const float*)d_in[16];
  const float* b1   = (const float*)d_in[17];
  const float* W2   = (const float*)d_in[18];
  const float* b2   = (const float*)d_in[19];
  const float* gamma= (const float*)d_in[20];
  const float* beta = (const float*)d_in[21];
  float* out = (float*)d_out;

  char* ws = (char*)d_ws;
  const size_t MB = 1024ull * 1024;
  float* zf   = (float*)(ws);             // z, then a (fp32 residual)
  float* resf = (float*)(ws + 16 * MB);
  bf16*  bz   = (bf16*) (ws + 32 * MB);   // z bf16, then a bf16
  f16*   qkv  = (f16*)  (ws + 40 * MB);   // [8192][1536] f16 (25.2 MB)
  bf16*  ffn1 = (bf16*) (ws + 40 * MB);   // reuses qkv region post-flash (32 MB)
  bf16*  concat = (bf16*)(ws + 72 * MB);  // attention output (8 MB)
  char* wp = ws + 80 * MB;
  bf16* wfqp = (bf16*)(wp);               // plain bf16 forward weights (512KB each)
  bf16* wfkp = (bf16*)(wp + 512 * 1024);
  bf16* wfvp = (bf16*)(wp + 1024 * 1024);
  bf16* wqt  = (bf16*)(wp + 1536 * 1024); // head weights^T (Q pre-scaled)
  bf16* wkt  = (bf16*)(wp + 2048 * 1024);
  bf16* wvt  = (bf16*)(wp + 2560 * 1024);
  bf16* wc   = (bf16*)(wp + 3072 * 1024); // combined QKV weights Bt [1536][512] (1.5MB)
  bf16* wot  = (bf16*)(wp + 4608 * 1024);
  bf16* w1t  = (bf16*)(wp + 5120 * 1024); // 2MB
  bf16* w2t  = (bf16*)(wp + 7168 * 1024); // 2MB
  float* bc  = (float*)(wp + 9216 * 1024); // combined bias [1536]

  // weight preparation
  conv_plain3<<<dim3(1024, 3), 256, 0, stream>>>(WfQ, WfK, WfV, wfqp, wfkp, wfvp);
  conv_t_heads<<<dim3(1024, 3), 256, 0, stream>>>(WQ, WK, WV, wqt, wkt, wvt);
  conv_t<<<1024, 256, 0, stream>>>(Wo, wot, 1, 512, 512, 1.0f);
  conv_t<<<4096, 256, 0, stream>>>(W1, w1t, 1, 512, 2048, 1.0f);
  conv_t<<<4096, 256, 0, stream>>>(W2, w2t, 1, 2048, 512, 1.0f);
  bias_comb<<<384, 256, 0, stream>>>(bfQv, bfKv, bfVv, WQ, WK, WV, bQ, bK, bV, bc);

  // combined weights: wc[n][d] = sum_e Whead^T[n][e] * Wf[d][e]   (Bt form for QKV GEMM)
  dim3 gcomb(4, 8);
  gemm_bt64<<<gcomb, 256, 0, stream>>>(wqt, wfqp, nullptr, nullptr, nullptr, wc,            512, 512, 512, 0);
  gemm_bt64<<<gcomb, 256, 0, stream>>>(wkt, wfkp, nullptr, nullptr, nullptr, wc + 262144,   512, 512, 512, 0);
  gemm_bt64<<<gcomb, 256, 0, stream>>>(wvt, wfvp, nullptr, nullptr, nullptr, wc + 524288,   512, 512, 512, 0);

  embed_pe<<<8192, 256, 0, stream>>>(x, emb, zf, bz);

  // fused QKV: [8192,1536] = z @ wc^T + bc   (f16 out for attention)
  gemm_bt<<<dim3(64, 12), 256, 0, stream>>>(bz, wc, bc, nullptr, nullptr, nullptr, qkv,
                                            8192, QKV_N, 512, 0);
  flash_attn<<<dim3(32, 32), 256, 0, stream>>>(qkv, concat);

  gemm_bt64<<<dim3(64, 8), 256, 0, stream>>>(concat, wot, bo, zf, resf, nullptr, 8192, 512, 512, 0);
  ln_kernel<<<2048, 256, 0, stream>>>(resf, gamma, beta, zf, bz, 0);
  gemm_bt<<<dim3(64, 16), 256, 0, stream>>>(bz, w1t, b1, nullptr, nullptr, ffn1, nullptr,
                                            8192, 2048, 512, 1);
  gemm_bt64<<<dim3(64, 8), 256, 0, stream>>>(ffn1, w2t, b2, zf, resf, nullptr, 8192, 512, 2048, 0);
  ln_kernel<<<2048, 256, 0, stream>>>(resf, gamma, beta, out, nullptr, 1);
}

// Round 3
// 450.141 us; speedup vs baseline: 1.2780x; 1.0212x over previous
//
#include <hip/hip_runtime.h>
#include <math.h>

typedef __bf16 bf16;
typedef __bf16 bf16x8 __attribute__((ext_vector_type(8)));
typedef __bf16 bf16x4 __attribute__((ext_vector_type(4)));
typedef _Float16 f16;
typedef _Float16 f16x8 __attribute__((ext_vector_type(8)));
typedef _Float16 f16x4 __attribute__((ext_vector_type(4)));
typedef float f32x4 __attribute__((ext_vector_type(4)));
typedef unsigned int u32;

#define S_LEN 2048
#define QKV_N 1536
// 0.125 (1/sqrt(DK)) * log2(e), folded into combined Q weights+bias so softmax uses exp2
#define QSCALE 0.18033688011112042f
#define FIXEDMAX 8.0f

__device__ __forceinline__ void gload_lds16(const void* g, void* l) {
  __builtin_amdgcn_global_load_lds((const __attribute__((address_space(1))) u32*)g,
                                   (__attribute__((address_space(3))) u32*)l, 16, 0, 0);
}

// ---------------- embedding + sinusoidal PE ----------------
__global__ __launch_bounds__(256) void embed_pe(const int* __restrict__ x,
    const float* __restrict__ emb, float* __restrict__ zf, bf16* __restrict__ zb)
{
  const int row = blockIdx.x;
  const int s = row & (S_LEN - 1);
  const int tok = x[row];
  const float* e = emb + (size_t)tok * 512;
  float* zr = zf + (size_t)row * 512;
  bf16* zbr = zb + (size_t)row * 512;
  for (int i = threadIdx.x; i < 512; i += 256) {
    float invf = __expf((float)i * (-9.210340371976184f / 512.0f));
    float ang = (float)s * invf;
    float pe = (i & 1) ? __cosf(ang) : __sinf(ang);
    float v = e[i] + pe;
    zr[i] = v;
    zbr[i] = (bf16)v;
  }
}

// ---------------- fp32 -> bf16 plain convert (3 tensors) ----------------
__global__ __launch_bounds__(256) void conv_plain3(const float* __restrict__ i0,
    const float* __restrict__ i1, const float* __restrict__ i2,
    bf16* __restrict__ o0, bf16* __restrict__ o1, bf16* __restrict__ o2)
{
  int gid = blockIdx.x * 256 + threadIdx.x;
  const float* in = blockIdx.y == 0 ? i0 : (blockIdx.y == 1 ? i1 : i2);
  bf16* out = blockIdx.y == 0 ? o0 : (blockIdx.y == 1 ? o1 : o2);
  out[gid] = (bf16)in[gid];
}

// ---------------- Wo/W1/W2 transpose to Bt form, single launch ----------------
__global__ __launch_bounds__(256) void conv_t3(const float* __restrict__ Wo,
    const float* __restrict__ W1, const float* __restrict__ W2,
    bf16* __restrict__ wot, bf16* __restrict__ w1t, bf16* __restrict__ w2t)
{
  int gid = blockIdx.x * 256 + threadIdx.x;
  if (blockIdx.y == 0) {
    if (gid < 512 * 512) {
      int r = gid & 511, c = gid >> 9;
      wot[gid] = (bf16)Wo[r * 512 + c];
    }
  } else if (blockIdx.y == 1) {
    int r = gid & 511, c = gid >> 9;          // c in 0..2047
    w1t[gid] = (bf16)W1[r * 2048 + c];
  } else {
    int r = gid & 2047, c = gid >> 11;        // c in 0..511
    w2t[gid] = (bf16)W2[r * 512 + c];
  }
}

// heads version: 3 tensors of [8][512][64] -> [8][64][512], Q scaled by QSCALE
__global__ __launch_bounds__(256) void conv_t_heads(const float* __restrict__ i0,
    const float* __restrict__ i1, const float* __restrict__ i2,
    bf16* __restrict__ o0, bf16* __restrict__ o1, bf16* __restrict__ o2)
{
  int gid = blockIdx.x * 256 + threadIdx.x;
  const float* in = blockIdx.y == 0 ? i0 : (blockIdx.y == 1 ? i1 : i2);
  bf16* out = blockIdx.y == 0 ? o0 : (blockIdx.y == 1 ? o1 : o2);
  float scale = blockIdx.y == 0 ? QSCALE : 1.0f;
  int r = gid & 511;
  int t = gid >> 9;
  int c = t & 63;
  int h = t >> 6;
  out[gid] = (bf16)(in[((size_t)(h * 512 + r)) * 64 + c] * scale);
}

// ---------------- combined bias ----------------
__global__ __launch_bounds__(256) void bias_comb(
    const float* __restrict__ bfQ, const float* __restrict__ bfK, const float* __restrict__ bfV,
    const float* __restrict__ WQ, const float* __restrict__ WK, const float* __restrict__ WV,
    const float* __restrict__ bQ, const float* __restrict__ bK, const float* __restrict__ bV,
    float* __restrict__ bc)
{
  int n = blockIdx.x * 4 + (threadIdx.x >> 6);
  int lane = threadIdx.x & 63;
  int z = n >> 9, hk = n & 511, h = hk >> 6, k = hk & 63;
  const float* bf = z == 0 ? bfQ : (z == 1 ? bfK : bfV);
  const float* W  = z == 0 ? WQ  : (z == 1 ? WK  : WV);
  const float* bH = z == 0 ? bQ  : (z == 1 ? bK  : bV);
  float s = 0.f;
  for (int e = lane; e < 512; e += 64)
    s += bf[e] * W[((size_t)h * 512 + e) * 64 + k];
  #pragma unroll
  for (int m = 1; m < 64; m <<= 1) s += __shfl_xor(s, m, 64);
  if (lane == 0) {
    float v = s + bH[h * 64 + k];
    if (z == 0) v *= QSCALE;
    bc[n] = v;
  }
}

// ---------------- GEMM 128x128 tile ----------------
__global__ __launch_bounds__(256) void gemm_bt(
    const bf16* __restrict__ A, const bf16* __restrict__ Bt,
    const float* __restrict__ bias, const float* __restrict__ res,
    float* __restrict__ outf, bf16* __restrict__ outb, f16* __restrict__ outh,
    int M, int N, int K, int relu)
{
  __shared__ bf16 As[128 * 32];
  __shared__ bf16 Bs[128 * 32];
  const int tid = threadIdx.x;
  const int wave = tid >> 6, lane = tid & 63, quad = lane >> 4, l16 = lane & 15;
  const int row0 = blockIdx.x * 128, col0 = blockIdx.y * 128;
  const int wm = wave >> 1, wn = wave & 1;
  f32x4 acc[4][4] = {};

  for (int kk = 0; kk < K; kk += 32) {
    __syncthreads();
    #pragma unroll
    for (int r = 0; r < 2; r++) {
      int c = r * 256 + tid;
      gload_lds16(A + (size_t)(row0 + (c >> 2)) * K + kk + (c & 3) * 8, As + c * 8);
    }
    #pragma unroll
    for (int r = 0; r < 2; r++) {
      int c = r * 256 + tid;
      gload_lds16(Bt + (size_t)(col0 + (c >> 2)) * K + kk + (c & 3) * 8, Bs + c * 8);
    }
    __syncthreads();
    bf16x8 af[4], bfr[4];
    #pragma unroll
    for (int i = 0; i < 4; i++)
      af[i] = *(const bf16x8*)(As + (wm * 64 + i * 16 + l16) * 32 + quad * 8);
    #pragma unroll
    for (int i = 0; i < 4; i++)
      bfr[i] = *(const bf16x8*)(Bs + (wn * 64 + i * 16 + l16) * 32 + quad * 8);
    #pragma unroll
    for (int mt = 0; mt < 4; mt++)
      #pragma unroll
      for (int nt = 0; nt < 4; nt++)
        acc[mt][nt] = __builtin_amdgcn_mfma_f32_16x16x32_bf16(af[mt], bfr[nt], acc[mt][nt], 0, 0, 0);
  }

  #pragma unroll
  for (int nt = 0; nt < 4; nt++) {
    int col = col0 + wn * 64 + nt * 16 + l16;
    float bv = bias ? bias[col] : 0.f;
    #pragma unroll
    for (int mt = 0; mt < 4; mt++) {
      int rowb = row0 + wm * 64 + mt * 16 + quad * 4;
      #pragma unroll
      for (int i = 0; i < 4; i++) {
        size_t idx = (size_t)(rowb + i) * N + col;
        float v = acc[mt][nt][i] + bv;
        if (res) v += res[idx];
        if (relu) v = fmaxf(v, 0.f);
        if (outf) outf[idx] = v;
        if (outb) outb[idx] = (bf16)v;
        if (outh) outh[idx] = (f16)v;
      }
    }
  }
}

// ---------------- GEMM 128x64 tile ----------------
__global__ __launch_bounds__(256) void gemm_bt64(
    const bf16* __restrict__ A, const bf16* __restrict__ Bt,
    const float* __restrict__ bias, const float* __restrict__ res,
    float* __restrict__ outf, bf16* __restrict__ outb,
    int M, int N, int K, int relu)
{
  __shared__ bf16 As[128 * 32];
  __shared__ bf16 Bs[64 * 32];
  const int tid = threadIdx.x;
  const int wave = tid >> 6, lane = tid & 63, quad = lane >> 4, l16 = lane & 15;
  const int row0 = blockIdx.x * 128, col0 = blockIdx.y * 64;
  const int wm = wave >> 1, wn = wave & 1;
  f32x4 acc[4][2] = {};

  for (int kk = 0; kk < K; kk += 32) {
    __syncthreads();
    #pragma unroll
    for (int r = 0; r < 2; r++) {
      int c = r * 256 + tid;
      gload_lds16(A + (size_t)(row0 + (c >> 2)) * K + kk + (c & 3) * 8, As + c * 8);
    }
    {
      int c = tid;
      gload_lds16(Bt + (size_t)(col0 + (c >> 2)) * K + kk + (c & 3) * 8, Bs + c * 8);
    }
    __syncthreads();
    bf16x8 af[4], bfr[2];
    #pragma unroll
    for (int i = 0; i < 4; i++)
      af[i] = *(const bf16x8*)(As + (wm * 64 + i * 16 + l16) * 32 + quad * 8);
    #pragma unroll
    for (int i = 0; i < 2; i++)
      bfr[i] = *(const bf16x8*)(Bs + (wn * 32 + i * 16 + l16) * 32 + quad * 8);
    #pragma unroll
    for (int mt = 0; mt < 4; mt++)
      #pragma unroll
      for (int nt = 0; nt < 2; nt++)
        acc[mt][nt] = __builtin_amdgcn_mfma_f32_16x16x32_bf16(af[mt], bfr[nt], acc[mt][nt], 0, 0, 0);
  }

  #pragma unroll
  for (int nt = 0; nt < 2; nt++) {
    int col = col0 + wn * 32 + nt * 16 + l16;
    float bv = bias ? bias[col] : 0.f;
    #pragma unroll
    for (int mt = 0; mt < 4; mt++) {
      int rowb = row0 + wm * 64 + mt * 16 + quad * 4;
      #pragma unroll
      for (int i = 0; i < 4; i++) {
        size_t idx = (size_t)(rowb + i) * N + col;
        float v = acc[mt][nt][i] + bv;
        if (res) v += res[idx];
        if (relu) v = fmaxf(v, 0.f);
        if (outf) outf[idx] = v;
        if (outb) outb[idx] = (bf16)v;
      }
    }
  }
}

// ---------------- flash attention, transposed, fixed-max softmax ----------------
// qkv: [b*S+s][1536] f16 (Q pre-scaled by QSCALE, exp2 domain). Wave = 32 queries
// (2 fragments), block = 4 waves = 128 q. Grid (qtile=16, bh=32).
__global__ __launch_bounds__(256) void flash_attn(
    const f16* __restrict__ qkv, bf16* __restrict__ outc)
{
  __shared__ f16 Ks[64 * 64];    // [key][dk], 16B-chunk XOR-swizzled by row&7
  __shared__ f16 Vts[64 * 72];   // [dv][key], padded 72
  const int bh = blockIdx.y;
  const int b = bh >> 3, h = bh & 7;
  const int q0 = blockIdx.x * 128;
  const int tid = threadIdx.x;
  const int wave = tid >> 6, lane = tid & 63, quad = lane >> 4, l16 = lane & 15;

  const f16* Qb = qkv + (size_t)b * S_LEN * QKV_N + h * 64;
  const f16* Kb = Qb + 512;
  const f16* Vb = Qb + 1024;

  // Q fragments: B[n=q=l16][k=dk=quad*8+j (+32*kh)]
  f16x8 qf[2][2];
  #pragma unroll
  for (int f = 0; f < 2; f++) {
    int qrow = q0 + wave * 32 + f * 16 + l16;
    #pragma unroll
    for (int kh = 0; kh < 2; kh++)
      qf[f][kh] = *(const f16x8*)(Qb + (size_t)qrow * QKV_N + kh * 32 + quad * 8);
  }

  f32x4 O[2][4] = {};            // O^T: row=dv, col=q=l16
  float rsum[2] = {0.f, 0.f};

  // loop-invariant LDS read addresses (swizzled)
  const int swz = l16 & 7;
  const f16* kf0p = Ks + l16 * 64 + ((quad ^ swz) * 8);
  const f16* kf1p = Ks + l16 * 64 + (((4 + quad) ^ swz) * 8);

  for (int kc = 0; kc < S_LEN; kc += 64) {
    // stage K [64 keys][64 dk], swizzled 16B chunks
    #pragma unroll
    for (int r = 0; r < 2; r++) {
      int c = r * 256 + tid;
      int krow = c >> 3, cc = c & 7;
      f16x8 kv = *(const f16x8*)(Kb + (size_t)(kc + krow) * QKV_N + cc * 8);
      *(f16x8*)(Ks + krow * 64 + ((cc ^ (krow & 7)) * 8)) = kv;
    }
    // stage V^T [dv][key]
    {
      int key = tid & 63, dvb = (tid >> 6) * 16;
      const f16* vp = Vb + (size_t)(kc + key) * QKV_N + dvb;
      f16x8 v0 = *(const f16x8*)vp;
      f16x8 v1 = *(const f16x8*)(vp + 8);
      #pragma unroll
      for (int i = 0; i < 8; i++) {
        Vts[(dvb + i) * 72 + key] = v0[i];
        Vts[(dvb + 8 + i) * 72 + key] = v1[i];
      }
    }
    __syncthreads();

    // S^T = K Q^T, then P = exp2(S^T - FIXEDMAX)
    f16x4 pf[2][4];
    #pragma unroll
    for (int nt = 0; nt < 4; nt++) {
      f16x8 kf0 = *(const f16x8*)(kf0p + nt * 1024);
      f16x8 kf1 = *(const f16x8*)(kf1p + nt * 1024);
      #pragma unroll
      for (int f = 0; f < 2; f++) {
        f32x4 a = {};
        a = __builtin_amdgcn_mfma_f32_16x16x32_f16(kf0, qf[f][0], a, 0, 0, 0);
        a = __builtin_amdgcn_mfma_f32_16x16x32_f16(kf1, qf[f][1], a, 0, 0, 0);
        #pragma unroll
        for (int i = 0; i < 4; i++) {
          float p = exp2f(a[i] - FIXEDMAX);
          rsum[f] += p;
          pf[f][nt][i] = (f16)p;
        }
      }
    }

    // O^T += V^T P^T  (16x16x16: A[m=dv][k=key=quad*4+j], B[k][n=q])
    #pragma unroll
    for (int nt = 0; nt < 4; nt++)
      #pragma unroll
      for (int mt = 0; mt < 4; mt++) {
        f16x4 vf = *(const f16x4*)(Vts + (mt * 16 + l16) * 72 + nt * 16 + quad * 4);
        #pragma unroll
        for (int f = 0; f < 2; f++)
          O[f][mt] = __builtin_amdgcn_mfma_f32_16x16x16f16(vf, pf[f][nt], O[f][mt], 0, 0, 0);
      }
    __syncthreads();
  }

  // final normalization (sum over key partitions = quads)
  #pragma unroll
  for (int f = 0; f < 2; f++) {
    rsum[f] += __shfl_xor(rsum[f], 16, 64);
    rsum[f] += __shfl_xor(rsum[f], 32, 64);
  }

  // epilogue: transpose via per-wave LDS regions, coalesced store
  #pragma unroll
  for (int f = 0; f < 2; f++) {
    float invl = 1.f / rsum[f];
    bf16* ob = (f == 0 ? (bf16*)Ks : (bf16*)Vts) + wave * 1024;  // [16 q][64 dv]
    #pragma unroll
    for (int mt = 0; mt < 4; mt++)
      #pragma unroll
      for (int i = 0; i < 4; i++)
        ob[l16 * 64 + mt * 16 + quad * 4 + i] = (bf16)(O[f][mt][i] * invl);
  }
  asm volatile("s_waitcnt lgkmcnt(0)" ::: "memory");
  #pragma unroll
  for (int f = 0; f < 2; f++) {
    bf16* ob = (f == 0 ? (bf16*)Ks : (bf16*)Vts) + wave * 1024;
    int row = lane >> 2, dvb = (lane & 3) * 16;
    bf16x8 o0 = *(const bf16x8*)(ob + row * 64 + dvb);
    bf16x8 o1 = *(const bf16x8*)(ob + row * 64 + dvb + 8);
    size_t g = ((size_t)b * S_LEN + q0 + wave * 32 + f * 16 + row) * 512 + h * 64 + dvb;
    *(bf16x8*)(outc + g) = o0;
    *(bf16x8*)(outc + g + 8) = o1;
  }
}

// ---------------- LayerNorm ----------------
__global__ __launch_bounds__(256) void ln_kernel(const float* __restrict__ in,
    const float* __restrict__ gamma, const float* __restrict__ beta,
    float* __restrict__ outf, bf16* __restrict__ outb, int relu)
{
  const int row = blockIdx.x * 4 + (threadIdx.x >> 6);
  const int lane = threadIdx.x & 63;
  const float4* p = (const float4*)(in + (size_t)row * 512);
  float4 v0 = p[lane];
  float4 v1 = p[lane + 64];
  float s = v0.x + v0.y + v0.z + v0.w + v1.x + v1.y + v1.z + v1.w;
  #pragma unroll
  for (int m = 1; m < 64; m <<= 1) s += __shfl_xor(s, m, 64);
  float mu = s * (1.f / 512.f);
  float d0 = v0.x - mu, d1 = v0.y - mu, d2 = v0.z - mu, d3 = v0.w - mu;
  float d4 = v1.x - mu, d5 = v1.y - mu, d6 = v1.z - mu, d7 = v1.w - mu;
  float q = d0*d0 + d1*d1 + d2*d2 + d3*d3 + d4*d4 + d5*d5 + d6*d6 + d7*d7;
  #pragma unroll
  for (int m = 1; m < 64; m <<= 1) q += __shfl_xor(q, m, 64);
  float rs = rsqrtf(q * (1.f / 512.f) + 1e-5f);
  const float4* gp = (const float4*)gamma;
  const float4* bp = (const float4*)beta;
  float4 g0 = gp[lane], g1 = gp[lane + 64];
  float4 b0 = bp[lane], b1 = bp[lane + 64];
  float y0 = d0 * rs * g0.x + b0.x, y1 = d1 * rs * g0.y + b0.y;
  float y2 = d2 * rs * g0.z + b0.z, y3 = d3 * rs * g0.w + b0.w;
  float y4 = d4 * rs * g1.x + b1.x, y5 = d5 * rs * g1.y + b1.y;
  float y6 = d6 * rs * g1.z + b1.z, y7 = d7 * rs * g1.w + b1.w;
  if (relu) {
    y0 = fmaxf(y0, 0.f); y1 = fmaxf(y1, 0.f); y2 = fmaxf(y2, 0.f); y3 = fmaxf(y3, 0.f);
    y4 = fmaxf(y4, 0.f); y5 = fmaxf(y5, 0.f); y6 = fmaxf(y6, 0.f); y7 = fmaxf(y7, 0.f);
  }
  float4* op = (float4*)(outf + (size_t)row * 512);
  float4 o0 = {y0, y1, y2, y3}, o1 = {y4, y5, y6, y7};
  op[lane] = o0;
  op[lane + 64] = o1;
  if (outb) {
    bf16x4 c0 = {(bf16)y0, (bf16)y1, (bf16)y2, (bf16)y3};
    bf16x4 c1 = {(bf16)y4, (bf16)y5, (bf16)y6, (bf16)y7};
    *(bf16x4*)(outb + (size_t)row * 512 + lane * 4) = c0;
    *(bf16x4*)(outb + (size_t)row * 512 + 256 + lane * 4) = c1;
  }
}

extern "C" void kernel_launch(void* const* d_in, const int* in_sizes, int n_in,
                              void* d_out, int out_size, void* d_ws, size_t ws_size,
                              hipStream_t stream)
{
  const int*   x    = (const int*)  d_in[0];
  const float* emb  = (const float*)d_in[1];
  const float* WfQ  = (const float*)d_in[2];
  const float* bfQv = (const float*)d_in[3];
  const float* WfK  = (const float*)d_in[4];
  const float* bfKv = (const float*)d_in[5];
  const float* WfV  = (const float*)d_in[6];
  const float* bfVv = (const float*)d_in[7];
  const float* WQ   = (const float*)d_in[8];
  const float* bQ   = (const float*)d_in[9];
  const float* WK   = (const float*)d_in[10];
  const float* bK   = (const float*)d_in[11];
  const float* WV   = (const float*)d_in[12];
  const float* bV   = (const float*)d_in[13];
  const float* Wo   = (const float*)d_in[14];
  const float* bo   = (const float*)d_in[15];
  const float* W1   = (const float*)d_in[16];
  const float* b1   = (const float*)d_in[17];
  const float* W2   = (const float*)d_in[18];
  const float* b2   = (const float*)d_in[19];
  const float* gamma= (const float*)d_in[20];
  const float* beta = (const float*)d_in[21];
  float* out = (float*)d_out;

  char* ws = (char*)d_ws;
  const size_t MB = 1024ull * 1024;
  float* zf   = (float*)(ws);
  float* resf = (float*)(ws + 16 * MB);
  bf16*  bz   = (bf16*) (ws + 32 * MB);
  f16*   qkv  = (f16*)  (ws + 40 * MB);
  bf16*  ffn1 = (bf16*) (ws + 40 * MB);
  bf16*  concat = (bf16*)(ws + 72 * MB);
  char* wp = ws + 80 * MB;
  bf16* wfqp = (bf16*)(wp);
  bf16* wfkp = (bf16*)(wp + 512 * 1024);
  bf16* wfvp = (bf16*)(wp + 1024 * 1024);
  bf16* wqt  = (bf16*)(wp + 1536 * 1024);
  bf16* wkt  = (bf16*)(wp + 2048 * 1024);
  bf16* wvt  = (bf16*)(wp + 2560 * 1024);
  bf16* wc   = (bf16*)(wp + 3072 * 1024);
  bf16* wot  = (bf16*)(wp + 4608 * 1024);
  bf16* w1t  = (bf16*)(wp + 5120 * 1024);
  bf16* w2t  = (bf16*)(wp + 7168 * 1024);
  float* bc  = (float*)(wp + 9216 * 1024);

  conv_plain3<<<dim3(1024, 3), 256, 0, stream>>>(WfQ, WfK, WfV, wfqp, wfkp, wfvp);
  conv_t_heads<<<dim3(1024, 3), 256, 0, stream>>>(WQ, WK, WV, wqt, wkt, wvt);
  conv_t3<<<dim3(4096, 3), 256, 0, stream>>>(Wo, W1, W2, wot, w1t, w2t);
  bias_comb<<<384, 256, 0, stream>>>(bfQv, bfKv, bfVv, WQ, WK, WV, bQ, bK, bV, bc);

  dim3 gcomb(4, 8);
  gemm_bt64<<<gcomb, 256, 0, stream>>>(wqt, wfqp, nullptr, nullptr, nullptr, wc,            512, 512, 512, 0);
  gemm_bt64<<<gcomb, 256, 0, stream>>>(wkt, wfkp, nullptr, nullptr, nullptr, wc + 262144,   512, 512, 512, 0);
  gemm_bt64<<<gcomb, 256, 0, stream>>>(wvt, wfvp, nullptr, nullptr, nullptr, wc + 524288,   512, 512, 512, 0);

  embed_pe<<<8192, 256, 0, stream>>>(x, emb, zf, bz);

  gemm_bt<<<dim3(64, 12), 256, 0, stream>>>(bz, wc, bc, nullptr, nullptr, nullptr, qkv,
                                            8192, QKV_N, 512, 0);
  flash_attn<<<dim3(16, 32), 256, 0, stream>>>(qkv, concat);

  gemm_bt64<<<dim3(64, 8), 256, 0, stream>>>(concat, wot, bo, zf, resf, nullptr, 8192, 512, 512, 0);
  ln_kernel<<<2048, 256, 0, stream>>>(resf, gamma, beta, zf, bz, 0);
  gemm_bt<<<dim3(64, 16), 256, 0, stream>>>(bz, w1t, b1, nullptr, nullptr, ffn1, nullptr,
                                            8192, 2048, 512, 1);
  gemm_bt64<<<dim3(64, 8), 256, 0, stream>>>(ffn1, w2t, b2, zf, resf, nullptr, 8192, 512, 2048, 0);
  ln_kernel<<<2048, 256, 0, stream>>>(resf, gamma, beta, out, nullptr, 1);
}

// Round 4
// 408.375 us; speedup vs baseline: 1.4087x; 1.1023x over previous
//
#include <hip/hip_runtime.h>
#include <math.h>

typedef __bf16 bf16;
typedef __bf16 bf16x8 __attribute__((ext_vector_type(8)));
typedef __bf16 bf16x4 __attribute__((ext_vector_type(4)));
typedef _Float16 f16;
typedef _Float16 f16x8 __attribute__((ext_vector_type(8)));
typedef _Float16 f16x4 __attribute__((ext_vector_type(4)));
typedef float f32x4 __attribute__((ext_vector_type(4)));
typedef unsigned int u32;

#define S_LEN 2048
#define QSCALE 0.18033688011112042f   // 0.125/sqrt-dk * log2(e), folded into Q weights+bias
#define FIXEDMAX 8.0f

__device__ __forceinline__ void gload_lds16(const void* g, void* l) {
  __builtin_amdgcn_global_load_lds((const __attribute__((address_space(1))) u32*)g,
                                   (__attribute__((address_space(3))) u32*)l, 16, 0, 0);
}

// ---------------- embedding + sinusoidal PE ----------------
__global__ __launch_bounds__(256) void embed_pe(const int* __restrict__ x,
    const float* __restrict__ emb, float* __restrict__ zf, bf16* __restrict__ zb)
{
  const int row = blockIdx.x;
  const int s = row & (S_LEN - 1);
  const int tok = x[row];
  const float* e = emb + (size_t)tok * 512;
  float* zr = zf + (size_t)row * 512;
  bf16* zbr = zb + (size_t)row * 512;
  for (int i = threadIdx.x; i < 512; i += 256) {
    float invf = __expf((float)i * (-9.210340371976184f / 512.0f));
    float ang = (float)s * invf;
    float pe = (i & 1) ? __cosf(ang) : __sinf(ang);
    float v = e[i] + pe;
    zr[i] = v;
    zbr[i] = (bf16)v;
  }
}

// ---------------- fp32 -> bf16 plain convert (3 tensors) ----------------
__global__ __launch_bounds__(256) void conv_plain3(const float* __restrict__ i0,
    const float* __restrict__ i1, const float* __restrict__ i2,
    bf16* __restrict__ o0, bf16* __restrict__ o1, bf16* __restrict__ o2)
{
  int gid = blockIdx.x * 256 + threadIdx.x;
  const float* in = blockIdx.y == 0 ? i0 : (blockIdx.y == 1 ? i1 : i2);
  bf16* out = blockIdx.y == 0 ? o0 : (blockIdx.y == 1 ? o1 : o2);
  out[gid] = (bf16)in[gid];
}

// ---------------- Wo/W1/W2 transpose to Bt form ----------------
__global__ __launch_bounds__(256) void conv_t3(const float* __restrict__ Wo,
    const float* __restrict__ W1, const float* __restrict__ W2,
    bf16* __restrict__ wot, bf16* __restrict__ w1t, bf16* __restrict__ w2t)
{
  int gid = blockIdx.x * 256 + threadIdx.x;
  if (blockIdx.y == 0) {
    if (gid < 512 * 512) {
      int r = gid & 511, c = gid >> 9;
      wot[gid] = (bf16)Wo[r * 512 + c];
    }
  } else if (blockIdx.y == 1) {
    int r = gid & 511, c = gid >> 9;
    w1t[gid] = (bf16)W1[r * 2048 + c];
  } else {
    int r = gid & 2047, c = gid >> 11;
    w2t[gid] = (bf16)W2[r * 512 + c];
  }
}

// heads: 3 tensors [8][512][64] -> [8][64][512], Q scaled
__global__ __launch_bounds__(256) void conv_t_heads(const float* __restrict__ i0,
    const float* __restrict__ i1, const float* __restrict__ i2,
    bf16* __restrict__ o0, bf16* __restrict__ o1, bf16* __restrict__ o2)
{
  int gid = blockIdx.x * 256 + threadIdx.x;
  const float* in = blockIdx.y == 0 ? i0 : (blockIdx.y == 1 ? i1 : i2);
  bf16* out = blockIdx.y == 0 ? o0 : (blockIdx.y == 1 ? o1 : o2);
  float scale = blockIdx.y == 0 ? QSCALE : 1.0f;
  int r = gid & 511;
  int t = gid >> 9;
  int c = t & 63;
  int h = t >> 6;
  out[gid] = (bf16)(in[((size_t)(h * 512 + r)) * 64 + c] * scale);
}

// ---------------- combined bias ----------------
__global__ __launch_bounds__(256) void bias_comb(
    const float* __restrict__ bfQ, const float* __restrict__ bfK, const float* __restrict__ bfV,
    const float* __restrict__ WQ, const float* __restrict__ WK, const float* __restrict__ WV,
    const float* __restrict__ bQ, const float* __restrict__ bK, const float* __restrict__ bV,
    float* __restrict__ bc)
{
  int n = blockIdx.x * 4 + (threadIdx.x >> 6);
  int lane = threadIdx.x & 63;
  int z = n >> 9, hk = n & 511, h = hk >> 6, k = hk & 63;
  const float* bf = z == 0 ? bfQ : (z == 1 ? bfK : bfV);
  const float* W  = z == 0 ? WQ  : (z == 1 ? WK  : WV);
  const float* bH = z == 0 ? bQ  : (z == 1 ? bK  : bV);
  float s = 0.f;
  for (int e = lane; e < 512; e += 64)
    s += bf[e] * W[((size_t)h * 512 + e) * 64 + k];
  #pragma unroll
  for (int m = 1; m < 64; m <<= 1) s += __shfl_xor(s, m, 64);
  if (lane == 0) {
    float v = s + bH[h * 64 + k];
    if (z == 0) v *= QSCALE;
    bc[n] = v;
  }
}

// ---------------- GEMM 128x128 tile (bf16 out; FFN1) ----------------
__global__ __launch_bounds__(256) void gemm_bt(
    const bf16* __restrict__ A, const bf16* __restrict__ Bt,
    const float* __restrict__ bias, const float* __restrict__ res,
    float* __restrict__ outf, bf16* __restrict__ outb,
    int M, int N, int K, int relu)
{
  __shared__ bf16 As[128 * 32];
  __shared__ bf16 Bs[128 * 32];
  const int tid = threadIdx.x;
  const int wave = tid >> 6, lane = tid & 63, quad = lane >> 4, l16 = lane & 15;
  const int row0 = blockIdx.x * 128, col0 = blockIdx.y * 128;
  const int wm = wave >> 1, wn = wave & 1;
  f32x4 acc[4][4] = {};

  for (int kk = 0; kk < K; kk += 32) {
    __syncthreads();
    #pragma unroll
    for (int r = 0; r < 2; r++) {
      int c = r * 256 + tid;
      gload_lds16(A + (size_t)(row0 + (c >> 2)) * K + kk + (c & 3) * 8, As + c * 8);
    }
    #pragma unroll
    for (int r = 0; r < 2; r++) {
      int c = r * 256 + tid;
      gload_lds16(Bt + (size_t)(col0 + (c >> 2)) * K + kk + (c & 3) * 8, Bs + c * 8);
    }
    __syncthreads();
    bf16x8 af[4], bfr[4];
    #pragma unroll
    for (int i = 0; i < 4; i++)
      af[i] = *(const bf16x8*)(As + (wm * 64 + i * 16 + l16) * 32 + quad * 8);
    #pragma unroll
    for (int i = 0; i < 4; i++)
      bfr[i] = *(const bf16x8*)(Bs + (wn * 64 + i * 16 + l16) * 32 + quad * 8);
    #pragma unroll
    for (int mt = 0; mt < 4; mt++)
      #pragma unroll
      for (int nt = 0; nt < 4; nt++)
        acc[mt][nt] = __builtin_amdgcn_mfma_f32_16x16x32_bf16(af[mt], bfr[nt], acc[mt][nt], 0, 0, 0);
  }

  #pragma unroll
  for (int nt = 0; nt < 4; nt++) {
    int col = col0 + wn * 64 + nt * 16 + l16;
    float bv = bias ? bias[col] : 0.f;
    #pragma unroll
    for (int mt = 0; mt < 4; mt++) {
      int rowb = row0 + wm * 64 + mt * 16 + quad * 4;
      #pragma unroll
      for (int i = 0; i < 4; i++) {
        size_t idx = (size_t)(rowb + i) * N + col;
        float v = acc[mt][nt][i] + bv;
        if (res) v += res[idx];
        if (relu) v = fmaxf(v, 0.f);
        if (outf) outf[idx] = v;
        if (outb) outb[idx] = (bf16)v;
      }
    }
  }
}

// ---------------- QKV GEMM: N=1536, writes qk f16[row][1024] + Vt f16[bh][dv][2048] ----------------
__global__ __launch_bounds__(256) void gemm_qkv(
    const bf16* __restrict__ A, const bf16* __restrict__ Bt,
    const float* __restrict__ bias, f16* __restrict__ qk, f16* __restrict__ Vt)
{
  __shared__ bf16 As[128 * 32];
  __shared__ bf16 Bs[128 * 32];
  const int tid = threadIdx.x;
  const int wave = tid >> 6, lane = tid & 63, quad = lane >> 4, l16 = lane & 15;
  const int row0 = blockIdx.x * 128, col0 = blockIdx.y * 128;
  const int wm = wave >> 1, wn = wave & 1;
  f32x4 acc[4][4] = {};

  for (int kk = 0; kk < 512; kk += 32) {
    __syncthreads();
    #pragma unroll
    for (int r = 0; r < 2; r++) {
      int c = r * 256 + tid;
      gload_lds16(A + (size_t)(row0 + (c >> 2)) * 512 + kk + (c & 3) * 8, As + c * 8);
    }
    #pragma unroll
    for (int r = 0; r < 2; r++) {
      int c = r * 256 + tid;
      gload_lds16(Bt + (size_t)(col0 + (c >> 2)) * 512 + kk + (c & 3) * 8, Bs + c * 8);
    }
    __syncthreads();
    bf16x8 af[4], bfr[4];
    #pragma unroll
    for (int i = 0; i < 4; i++)
      af[i] = *(const bf16x8*)(As + (wm * 64 + i * 16 + l16) * 32 + quad * 8);
    #pragma unroll
    for (int i = 0; i < 4; i++)
      bfr[i] = *(const bf16x8*)(Bs + (wn * 64 + i * 16 + l16) * 32 + quad * 8);
    #pragma unroll
    for (int mt = 0; mt < 4; mt++)
      #pragma unroll
      for (int nt = 0; nt < 4; nt++)
        acc[mt][nt] = __builtin_amdgcn_mfma_f32_16x16x32_bf16(af[mt], bfr[nt], acc[mt][nt], 0, 0, 0);
  }

  #pragma unroll
  for (int nt = 0; nt < 4; nt++) {
    int col = col0 + wn * 64 + nt * 16 + l16;
    float bv = bias[col];
    if (col < 1024) {
      #pragma unroll
      for (int mt = 0; mt < 4; mt++) {
        int rowb = row0 + wm * 64 + mt * 16 + quad * 4;
        #pragma unroll
        for (int i = 0; i < 4; i++)
          qk[(size_t)(rowb + i) * 1024 + col] = (f16)(acc[mt][nt][i] + bv);
      }
    } else {
      int h = (col - 1024) >> 6, dv = col & 63;
      #pragma unroll
      for (int mt = 0; mt < 4; mt++) {
        int rowb = row0 + wm * 64 + mt * 16 + quad * 4;
        int b = rowb >> 11, s = rowb & 2047;
        f16x4 vv;
        #pragma unroll
        for (int i = 0; i < 4; i++) vv[i] = (f16)(acc[mt][nt][i] + bv);
        *(f16x4*)(Vt + ((size_t)((b * 8 + h) * 64 + dv)) * 2048 + s) = vv;
      }
    }
  }
}

// ---------------- FFN2 split-K partial GEMM (raw f32 partials) ----------------
__global__ __launch_bounds__(256) void gemm_part(
    const bf16* __restrict__ A, const bf16* __restrict__ Bt,
    float* __restrict__ Pa, float* __restrict__ Pb, int N, int K, int Kh)
{
  __shared__ bf16 As[128 * 32];
  __shared__ bf16 Bs[128 * 32];
  const int tid = threadIdx.x;
  const int wave = tid >> 6, lane = tid & 63, quad = lane >> 4, l16 = lane & 15;
  const int row0 = blockIdx.x * 128, col0 = blockIdx.y * 128;
  const int wm = wave >> 1, wn = wave & 1;
  const int kk0 = blockIdx.z * Kh;
  float* P = blockIdx.z ? Pb : Pa;
  f32x4 acc[4][4] = {};

  for (int kk = kk0; kk < kk0 + Kh; kk += 32) {
    __syncthreads();
    #pragma unroll
    for (int r = 0; r < 2; r++) {
      int c = r * 256 + tid;
      gload_lds16(A + (size_t)(row0 + (c >> 2)) * K + kk + (c & 3) * 8, As + c * 8);
    }
    #pragma unroll
    for (int r = 0; r < 2; r++) {
      int c = r * 256 + tid;
      gload_lds16(Bt + (size_t)(col0 + (c >> 2)) * K + kk + (c & 3) * 8, Bs + c * 8);
    }
    __syncthreads();
    bf16x8 af[4], bfr[4];
    #pragma unroll
    for (int i = 0; i < 4; i++)
      af[i] = *(const bf16x8*)(As + (wm * 64 + i * 16 + l16) * 32 + quad * 8);
    #pragma unroll
    for (int i = 0; i < 4; i++)
      bfr[i] = *(const bf16x8*)(Bs + (wn * 64 + i * 16 + l16) * 32 + quad * 8);
    #pragma unroll
    for (int mt = 0; mt < 4; mt++)
      #pragma unroll
      for (int nt = 0; nt < 4; nt++)
        acc[mt][nt] = __builtin_amdgcn_mfma_f32_16x16x32_bf16(af[mt], bfr[nt], acc[mt][nt], 0, 0, 0);
  }

  #pragma unroll
  for (int nt = 0; nt < 4; nt++) {
    int col = col0 + wn * 64 + nt * 16 + l16;
    #pragma unroll
    for (int mt = 0; mt < 4; mt++) {
      int rowb = row0 + wm * 64 + mt * 16 + quad * 4;
      #pragma unroll
      for (int i = 0; i < 4; i++)
        P[(size_t)(rowb + i) * N + col] = acc[mt][nt][i];
    }
  }
}

// ---------------- flash attention: split-K, ping-pong LDS, 1 barrier/chunk ----------------
// qk: [8192][1024] f16 (Q cols 0..511 pre-scaled, K cols 512..1023)
// Vt: [32 bh][64 dv][2048 s] f16. Grid (16 qtile, 32 bh, 2 half).
// Outputs un-normalized O partials (bf16) + per-half row sums.
__global__ __launch_bounds__(256) void flash_attn(
    const f16* __restrict__ qk, const f16* __restrict__ Vt,
    bf16* __restrict__ Op, float* __restrict__ Rp)
{
  __shared__ f16 Ks[2][4096];   // [key][dk], 16B chunks XOR-swizzled by row&7
  __shared__ f16 Vs[2][4096];   // [dv][key], same swizzle
  const int bh = blockIdx.y, b = bh >> 3, h = bh & 7;
  const int q0 = blockIdx.x * 128;
  const int half = blockIdx.z;
  const int tid = threadIdx.x;
  const int wave = tid >> 6, lane = tid & 63, quad = lane >> 4, l16 = lane & 15;

  const f16* Qb = qk + ((size_t)b * S_LEN) * 1024 + h * 64;
  const f16* Kb = Qb + 512;
  const f16* Vtb = Vt + ((size_t)bh * 64) * 2048;
  const int key0 = half * 1024;

  f16x8 qf[2][2];
  #pragma unroll
  for (int f = 0; f < 2; f++) {
    int qrow = q0 + wave * 32 + f * 16 + l16;
    #pragma unroll
    for (int kh = 0; kh < 2; kh++)
      qf[f][kh] = *(const f16x8*)(Qb + (size_t)qrow * 1024 + kh * 32 + quad * 8);
  }

  f32x4 O[2][4] = {};
  float rsum[2] = {0.f, 0.f};
  const int swz = l16 & 7;

  f16x8 kreg[2], vreg[2];
  const int srow = tid >> 3, soff = tid & 7;        // staging row / 16B-chunk (it=0)
  const int srow1 = (256 + tid) >> 3, soff1 = tid & 7;

  // prefetch chunk 0
  {
    int kb = key0;
    kreg[0] = *(const f16x8*)(Kb + (size_t)(kb + srow) * 1024 + soff * 8);
    vreg[0] = *(const f16x8*)(Vtb + (size_t)srow * 2048 + kb + soff * 8);
    kreg[1] = *(const f16x8*)(Kb + (size_t)(kb + srow1) * 1024 + soff1 * 8);
    vreg[1] = *(const f16x8*)(Vtb + (size_t)srow1 * 2048 + kb + soff1 * 8);
  }

  for (int c = 0; c < 16; c++) {
    f16* KsB = Ks[c & 1];
    f16* VsB = Vs[c & 1];
    *(f16x8*)(KsB + srow * 64 + ((soff ^ (srow & 7)) * 8)) = kreg[0];
    *(f16x8*)(VsB + srow * 64 + ((soff ^ (srow & 7)) * 8)) = vreg[0];
    *(f16x8*)(KsB + srow1 * 64 + ((soff1 ^ (srow1 & 7)) * 8)) = kreg[1];
    *(f16x8*)(VsB + srow1 * 64 + ((soff1 ^ (srow1 & 7)) * 8)) = vreg[1];
    __syncthreads();
    if (c < 15) {   // prefetch next chunk into regs (overlaps compute below)
      int kb = key0 + (c + 1) * 64;
      kreg[0] = *(const f16x8*)(Kb + (size_t)(kb + srow) * 1024 + soff * 8);
      vreg[0] = *(const f16x8*)(Vtb + (size_t)srow * 2048 + kb + soff * 8);
      kreg[1] = *(const f16x8*)(Kb + (size_t)(kb + srow1) * 1024 + soff1 * 8);
      vreg[1] = *(const f16x8*)(Vtb + (size_t)srow1 * 2048 + kb + soff1 * 8);
    }

    // S^T = K Q^T -> P = exp2(S^T - FIXEDMAX)
    f16x4 pf[2][4];
    #pragma unroll
    for (int nt = 0; nt < 4; nt++) {
      const f16* kp = KsB + (nt * 16 + l16) * 64;
      f16x8 kf0 = *(const f16x8*)(kp + ((quad ^ swz) * 8));
      f16x8 kf1 = *(const f16x8*)(kp + (((4 + quad) ^ swz) * 8));
      #pragma unroll
      for (int f = 0; f < 2; f++) {
        f32x4 a = {};
        a = __builtin_amdgcn_mfma_f32_16x16x32_f16(kf0, qf[f][0], a, 0, 0, 0);
        a = __builtin_amdgcn_mfma_f32_16x16x32_f16(kf1, qf[f][1], a, 0, 0, 0);
        #pragma unroll
        for (int i = 0; i < 4; i++) {
          float p = exp2f(a[i] - FIXEDMAX);
          rsum[f] += p;
          pf[f][nt][i] = (f16)p;
        }
      }
    }

    // O^T += V^T P^T  (16x16x16)
    #pragma unroll
    for (int nt = 0; nt < 4; nt++) {
      int vchunk = (nt * 2 + (quad >> 1));
      #pragma unroll
      for (int mt = 0; mt < 4; mt++) {
        const f16* vp = VsB + (mt * 16 + l16) * 64 + ((vchunk ^ swz) * 8) + (quad & 1) * 4;
        f16x4 vf = *(const f16x4*)vp;
        #pragma unroll
        for (int f = 0; f < 2; f++)
          O[f][mt] = __builtin_amdgcn_mfma_f32_16x16x16f16(vf, pf[f][nt], O[f][mt], 0, 0, 0);
      }
    }
    __syncthreads();
  }

  #pragma unroll
  for (int f = 0; f < 2; f++) {
    rsum[f] += __shfl_xor(rsum[f], 16, 64);
    rsum[f] += __shfl_xor(rsum[f], 32, 64);
  }

  // store un-normalized partials: transpose via per-wave LDS regions
  #pragma unroll
  for (int f = 0; f < 2; f++) {
    bf16* ob = (f == 0 ? (bf16*)&Ks[0][0] : (bf16*)&Vs[0][0]) + wave * 1024;
    #pragma unroll
    for (int mt = 0; mt < 4; mt++)
      #pragma unroll
      for (int i = 0; i < 4; i++)
        ob[l16 * 64 + mt * 16 + quad * 4 + i] = (bf16)O[f][mt][i];
  }
  asm volatile("s_waitcnt lgkmcnt(0)" ::: "memory");
  const size_t obase = (size_t)(half * 32 + bh) * 2048;
  #pragma unroll
  for (int f = 0; f < 2; f++) {
    bf16* ob = (f == 0 ? (bf16*)&Ks[0][0] : (bf16*)&Vs[0][0]) + wave * 1024;
    int row = lane >> 2, dvb = (lane & 3) * 16;
    bf16x8 o0 = *(const bf16x8*)(ob + row * 64 + dvb);
    bf16x8 o1 = *(const bf16x8*)(ob + row * 64 + dvb + 8);
    size_t g = (obase + q0 + wave * 32 + f * 16 + row) * 64 + dvb;
    *(bf16x8*)(Op + g) = o0;
    *(bf16x8*)(Op + g + 8) = o1;
  }
  if (lane < 16) Rp[obase + q0 + wave * 32 + l16] = rsum[0];
  else if (lane < 32) Rp[obase + q0 + wave * 32 + 16 + l16] = rsum[1];
}

// ---------------- attention partial merge -> concat bf16 ----------------
__global__ __launch_bounds__(256) void attn_merge(const bf16* __restrict__ Op,
    const float* __restrict__ Rp, bf16* __restrict__ concat)
{
  int t = blockIdx.x * 256 + threadIdx.x;   // 32bh * 2048s * 16(dv4)
  int dv4 = t & 15, s = (t >> 4) & 2047, bh = t >> 15;
  float r = Rp[bh * 2048 + s] + Rp[65536 + bh * 2048 + s];
  float inv = 1.f / r;
  size_t ia = ((size_t)bh * 2048 + s) * 64 + dv4 * 4;
  bf16x4 a = *(const bf16x4*)(Op + ia);
  bf16x4 c = *(const bf16x4*)(Op + 4194304ull + ia);
  bf16x4 o;
  #pragma unroll
  for (int i = 0; i < 4; i++) o[i] = (bf16)(((float)a[i] + (float)c[i]) * inv);
  int b = bh >> 3, h = bh & 7;
  *(bf16x4*)(concat + ((size_t)(b * 2048 + s)) * 512 + h * 64 + dv4 * 4) = o;
}

// ---------------- GEMM 128x64 tile (weight-combine, Wo) ----------------
__global__ __launch_bounds__(256) void gemm_bt64(
    const bf16* __restrict__ A, const bf16* __restrict__ Bt,
    const float* __restrict__ bias, const float* __restrict__ res,
    float* __restrict__ outf, bf16* __restrict__ outb,
    int M, int N, int K, int relu)
{
  __shared__ bf16 As[128 * 32];
  __shared__ bf16 Bs[64 * 32];
  const int tid = threadIdx.x;
  const int wave = tid >> 6, lane = tid & 63, quad = lane >> 4, l16 = lane & 15;
  const int row0 = blockIdx.x * 128, col0 = blockIdx.y * 64;
  const int wm = wave >> 1, wn = wave & 1;
  f32x4 acc[4][2] = {};

  for (int kk = 0; kk < K; kk += 32) {
    __syncthreads();
    #pragma unroll
    for (int r = 0; r < 2; r++) {
      int c = r * 256 + tid;
      gload_lds16(A + (size_t)(row0 + (c >> 2)) * K + kk + (c & 3) * 8, As + c * 8);
    }
    {
      int c = tid;
      gload_lds16(Bt + (size_t)(col0 + (c >> 2)) * K + kk + (c & 3) * 8, Bs + c * 8);
    }
    __syncthreads();
    bf16x8 af[4], bfr[2];
    #pragma unroll
    for (int i = 0; i < 4; i++)
      af[i] = *(const bf16x8*)(As + (wm * 64 + i * 16 + l16) * 32 + quad * 8);
    #pragma unroll
    for (int i = 0; i < 2; i++)
      bfr[i] = *(const bf16x8*)(Bs + (wn * 32 + i * 16 + l16) * 32 + quad * 8);
    #pragma unroll
    for (int mt = 0; mt < 4; mt++)
      #pragma unroll
      for (int nt = 0; nt < 2; nt++)
        acc[mt][nt] = __builtin_amdgcn_mfma_f32_16x16x32_bf16(af[mt], bfr[nt], acc[mt][nt], 0, 0, 0);
  }

  #pragma unroll
  for (int nt = 0; nt < 2; nt++) {
    int col = col0 + wn * 32 + nt * 16 + l16;
    float bv = bias ? bias[col] : 0.f;
    #pragma unroll
    for (int mt = 0; mt < 4; mt++) {
      int rowb = row0 + wm * 64 + mt * 16 + quad * 4;
      #pragma unroll
      for (int i = 0; i < 4; i++) {
        size_t idx = (size_t)(rowb + i) * N + col;
        float v = acc[mt][nt][i] + bv;
        if (res) v += res[idx];
        if (relu) v = fmaxf(v, 0.f);
        if (outf) outf[idx] = v;
        if (outb) outb[idx] = (bf16)v;
      }
    }
  }
}

// ---------------- LayerNorm (ln1: fp32 in, fp32 + bf16 out) ----------------
__global__ __launch_bounds__(256) void ln_kernel(const float* __restrict__ in,
    const float* __restrict__ gamma, const float* __restrict__ beta,
    float* __restrict__ outf, bf16* __restrict__ outb, int relu)
{
  const int row = blockIdx.x * 4 + (threadIdx.x >> 6);
  const int lane = threadIdx.x & 63;
  const float4* p = (const float4*)(in + (size_t)row * 512);
  float4 v0 = p[lane];
  float4 v1 = p[lane + 64];
  float s = v0.x + v0.y + v0.z + v0.w + v1.x + v1.y + v1.z + v1.w;
  #pragma unroll
  for (int m = 1; m < 64; m <<= 1) s += __shfl_xor(s, m, 64);
  float mu = s * (1.f / 512.f);
  float d0 = v0.x - mu, d1 = v0.y - mu, d2 = v0.z - mu, d3 = v0.w - mu;
  float d4 = v1.x - mu, d5 = v1.y - mu, d6 = v1.z - mu, d7 = v1.w - mu;
  float q = d0*d0 + d1*d1 + d2*d2 + d3*d3 + d4*d4 + d5*d5 + d6*d6 + d7*d7;
  #pragma unroll
  for (int m = 1; m < 64; m <<= 1) q += __shfl_xor(q, m, 64);
  float rs = rsqrtf(q * (1.f / 512.f) + 1e-5f);
  const float4* gp = (const float4*)gamma;
  const float4* bp = (const float4*)beta;
  float4 g0 = gp[lane], g1 = gp[lane + 64];
  float4 b0 = bp[lane], b1 = bp[lane + 64];
  float y0 = d0 * rs * g0.x + b0.x, y1 = d1 * rs * g0.y + b0.y;
  float y2 = d2 * rs * g0.z + b0.z, y3 = d3 * rs * g0.w + b0.w;
  float y4 = d4 * rs * g1.x + b1.x, y5 = d5 * rs * g1.y + b1.y;
  float y6 = d6 * rs * g1.z + b1.z, y7 = d7 * rs * g1.w + b1.w;
  if (relu) {
    y0 = fmaxf(y0, 0.f); y1 = fmaxf(y1, 0.f); y2 = fmaxf(y2, 0.f); y3 = fmaxf(y3, 0.f);
    y4 = fmaxf(y4, 0.f); y5 = fmaxf(y5, 0.f); y6 = fmaxf(y6, 0.f); y7 = fmaxf(y7, 0.f);
  }
  float4* op = (float4*)(outf + (size_t)row * 512);
  float4 o0 = {y0, y1, y2, y3}, o1 = {y4, y5, y6, y7};
  op[lane] = o0;
  op[lane + 64] = o1;
  if (outb) {
    bf16x4 c0 = {(bf16)y0, (bf16)y1, (bf16)y2, (bf16)y3};
    bf16x4 c1 = {(bf16)y4, (bf16)y5, (bf16)y6, (bf16)y7};
    *(bf16x4*)(outb + (size_t)row * 512 + lane * 4) = c0;
    *(bf16x4*)(outb + (size_t)row * 512 + 256 + lane * 4) = c1;
  }
}

// ---------------- final LN: merges FFN2 partials + bias + residual, relu ----------------
__global__ __launch_bounds__(256) void ln_merge(const float* __restrict__ Pa,
    const float* __restrict__ Pb, const float* __restrict__ b2,
    const float* __restrict__ resid, const float* __restrict__ gamma,
    const float* __restrict__ beta, float* __restrict__ outf)
{
  const int row = blockIdx.x * 4 + (threadIdx.x >> 6);
  const int lane = threadIdx.x & 63;
  const size_t base = (size_t)row * 512;
  const float4* pa = (const float4*)(Pa + base);
  const float4* pb = (const float4*)(Pb + base);
  const float4* rr = (const float4*)(resid + base);
  const float4* bb = (const float4*)b2;
  float4 A0 = pa[lane], A1 = pa[lane + 64];
  float4 B0 = pb[lane], B1 = pb[lane + 64];
  float4 R0 = rr[lane], R1 = rr[lane + 64];
  float4 C0 = bb[lane], C1 = bb[lane + 64];
  float4 v0 = {A0.x+B0.x+R0.x+C0.x, A0.y+B0.y+R0.y+C0.y, A0.z+B0.z+R0.z+C0.z, A0.w+B0.w+R0.w+C0.w};
  float4 v1 = {A1.x+B1.x+R1.x+C1.x, A1.y+B1.y+R1.y+C1.y, A1.z+B1.z+R1.z+C1.z, A1.w+B1.w+R1.w+C1.w};
  float s = v0.x + v0.y + v0.z + v0.w + v1.x + v1.y + v1.z + v1.w;
  #pragma unroll
  for (int m = 1; m < 64; m <<= 1) s += __shfl_xor(s, m, 64);
  float mu = s * (1.f / 512.f);
  float d0 = v0.x - mu, d1 = v0.y - mu, d2 = v0.z - mu, d3 = v0.w - mu;
  float d4 = v1.x - mu, d5 = v1.y - mu, d6 = v1.z - mu, d7 = v1.w - mu;
  float q = d0*d0 + d1*d1 + d2*d2 + d3*d3 + d4*d4 + d5*d5 + d6*d6 + d7*d7;
  #pragma unroll
  for (int m = 1; m < 64; m <<= 1) q += __shfl_xor(q, m, 64);
  float rs = rsqrtf(q * (1.f / 512.f) + 1e-5f);
  const float4* gp = (const float4*)gamma;
  const float4* bp = (const float4*)beta;
  float4 g0 = gp[lane], g1 = gp[lane + 64];
  float4 b0 = bp[lane], b1 = bp[lane + 64];
  float4 o0 = {fmaxf(d0*rs*g0.x+b0.x,0.f), fmaxf(d1*rs*g0.y+b0.y,0.f),
               fmaxf(d2*rs*g0.z+b0.z,0.f), fmaxf(d3*rs*g0.w+b0.w,0.f)};
  float4 o1 = {fmaxf(d4*rs*g1.x+b1.x,0.f), fmaxf(d5*rs*g1.y+b1.y,0.f),
               fmaxf(d6*rs*g1.z+b1.z,0.f), fmaxf(d7*rs*g1.w+b1.w,0.f)};
  float4* op = (float4*)(outf + base);
  op[lane] = o0;
  op[lane + 64] = o1;
}

extern "C" void kernel_launch(void* const* d_in, const int* in_sizes, int n_in,
                              void* d_out, int out_size, void* d_ws, size_t ws_size,
                              hipStream_t stream)
{
  const int*   x    = (const int*)  d_in[0];
  const float* emb  = (const float*)d_in[1];
  const float* WfQ  = (const float*)d_in[2];
  const float* bfQv = (const float*)d_in[3];
  const float* WfK  = (const float*)d_in[4];
  const float* bfKv = (const float*)d_in[5];
  const float* WfV  = (const float*)d_in[6];
  const float* bfVv = (const float*)d_in[7];
  const float* WQ   = (const float*)d_in[8];
  const float* bQ   = (const float*)d_in[9];
  const float* WK   = (const float*)d_in[10];
  const float* bK   = (const float*)d_in[11];
  const float* WV   = (const float*)d_in[12];
  const float* bV   = (const float*)d_in[13];
  const float* Wo   = (const float*)d_in[14];
  const float* bo   = (const float*)d_in[15];
  const float* W1   = (const float*)d_in[16];
  const float* b1   = (const float*)d_in[17];
  const float* W2   = (const float*)d_in[18];
  const float* b2   = (const float*)d_in[19];
  const float* gamma= (const float*)d_in[20];
  const float* beta = (const float*)d_in[21];
  float* out = (float*)d_out;

  char* ws = (char*)d_ws;
  const size_t MB = 1024ull * 1024;
  float* zf   = (float*)(ws);              // z, then a (residuals, fp32)
  float* resf = (float*)(ws + 16 * MB);    // attn_out+z; later FFN2 partial A
  bf16*  bz   = (bf16*) (ws + 32 * MB);    // z bf16, then a bf16
  f16*   qkh  = (f16*)  (ws + 40 * MB);    // qk [8192][1024] f16 (16MB)
  f16*   Vt   = (f16*)  (ws + 56 * MB);    // V^T [32][64][2048] f16 (8MB)
  bf16*  ffn1 = (bf16*) (ws + 40 * MB);    // [8192][2048] bf16 (32MB), after flash
  bf16*  concat = (bf16*)(ws + 72 * MB);   // (8MB)
  bf16*  Op   = (bf16*) (ws + 80 * MB);    // flash O partials, 2 halves (16MB)
  float* Rp   = (float*)(ws + 96 * MB);    // row-sum partials (512KB)
  float* Pb   = (float*)(ws + 80 * MB);    // FFN2 partial B (reuses Op after merge)
  float* Pa   = resf;                      // FFN2 partial A (resf dead after ln1)
  char* wp = ws + 97 * MB;
  bf16* wfqp = (bf16*)(wp);
  bf16* wfkp = (bf16*)(wp + 512 * 1024);
  bf16* wfvp = (bf16*)(wp + 1024 * 1024);
  bf16* wqt  = (bf16*)(wp + 1536 * 1024);
  bf16* wkt  = (bf16*)(wp + 2048 * 1024);
  bf16* wvt  = (bf16*)(wp + 2560 * 1024);
  bf16* wc   = (bf16*)(wp + 3072 * 1024);
  bf16* wot  = (bf16*)(wp + 4608 * 1024);
  bf16* w1t  = (bf16*)(wp + 5120 * 1024);
  bf16* w2t  = (bf16*)(wp + 7168 * 1024);
  float* bc  = (float*)(wp + 9216 * 1024);

  conv_plain3<<<dim3(1024, 3), 256, 0, stream>>>(WfQ, WfK, WfV, wfqp, wfkp, wfvp);
  conv_t_heads<<<dim3(1024, 3), 256, 0, stream>>>(WQ, WK, WV, wqt, wkt, wvt);
  conv_t3<<<dim3(4096, 3), 256, 0, stream>>>(Wo, W1, W2, wot, w1t, w2t);
  bias_comb<<<384, 256, 0, stream>>>(bfQv, bfKv, bfVv, WQ, WK, WV, bQ, bK, bV, bc);

  dim3 gcomb(4, 8);
  gemm_bt64<<<gcomb, 256, 0, stream>>>(wqt, wfqp, nullptr, nullptr, nullptr, wc,          512, 512, 512, 0);
  gemm_bt64<<<gcomb, 256, 0, stream>>>(wkt, wfkp, nullptr, nullptr, nullptr, wc + 262144, 512, 512, 512, 0);
  gemm_bt64<<<gcomb, 256, 0, stream>>>(wvt, wfvp, nullptr, nullptr, nullptr, wc + 524288, 512, 512, 512, 0);

  embed_pe<<<8192, 256, 0, stream>>>(x, emb, zf, bz);

  gemm_qkv<<<dim3(64, 12), 256, 0, stream>>>(bz, wc, bc, qkh, Vt);
  flash_attn<<<dim3(16, 32, 2), 256, 0, stream>>>(qkh, Vt, Op, Rp);
  attn_merge<<<4096, 256, 0, stream>>>(Op, Rp, concat);

  gemm_bt64<<<dim3(64, 8), 256, 0, stream>>>(concat, wot, bo, zf, resf, nullptr, 8192, 512, 512, 0);
  ln_kernel<<<2048, 256, 0, stream>>>(resf, gamma, beta, zf, bz, 0);
  gemm_bt<<<dim3(64, 16), 256, 0, stream>>>(bz, w1t, b1, nullptr, nullptr, ffn1, 8192, 2048, 512, 1);
  gemm_part<<<dim3(64, 4, 2), 256, 0, stream>>>(ffn1, w2t, Pa, Pb, 512, 2048, 1024);
  ln_merge<<<2048, 256, 0, stream>>>(Pa, Pb, b2, zf, gamma, beta, out);
}

// Round 5
// 399.473 us; speedup vs baseline: 1.4401x; 1.0223x over previous
//
#include <hip/hip_runtime.h>
#include <math.h>

typedef __bf16 bf16;
typedef __bf16 bf16x8 __attribute__((ext_vector_type(8)));
typedef __bf16 bf16x4 __attribute__((ext_vector_type(4)));
typedef _Float16 f16;
typedef _Float16 f16x8 __attribute__((ext_vector_type(8)));
typedef _Float16 f16x4 __attribute__((ext_vector_type(4)));
typedef float f32x4 __attribute__((ext_vector_type(4)));
typedef unsigned int u32;

#define S_LEN 2048
#define QSCALE 0.18033688011112042f   // (1/8)*log2(e), folded into Q weights+bias
#define FIXEDMAX 8.0f

__device__ __forceinline__ void gload_lds16(const void* g, void* l) {
  __builtin_amdgcn_global_load_lds((const __attribute__((address_space(1))) u32*)g,
                                   (__attribute__((address_space(3))) u32*)l, 16, 0, 0);
}

// ---------------- embedding + sinusoidal PE ----------------
__global__ __launch_bounds__(256) void embed_pe(const int* __restrict__ x,
    const float* __restrict__ emb, float* __restrict__ zf, bf16* __restrict__ zb)
{
  const int row = blockIdx.x;
  const int s = row & (S_LEN - 1);
  const int tok = x[row];
  const float* e = emb + (size_t)tok * 512;
  float* zr = zf + (size_t)row * 512;
  bf16* zbr = zb + (size_t)row * 512;
  for (int i = threadIdx.x; i < 512; i += 256) {
    float invf = __expf((float)i * (-9.210340371976184f / 512.0f));
    float ang = (float)s * invf;
    float pe = (i & 1) ? __cosf(ang) : __sinf(ang);
    float v = e[i] + pe;
    zr[i] = v;
    zbr[i] = (bf16)v;
  }
}

// ---------------- all weight conversions in one launch ----------------
// y=0..2: WfQ/K/V plain fp32->bf16 (256K elems each)
// y=3..5: WQ/WK/WV [8][512][64] -> [8][64][512] transpose (Q scaled)
// y=6: Wo^T (256K); y=7: W1^T (1M); y=8: W2^T (1M)
__global__ __launch_bounds__(256) void conv_all(
    const float* __restrict__ WfQ, const float* __restrict__ WfK, const float* __restrict__ WfV,
    const float* __restrict__ WQ, const float* __restrict__ WK, const float* __restrict__ WV,
    const float* __restrict__ Wo, const float* __restrict__ W1, const float* __restrict__ W2,
    bf16* __restrict__ wfqp, bf16* __restrict__ wfkp, bf16* __restrict__ wfvp,
    bf16* __restrict__ wqt, bf16* __restrict__ wkt, bf16* __restrict__ wvt,
    bf16* __restrict__ wot, bf16* __restrict__ w1t, bf16* __restrict__ w2t)
{
  int gid = blockIdx.x * 256 + threadIdx.x;
  int y = blockIdx.y;
  if (y < 3) {
    if (gid >= 262144) return;
    const float* in = y == 0 ? WfQ : (y == 1 ? WfK : WfV);
    bf16* out = y == 0 ? wfqp : (y == 1 ? wfkp : wfvp);
    out[gid] = (bf16)in[gid];
  } else if (y < 6) {
    if (gid >= 262144) return;
    const float* in = y == 3 ? WQ : (y == 4 ? WK : WV);
    bf16* out = y == 3 ? wqt : (y == 4 ? wkt : wvt);
    float scale = y == 3 ? QSCALE : 1.0f;
    int r = gid & 511, t = gid >> 9, c = t & 63, h = t >> 6;
    out[gid] = (bf16)(in[((size_t)(h * 512 + r)) * 64 + c] * scale);
  } else if (y == 6) {
    if (gid >= 262144) return;
    int r = gid & 511, c = gid >> 9;
    wot[gid] = (bf16)Wo[r * 512 + c];
  } else if (y == 7) {
    int r = gid & 511, c = gid >> 9;
    w1t[gid] = (bf16)W1[r * 2048 + c];
  } else {
    int r = gid & 2047, c = gid >> 11;
    w2t[gid] = (bf16)W2[r * 512 + c];
  }
}

// ---------------- combined bias ----------------
__global__ __launch_bounds__(256) void bias_comb(
    const float* __restrict__ bfQ, const float* __restrict__ bfK, const float* __restrict__ bfV,
    const float* __restrict__ WQ, const float* __restrict__ WK, const float* __restrict__ WV,
    const float* __restrict__ bQ, const float* __restrict__ bK, const float* __restrict__ bV,
    float* __restrict__ bc)
{
  int n = blockIdx.x * 4 + (threadIdx.x >> 6);
  int lane = threadIdx.x & 63;
  int z = n >> 9, hk = n & 511, h = hk >> 6, k = hk & 63;
  const float* bf = z == 0 ? bfQ : (z == 1 ? bfK : bfV);
  const float* W  = z == 0 ? WQ  : (z == 1 ? WK  : WV);
  const float* bH = z == 0 ? bQ  : (z == 1 ? bK  : bV);
  float s = 0.f;
  for (int e = lane; e < 512; e += 64)
    s += bf[e] * W[((size_t)h * 512 + e) * 64 + k];
  #pragma unroll
  for (int m = 1; m < 64; m <<= 1) s += __shfl_xor(s, m, 64);
  if (lane == 0) {
    float v = s + bH[h * 64 + k];
    if (z == 0) v *= QSCALE;
    bc[n] = v;
  }
}

// ---------------- weight-combine GEMMs (3 in one launch, 128x64 tiles) ----------------
__global__ __launch_bounds__(256) void gemm_comb(
    const bf16* __restrict__ wqt, const bf16* __restrict__ wkt, const bf16* __restrict__ wvt,
    const bf16* __restrict__ wfqp, const bf16* __restrict__ wfkp, const bf16* __restrict__ wfvp,
    bf16* __restrict__ wc)
{
  __shared__ bf16 As[128 * 32];
  __shared__ bf16 Bs[64 * 32];
  const int z = blockIdx.z;
  const bf16* A  = z == 0 ? wqt : (z == 1 ? wkt : wvt);
  const bf16* Bt = z == 0 ? wfqp : (z == 1 ? wfkp : wfvp);
  bf16* outb = wc + (size_t)z * 262144;
  const int tid = threadIdx.x;
  const int wave = tid >> 6, lane = tid & 63, quad = lane >> 4, l16 = lane & 15;
  const int row0 = blockIdx.x * 128, col0 = blockIdx.y * 64;
  const int wm = wave >> 1, wn = wave & 1;
  f32x4 acc[4][2] = {};

  for (int kk = 0; kk < 512; kk += 32) {
    __syncthreads();
    #pragma unroll
    for (int r = 0; r < 2; r++) {
      int c = r * 256 + tid;
      gload_lds16(A + (size_t)(row0 + (c >> 2)) * 512 + kk + (c & 3) * 8, As + c * 8);
    }
    gload_lds16(Bt + (size_t)(col0 + (tid >> 2)) * 512 + kk + (tid & 3) * 8, Bs + tid * 8);
    __syncthreads();
    bf16x8 af[4], bfr[2];
    #pragma unroll
    for (int i = 0; i < 4; i++)
      af[i] = *(const bf16x8*)(As + (wm * 64 + i * 16 + l16) * 32 + quad * 8);
    #pragma unroll
    for (int i = 0; i < 2; i++)
      bfr[i] = *(const bf16x8*)(Bs + (wn * 32 + i * 16 + l16) * 32 + quad * 8);
    #pragma unroll
    for (int mt = 0; mt < 4; mt++)
      #pragma unroll
      for (int nt = 0; nt < 2; nt++)
        acc[mt][nt] = __builtin_amdgcn_mfma_f32_16x16x32_bf16(af[mt], bfr[nt], acc[mt][nt], 0, 0, 0);
  }
  #pragma unroll
  for (int nt = 0; nt < 2; nt++) {
    int col = col0 + wn * 32 + nt * 16 + l16;
    #pragma unroll
    for (int mt = 0; mt < 4; mt++) {
      int rowb = row0 + wm * 64 + mt * 16 + quad * 4;
      #pragma unroll
      for (int i = 0; i < 4; i++)
        outb[(size_t)(rowb + i) * 512 + col] = (bf16)acc[mt][nt][i];
    }
  }
}

// ---------------- GEMM 128x128 tile (bf16 out; FFN1) ----------------
__global__ __launch_bounds__(256) void gemm_bt(
    const bf16* __restrict__ A, const bf16* __restrict__ Bt,
    const float* __restrict__ bias, bf16* __restrict__ outb,
    int M, int N, int K, int relu)
{
  __shared__ bf16 As[128 * 32];
  __shared__ bf16 Bs[128 * 32];
  const int tid = threadIdx.x;
  const int wave = tid >> 6, lane = tid & 63, quad = lane >> 4, l16 = lane & 15;
  const int row0 = blockIdx.x * 128, col0 = blockIdx.y * 128;
  const int wm = wave >> 1, wn = wave & 1;
  f32x4 acc[4][4] = {};

  for (int kk = 0; kk < K; kk += 32) {
    __syncthreads();
    #pragma unroll
    for (int r = 0; r < 2; r++) {
      int c = r * 256 + tid;
      gload_lds16(A + (size_t)(row0 + (c >> 2)) * K + kk + (c & 3) * 8, As + c * 8);
    }
    #pragma unroll
    for (int r = 0; r < 2; r++) {
      int c = r * 256 + tid;
      gload_lds16(Bt + (size_t)(col0 + (c >> 2)) * K + kk + (c & 3) * 8, Bs + c * 8);
    }
    __syncthreads();
    bf16x8 af[4], bfr[4];
    #pragma unroll
    for (int i = 0; i < 4; i++)
      af[i] = *(const bf16x8*)(As + (wm * 64 + i * 16 + l16) * 32 + quad * 8);
    #pragma unroll
    for (int i = 0; i < 4; i++)
      bfr[i] = *(const bf16x8*)(Bs + (wn * 64 + i * 16 + l16) * 32 + quad * 8);
    #pragma unroll
    for (int mt = 0; mt < 4; mt++)
      #pragma unroll
      for (int nt = 0; nt < 4; nt++)
        acc[mt][nt] = __builtin_amdgcn_mfma_f32_16x16x32_bf16(af[mt], bfr[nt], acc[mt][nt], 0, 0, 0);
  }

  #pragma unroll
  for (int nt = 0; nt < 4; nt++) {
    int col = col0 + wn * 64 + nt * 16 + l16;
    float bv = bias[col];
    #pragma unroll
    for (int mt = 0; mt < 4; mt++) {
      int rowb = row0 + wm * 64 + mt * 16 + quad * 4;
      #pragma unroll
      for (int i = 0; i < 4; i++) {
        float v = acc[mt][nt][i] + bv;
        if (relu) v = fmaxf(v, 0.f);
        outb[(size_t)(rowb + i) * N + col] = (bf16)v;
      }
    }
  }
}

// ---------------- QKV GEMM: N=1536, writes qk f16[row][1024] + Vt f16[bh][dv][2048] ----------------
__global__ __launch_bounds__(256) void gemm_qkv(
    const bf16* __restrict__ A, const bf16* __restrict__ Bt,
    const float* __restrict__ bias, f16* __restrict__ qk, f16* __restrict__ Vt)
{
  __shared__ bf16 As[128 * 32];
  __shared__ bf16 Bs[128 * 32];
  const int tid = threadIdx.x;
  const int wave = tid >> 6, lane = tid & 63, quad = lane >> 4, l16 = lane & 15;
  const int row0 = blockIdx.x * 128, col0 = blockIdx.y * 128;
  const int wm = wave >> 1, wn = wave & 1;
  f32x4 acc[4][4] = {};

  for (int kk = 0; kk < 512; kk += 32) {
    __syncthreads();
    #pragma unroll
    for (int r = 0; r < 2; r++) {
      int c = r * 256 + tid;
      gload_lds16(A + (size_t)(row0 + (c >> 2)) * 512 + kk + (c & 3) * 8, As + c * 8);
    }
    #pragma unroll
    for (int r = 0; r < 2; r++) {
      int c = r * 256 + tid;
      gload_lds16(Bt + (size_t)(col0 + (c >> 2)) * 512 + kk + (c & 3) * 8, Bs + c * 8);
    }
    __syncthreads();
    bf16x8 af[4], bfr[4];
    #pragma unroll
    for (int i = 0; i < 4; i++)
      af[i] = *(const bf16x8*)(As + (wm * 64 + i * 16 + l16) * 32 + quad * 8);
    #pragma unroll
    for (int i = 0; i < 4; i++)
      bfr[i] = *(const bf16x8*)(Bs + (wn * 64 + i * 16 + l16) * 32 + quad * 8);
    #pragma unroll
    for (int mt = 0; mt < 4; mt++)
      #pragma unroll
      for (int nt = 0; nt < 4; nt++)
        acc[mt][nt] = __builtin_amdgcn_mfma_f32_16x16x32_bf16(af[mt], bfr[nt], acc[mt][nt], 0, 0, 0);
  }

  #pragma unroll
  for (int nt = 0; nt < 4; nt++) {
    int col = col0 + wn * 64 + nt * 16 + l16;
    float bv = bias[col];
    if (col < 1024) {
      #pragma unroll
      for (int mt = 0; mt < 4; mt++) {
        int rowb = row0 + wm * 64 + mt * 16 + quad * 4;
        #pragma unroll
        for (int i = 0; i < 4; i++)
          qk[(size_t)(rowb + i) * 1024 + col] = (f16)(acc[mt][nt][i] + bv);
      }
    } else {
      int h = (col - 1024) >> 6, dv = col & 63;
      #pragma unroll
      for (int mt = 0; mt < 4; mt++) {
        int rowb = row0 + wm * 64 + mt * 16 + quad * 4;
        int b = rowb >> 11, s = rowb & 2047;
        f16x4 vv;
        #pragma unroll
        for (int i = 0; i < 4; i++) vv[i] = (f16)(acc[mt][nt][i] + bv);
        *(f16x4*)(Vt + ((size_t)((b * 8 + h) * 64 + dv)) * 2048 + s) = vv;
      }
    }
  }
}

// ---------------- split-K partial GEMM (raw f32 partials, no epilogue) ----------------
__global__ __launch_bounds__(256) void gemm_part(
    const bf16* __restrict__ A, const bf16* __restrict__ Bt,
    float* __restrict__ Pa, float* __restrict__ Pb, int N, int K, int Kh)
{
  __shared__ bf16 As[128 * 32];
  __shared__ bf16 Bs[128 * 32];
  const int tid = threadIdx.x;
  const int wave = tid >> 6, lane = tid & 63, quad = lane >> 4, l16 = lane & 15;
  const int row0 = blockIdx.x * 128, col0 = blockIdx.y * 128;
  const int wm = wave >> 1, wn = wave & 1;
  const int kk0 = blockIdx.z * Kh;
  float* P = blockIdx.z ? Pb : Pa;
  f32x4 acc[4][4] = {};

  for (int kk = kk0; kk < kk0 + Kh; kk += 32) {
    __syncthreads();
    #pragma unroll
    for (int r = 0; r < 2; r++) {
      int c = r * 256 + tid;
      gload_lds16(A + (size_t)(row0 + (c >> 2)) * K + kk + (c & 3) * 8, As + c * 8);
    }
    #pragma unroll
    for (int r = 0; r < 2; r++) {
      int c = r * 256 + tid;
      gload_lds16(Bt + (size_t)(col0 + (c >> 2)) * K + kk + (c & 3) * 8, Bs + c * 8);
    }
    __syncthreads();
    bf16x8 af[4], bfr[4];
    #pragma unroll
    for (int i = 0; i < 4; i++)
      af[i] = *(const bf16x8*)(As + (wm * 64 + i * 16 + l16) * 32 + quad * 8);
    #pragma unroll
    for (int i = 0; i < 4; i++)
      bfr[i] = *(const bf16x8*)(Bs + (wn * 64 + i * 16 + l16) * 32 + quad * 8);
    #pragma unroll
    for (int mt = 0; mt < 4; mt++)
      #pragma unroll
      for (int nt = 0; nt < 4; nt++)
        acc[mt][nt] = __builtin_amdgcn_mfma_f32_16x16x32_bf16(af[mt], bfr[nt], acc[mt][nt], 0, 0, 0);
  }

  #pragma unroll
  for (int nt = 0; nt < 4; nt++) {
    int col = col0 + wn * 64 + nt * 16 + l16;
    #pragma unroll
    for (int mt = 0; mt < 4; mt++) {
      int rowb = row0 + wm * 64 + mt * 16 + quad * 4;
      #pragma unroll
      for (int i = 0; i < 4; i++)
        P[(size_t)(rowb + i) * N + col] = acc[mt][nt][i];
    }
  }
}

// ---------------- flash attention: 64 q/wave, split-K 4, dbuf LDS, 1 barrier/chunk ----------------
// qk: [8192][1024] f16; Vt: [32 bh][64 dv][2048 s] f16. Grid (8 qtile, 32 bh, 4 quarter).
__global__ __launch_bounds__(256) void flash_attn(
    const f16* __restrict__ qk, const f16* __restrict__ Vt,
    bf16* __restrict__ Op, float* __restrict__ Rp)
{
  __shared__ f16 Ks[2][4096];   // [key][dk], 16B chunks XOR-swizzled by row&7
  __shared__ f16 Vs[2][4096];   // [dv][key], same swizzle
  const int bh = blockIdx.y, b = bh >> 3, h = bh & 7;
  const int q0 = blockIdx.x * 256;
  const int quarter = blockIdx.z;
  const int tid = threadIdx.x;
  const int wave = tid >> 6, lane = tid & 63, quad = lane >> 4, l16 = lane & 15;

  const f16* Qb = qk + ((size_t)b * S_LEN) * 1024 + h * 64;
  const f16* Kb = Qb + 512;
  const f16* Vtb = Vt + ((size_t)bh * 64) * 2048;
  const int key0 = quarter * 512;

  f16x8 qf[4][2];   // 4 q-fragments of 16; B[n=q=l16][k=dk=quad*8+j(+32)]
  #pragma unroll
  for (int f = 0; f < 4; f++) {
    int qrow = q0 + wave * 64 + f * 16 + l16;
    #pragma unroll
    for (int kh = 0; kh < 2; kh++)
      qf[f][kh] = *(const f16x8*)(Qb + (size_t)qrow * 1024 + kh * 32 + quad * 8);
  }

  f32x4 O[4][4] = {};            // [f][mt]: O^T row=dv, col=q
  float rsum[4] = {0.f, 0.f, 0.f, 0.f};
  const int swz = l16 & 7;

  f16x8 kreg[2], vreg[2];
  const int srow = tid >> 3, soff = tid & 7;
  const int srow1 = srow + 32;

  {
    int kb = key0;
    kreg[0] = *(const f16x8*)(Kb + (size_t)(kb + srow) * 1024 + soff * 8);
    vreg[0] = *(const f16x8*)(Vtb + (size_t)srow * 2048 + kb + soff * 8);
    kreg[1] = *(const f16x8*)(Kb + (size_t)(kb + srow1) * 1024 + soff * 8);
    vreg[1] = *(const f16x8*)(Vtb + (size_t)srow1 * 2048 + kb + soff * 8);
  }

  for (int c = 0; c < 8; c++) {
    f16* KsB = Ks[c & 1];
    f16* VsB = Vs[c & 1];
    *(f16x8*)(KsB + srow * 64 + ((soff ^ (srow & 7)) * 8)) = kreg[0];
    *(f16x8*)(VsB + srow * 64 + ((soff ^ (srow & 7)) * 8)) = vreg[0];
    *(f16x8*)(KsB + srow1 * 64 + ((soff ^ (srow1 & 7)) * 8)) = kreg[1];
    *(f16x8*)(VsB + srow1 * 64 + ((soff ^ (srow1 & 7)) * 8)) = vreg[1];
    __syncthreads();
    if (c < 7) {
      int kb = key0 + (c + 1) * 64;
      kreg[0] = *(const f16x8*)(Kb + (size_t)(kb + srow) * 1024 + soff * 8);
      vreg[0] = *(const f16x8*)(Vtb + (size_t)srow * 2048 + kb + soff * 8);
      kreg[1] = *(const f16x8*)(Kb + (size_t)(kb + srow1) * 1024 + soff * 8);
      vreg[1] = *(const f16x8*)(Vtb + (size_t)srow1 * 2048 + kb + soff * 8);
    }

    #pragma unroll
    for (int nt = 0; nt < 4; nt++) {
      const f16* kp = KsB + (nt * 16 + l16) * 64;
      f16x8 kf0 = *(const f16x8*)(kp + ((quad ^ swz) * 8));
      f16x8 kf1 = *(const f16x8*)(kp + (((4 + quad) ^ swz) * 8));
      f16x4 pf[4];
      #pragma unroll
      for (int f = 0; f < 4; f++) {
        f32x4 a = {};
        a = __builtin_amdgcn_mfma_f32_16x16x32_f16(kf0, qf[f][0], a, 0, 0, 0);
        a = __builtin_amdgcn_mfma_f32_16x16x32_f16(kf1, qf[f][1], a, 0, 0, 0);
        #pragma unroll
        for (int i = 0; i < 4; i++) {
          float p = exp2f(a[i] - FIXEDMAX);
          rsum[f] += p;
          pf[f][i] = (f16)p;
        }
      }
      int vchunk = nt * 2 + (quad >> 1);
      #pragma unroll
      for (int mt = 0; mt < 4; mt++) {
        const f16* vp = VsB + (mt * 16 + l16) * 64 + ((vchunk ^ swz) * 8) + (quad & 1) * 4;
        f16x4 vf = *(const f16x4*)vp;
        #pragma unroll
        for (int f = 0; f < 4; f++)
          O[f][mt] = __builtin_amdgcn_mfma_f32_16x16x16f16(vf, pf[f], O[f][mt], 0, 0, 0);
      }
    }
  }

  #pragma unroll
  for (int f = 0; f < 4; f++) {
    rsum[f] += __shfl_xor(rsum[f], 16, 64);
    rsum[f] += __shfl_xor(rsum[f], 32, 64);
  }

  // store un-normalized partials (transpose through per-wave LDS regions)
  __syncthreads();
  bf16* bufs[4] = {(bf16*)&Ks[0][0], (bf16*)&Ks[1][0], (bf16*)&Vs[0][0], (bf16*)&Vs[1][0]};
  #pragma unroll
  for (int f = 0; f < 4; f++) {
    bf16* ob = bufs[f] + wave * 1024;
    #pragma unroll
    for (int mt = 0; mt < 4; mt++)
      #pragma unroll
      for (int i = 0; i < 4; i++)
        ob[l16 * 64 + mt * 16 + quad * 4 + i] = (bf16)O[f][mt][i];
  }
  asm volatile("s_waitcnt lgkmcnt(0)" ::: "memory");
  const size_t qbase = (size_t)(quarter * 32 + bh) * 2048 + q0;
  #pragma unroll
  for (int f = 0; f < 4; f++) {
    bf16* ob = bufs[f] + wave * 1024;
    int row = lane >> 2, dvb = (lane & 3) * 16;
    bf16x8 o0 = *(const bf16x8*)(ob + row * 64 + dvb);
    bf16x8 o1 = *(const bf16x8*)(ob + row * 64 + dvb + 8);
    size_t g = (qbase + wave * 64 + f * 16 + row) * 64 + dvb;
    *(bf16x8*)(Op + g) = o0;
    *(bf16x8*)(Op + g + 8) = o1;
    if (quad == f)
      Rp[qbase + wave * 64 + f * 16 + l16] = rsum[f];
  }
}

// ---------------- attention partial merge (4-way) -> concat bf16 ----------------
__global__ __launch_bounds__(256) void attn_merge(const bf16* __restrict__ Op,
    const float* __restrict__ Rp, bf16* __restrict__ concat)
{
  int t = blockIdx.x * 256 + threadIdx.x;   // 32bh * 2048s * 16(dv4)
  int dv4 = t & 15, s = (t >> 4) & 2047, bh = t >> 15;
  int rb = bh * 2048 + s;
  float r = Rp[rb] + Rp[65536 + rb] + Rp[131072 + rb] + Rp[196608 + rb];
  float inv = 1.f / r;
  size_t ia = ((size_t)bh * 2048 + s) * 64 + dv4 * 4;
  bf16x4 p0 = *(const bf16x4*)(Op + ia);
  bf16x4 p1 = *(const bf16x4*)(Op + 4194304ull + ia);
  bf16x4 p2 = *(const bf16x4*)(Op + 8388608ull + ia);
  bf16x4 p3 = *(const bf16x4*)(Op + 12582912ull + ia);
  bf16x4 o;
  #pragma unroll
  for (int i = 0; i < 4; i++)
    o[i] = (bf16)((((float)p0[i] + (float)p1[i]) + ((float)p2[i] + (float)p3[i])) * inv);
  int b = bh >> 3, h = bh & 7;
  *(bf16x4*)(concat + ((size_t)(b * 2048 + s)) * 512 + h * 64 + dv4 * 4) = o;
}

// ---------------- LN with partial merge: (Pa+Pb+badd+resid) -> LN -> outf(+outb)(+relu) ----------------
__global__ __launch_bounds__(256) void ln_merge(const float* __restrict__ Pa,
    const float* __restrict__ Pb, const float* __restrict__ badd,
    const float* __restrict__ resid, const float* __restrict__ gamma,
    const float* __restrict__ beta, float* __restrict__ outf,
    bf16* __restrict__ outb, int relu)
{
  const int row = blockIdx.x * 4 + (threadIdx.x >> 6);
  const int lane = threadIdx.x & 63;
  const size_t base = (size_t)row * 512;
  const float4* pa = (const float4*)(Pa + base);
  const float4* pb = (const float4*)(Pb + base);
  const float4* rr = (const float4*)(resid + base);
  const float4* bb = (const float4*)badd;
  float4 A0 = pa[lane], A1 = pa[lane + 64];
  float4 B0 = pb[lane], B1 = pb[lane + 64];
  float4 R0 = rr[lane], R1 = rr[lane + 64];
  float4 C0 = bb[lane], C1 = bb[lane + 64];
  float4 v0 = {A0.x+B0.x+R0.x+C0.x, A0.y+B0.y+R0.y+C0.y, A0.z+B0.z+R0.z+C0.z, A0.w+B0.w+R0.w+C0.w};
  float4 v1 = {A1.x+B1.x+R1.x+C1.x, A1.y+B1.y+R1.y+C1.y, A1.z+B1.z+R1.z+C1.z, A1.w+B1.w+R1.w+C1.w};
  float s = v0.x + v0.y + v0.z + v0.w + v1.x + v1.y + v1.z + v1.w;
  #pragma unroll
  for (int m = 1; m < 64; m <<= 1) s += __shfl_xor(s, m, 64);
  float mu = s * (1.f / 512.f);
  float d0 = v0.x - mu, d1 = v0.y - mu, d2 = v0.z - mu, d3 = v0.w - mu;
  float d4 = v1.x - mu, d5 = v1.y - mu, d6 = v1.z - mu, d7 = v1.w - mu;
  float q = d0*d0 + d1*d1 + d2*d2 + d3*d3 + d4*d4 + d5*d5 + d6*d6 + d7*d7;
  #pragma unroll
  for (int m = 1; m < 64; m <<= 1) q += __shfl_xor(q, m, 64);
  float rs = rsqrtf(q * (1.f / 512.f) + 1e-5f);
  const float4* gp = (const float4*)gamma;
  const float4* bp = (const float4*)beta;
  float4 g0 = gp[lane], g1 = gp[lane + 64];
  float4 b0 = bp[lane], b1 = bp[lane + 64];
  float y0 = d0 * rs * g0.x + b0.x, y1 = d1 * rs * g0.y + b0.y;
  float y2 = d2 * rs * g0.z + b0.z, y3 = d3 * rs * g0.w + b0.w;
  float y4 = d4 * rs * g1.x + b1.x, y5 = d5 * rs * g1.y + b1.y;
  float y6 = d6 * rs * g1.z + b1.z, y7 = d7 * rs * g1.w + b1.w;
  if (relu) {
    y0 = fmaxf(y0, 0.f); y1 = fmaxf(y1, 0.f); y2 = fmaxf(y2, 0.f); y3 = fmaxf(y3, 0.f);
    y4 = fmaxf(y4, 0.f); y5 = fmaxf(y5, 0.f); y6 = fmaxf(y6, 0.f); y7 = fmaxf(y7, 0.f);
  }
  float4* op = (float4*)(outf + base);
  float4 o0 = {y0, y1, y2, y3}, o1 = {y4, y5, y6, y7};
  op[lane] = o0;
  op[lane + 64] = o1;
  if (outb) {
    bf16x4 c0 = {(bf16)y0, (bf16)y1, (bf16)y2, (bf16)y3};
    bf16x4 c1 = {(bf16)y4, (bf16)y5, (bf16)y6, (bf16)y7};
    *(bf16x4*)(outb + base + lane * 4) = c0;
    *(bf16x4*)(outb + base + 256 + lane * 4) = c1;
  }
}

extern "C" void kernel_launch(void* const* d_in, const int* in_sizes, int n_in,
                              void* d_out, int out_size, void* d_ws, size_t ws_size,
                              hipStream_t stream)
{
  const int*   x    = (const int*)  d_in[0];
  const float* emb  = (const float*)d_in[1];
  const float* WfQ  = (const float*)d_in[2];
  const float* bfQv = (const float*)d_in[3];
  const float* WfK  = (const float*)d_in[4];
  const float* bfKv = (const float*)d_in[5];
  const float* WfV  = (const float*)d_in[6];
  const float* bfVv = (const float*)d_in[7];
  const float* WQ   = (const float*)d_in[8];
  const float* bQ   = (const float*)d_in[9];
  const float* WK   = (const float*)d_in[10];
  const float* bK   = (const float*)d_in[11];
  const float* WV   = (const float*)d_in[12];
  const float* bV   = (const float*)d_in[13];
  const float* Wo   = (const float*)d_in[14];
  const float* bo   = (const float*)d_in[15];
  const float* W1   = (const float*)d_in[16];
  const float* b1   = (const float*)d_in[17];
  const float* W2   = (const float*)d_in[18];
  const float* b2   = (const float*)d_in[19];
  const float* gamma= (const float*)d_in[20];
  const float* beta = (const float*)d_in[21];
  float* out = (float*)d_out;

  char* ws = (char*)d_ws;
  const size_t MB = 1024ull * 1024;
  // layout (sequential reuse):
  float* zf   = (float*)(ws);              // 0-16: z fp32, then a fp32 (in-place LN)
  bf16*  bz   = (bf16*) (ws + 16 * MB);    // 16-24: z bf16, then a bf16
  f16*   qkh  = (f16*)  (ws + 24 * MB);    // 24-40: qk f16 (dead after flash)
  f16*   Vt   = (f16*)  (ws + 40 * MB);    // 40-48: V^T f16 (dead after flash)
  bf16*  Op   = (bf16*) (ws + 48 * MB);    // 48-80: flash O partials x4 (dead after merge)
  float* Rp   = (float*)(ws + 80 * MB);    // 80-81: row sums x4
  bf16*  concat = (bf16*)(ws + 82 * MB);   // 82-90 (dead after Wo)
  float* PaW  = (float*)(ws + 48 * MB);    // Wo partials reuse Op region
  float* PbW  = (float*)(ws + 64 * MB);
  bf16*  ffn1 = (bf16*) (ws + 24 * MB);    // 24-56 (after ln1)
  float* Pa2  = (float*)(ws + 56 * MB);    // FFN2 partials 56-88
  float* Pb2  = (float*)(ws + 72 * MB);
  char* wp = ws + 90 * MB;
  bf16* wfqp = (bf16*)(wp);
  bf16* wfkp = (bf16*)(wp + 512 * 1024);
  bf16* wfvp = (bf16*)(wp + 1024 * 1024);
  bf16* wqt  = (bf16*)(wp + 1536 * 1024);
  bf16* wkt  = (bf16*)(wp + 2048 * 1024);
  bf16* wvt  = (bf16*)(wp + 2560 * 1024);
  bf16* wc   = (bf16*)(wp + 3072 * 1024);  // [1536][512]
  bf16* wot  = (bf16*)(wp + 4608 * 1024);
  bf16* w1t  = (bf16*)(wp + 5120 * 1024);
  bf16* w2t  = (bf16*)(wp + 7168 * 1024);
  float* bc  = (float*)(wp + 9216 * 1024);

  conv_all<<<dim3(4096, 9), 256, 0, stream>>>(WfQ, WfK, WfV, WQ, WK, WV, Wo, W1, W2,
                                              wfqp, wfkp, wfvp, wqt, wkt, wvt, wot, w1t, w2t);
  bias_comb<<<384, 256, 0, stream>>>(bfQv, bfKv, bfVv, WQ, WK, WV, bQ, bK, bV, bc);
  gemm_comb<<<dim3(4, 8, 3), 256, 0, stream>>>(wqt, wkt, wvt, wfqp, wfkp, wfvp, wc);

  embed_pe<<<8192, 256, 0, stream>>>(x, emb, zf, bz);

  gemm_qkv<<<dim3(64, 12), 256, 0, stream>>>(bz, wc, bc, qkh, Vt);
  flash_attn<<<dim3(8, 32, 4), 256, 0, stream>>>(qkh, Vt, Op, Rp);
  attn_merge<<<4096, 256, 0, stream>>>(Op, Rp, concat);

  gemm_part<<<dim3(64, 4, 2), 256, 0, stream>>>(concat, wot, PaW, PbW, 512, 512, 256);
  ln_merge<<<2048, 256, 0, stream>>>(PaW, PbW, bo, zf, gamma, beta, zf, bz, 0);
  gemm_bt<<<dim3(64, 16), 256, 0, stream>>>(bz, w1t, b1, ffn1, 8192, 2048, 512, 1);
  gemm_part<<<dim3(64, 4, 2), 256, 0, stream>>>(ffn1, w2t, Pa2, Pb2, 512, 2048, 1024);
  ln_merge<<<2048, 256, 0, stream>>>(Pa2, Pb2, b2, zf, gamma, beta, out, nullptr, 1);
}

// Round 7
// 376.165 us; speedup vs baseline: 1.5293x; 1.0620x over previous
//
#include <hip/hip_runtime.h>
#include <math.h>

typedef __bf16 bf16;
typedef __bf16 bf16x8 __attribute__((ext_vector_type(8)));
typedef __bf16 bf16x4 __attribute__((ext_vector_type(4)));
typedef _Float16 f16;
typedef _Float16 f16x8 __attribute__((ext_vector_type(8)));
typedef _Float16 f16x4 __attribute__((ext_vector_type(4)));
typedef _Float16 f16x2 __attribute__((ext_vector_type(2)));
typedef __fp16 h16x2 __attribute__((ext_vector_type(2)));
typedef float f32x4 __attribute__((ext_vector_type(4)));
typedef unsigned int u32;

#define S_LEN 2048
#define QSCALE 0.18033688011112042f   // (1/8)*log2(e), folded into Q weights+bias
#define FIXEDMAX 8.0f

__device__ __forceinline__ void gload_lds16(const void* g, void* l) {
  __builtin_amdgcn_global_load_lds((const __attribute__((address_space(1))) u32*)g,
                                   (__attribute__((address_space(3))) u32*)l, 16, 0, 0);
}

// ---------------- embedding + sinusoidal PE ----------------
__global__ __launch_bounds__(256) void embed_pe(const int* __restrict__ x,
    const float* __restrict__ emb, float* __restrict__ zf, bf16* __restrict__ zb)
{
  const int row = blockIdx.x;
  const int s = row & (S_LEN - 1);
  const int tok = x[row];
  const float* e = emb + (size_t)tok * 512;
  float* zr = zf + (size_t)row * 512;
  bf16* zbr = zb + (size_t)row * 512;
  for (int i = threadIdx.x; i < 512; i += 256) {
    float invf = __expf((float)i * (-9.210340371976184f / 512.0f));
    float ang = (float)s * invf;
    float pe = (i & 1) ? __cosf(ang) : __sinf(ang);
    float v = e[i] + pe;
    zr[i] = v;
    zbr[i] = (bf16)v;
  }
}

// ---------------- all weight conversions in one launch ----------------
__global__ __launch_bounds__(256) void conv_all(
    const float* __restrict__ WfQ, const float* __restrict__ WfK, const float* __restrict__ WfV,
    const float* __restrict__ WQ, const float* __restrict__ WK, const float* __restrict__ WV,
    const float* __restrict__ Wo, const float* __restrict__ W1, const float* __restrict__ W2,
    bf16* __restrict__ wfqp, bf16* __restrict__ wfkp, bf16* __restrict__ wfvp,
    bf16* __restrict__ wqt, bf16* __restrict__ wkt, bf16* __restrict__ wvt,
    bf16* __restrict__ wot, bf16* __restrict__ w1t, bf16* __restrict__ w2t)
{
  int gid = blockIdx.x * 256 + threadIdx.x;
  int y = blockIdx.y;
  if (y < 3) {
    if (gid >= 262144) return;
    const float* in = y == 0 ? WfQ : (y == 1 ? WfK : WfV);
    bf16* out = y == 0 ? wfqp : (y == 1 ? wfkp : wfvp);
    out[gid] = (bf16)in[gid];
  } else if (y < 6) {
    if (gid >= 262144) return;
    const float* in = y == 3 ? WQ : (y == 4 ? WK : WV);
    bf16* out = y == 3 ? wqt : (y == 4 ? wkt : wvt);
    float scale = y == 3 ? QSCALE : 1.0f;
    int r = gid & 511, t = gid >> 9, c = t & 63, h = t >> 6;
    out[gid] = (bf16)(in[((size_t)(h * 512 + r)) * 64 + c] * scale);
  } else if (y == 6) {
    if (gid >= 262144) return;
    int r = gid & 511, c = gid >> 9;
    wot[gid] = (bf16)Wo[r * 512 + c];
  } else if (y == 7) {
    int r = gid & 511, c = gid >> 9;
    w1t[gid] = (bf16)W1[r * 2048 + c];
  } else {
    int r = gid & 2047, c = gid >> 11;
    w2t[gid] = (bf16)W2[r * 512 + c];
  }
}

// ---------------- combined bias ----------------
__global__ __launch_bounds__(256) void bias_comb(
    const float* __restrict__ bfQ, const float* __restrict__ bfK, const float* __restrict__ bfV,
    const float* __restrict__ WQ, const float* __restrict__ WK, const float* __restrict__ WV,
    const float* __restrict__ bQ, const float* __restrict__ bK, const float* __restrict__ bV,
    float* __restrict__ bc)
{
  int n = blockIdx.x * 4 + (threadIdx.x >> 6);
  int lane = threadIdx.x & 63;
  int z = n >> 9, hk = n & 511, h = hk >> 6, k = hk & 63;
  const float* bf = z == 0 ? bfQ : (z == 1 ? bfK : bfV);
  const float* W  = z == 0 ? WQ  : (z == 1 ? WK  : WV);
  const float* bH = z == 0 ? bQ  : (z == 1 ? bK  : bV);
  float s = 0.f;
  for (int e = lane; e < 512; e += 64)
    s += bf[e] * W[((size_t)h * 512 + e) * 64 + k];
  #pragma unroll
  for (int m = 1; m < 64; m <<= 1) s += __shfl_xor(s, m, 64);
  if (lane == 0) {
    float v = s + bH[h * 64 + k];
    if (z == 0) v *= QSCALE;
    bc[n] = v;
  }
}

// ---------------- weight-combine GEMMs (3 in one launch, 128x64 tiles) ----------------
__global__ __launch_bounds__(256) void gemm_comb(
    const bf16* __restrict__ wqt, const bf16* __restrict__ wkt, const bf16* __restrict__ wvt,
    const bf16* __restrict__ wfqp, const bf16* __restrict__ wfkp, const bf16* __restrict__ wfvp,
    bf16* __restrict__ wc)
{
  __shared__ bf16 As[128 * 32];
  __shared__ bf16 Bs[64 * 32];
  const int z = blockIdx.z;
  const bf16* A  = z == 0 ? wqt : (z == 1 ? wkt : wvt);
  const bf16* Bt = z == 0 ? wfqp : (z == 1 ? wfkp : wfvp);
  bf16* outb = wc + (size_t)z * 262144;
  const int tid = threadIdx.x;
  const int wave = tid >> 6, lane = tid & 63, quad = lane >> 4, l16 = lane & 15;
  const int row0 = blockIdx.x * 128, col0 = blockIdx.y * 64;
  const int wm = wave >> 1, wn = wave & 1;
  f32x4 acc[4][2] = {};

  for (int kk = 0; kk < 512; kk += 32) {
    __syncthreads();
    #pragma unroll
    for (int r = 0; r < 2; r++) {
      int c = r * 256 + tid;
      gload_lds16(A + (size_t)(row0 + (c >> 2)) * 512 + kk + (c & 3) * 8, As + c * 8);
    }
    gload_lds16(Bt + (size_t)(col0 + (tid >> 2)) * 512 + kk + (tid & 3) * 8, Bs + tid * 8);
    __syncthreads();
    bf16x8 af[4], bfr[2];
    #pragma unroll
    for (int i = 0; i < 4; i++)
      af[i] = *(const bf16x8*)(As + (wm * 64 + i * 16 + l16) * 32 + quad * 8);
    #pragma unroll
    for (int i = 0; i < 2; i++)
      bfr[i] = *(const bf16x8*)(Bs + (wn * 32 + i * 16 + l16) * 32 + quad * 8);
    #pragma unroll
    for (int mt = 0; mt < 4; mt++)
      #pragma unroll
      for (int nt = 0; nt < 2; nt++)
        acc[mt][nt] = __builtin_amdgcn_mfma_f32_16x16x32_bf16(af[mt], bfr[nt], acc[mt][nt], 0, 0, 0);
  }
  #pragma unroll
  for (int nt = 0; nt < 2; nt++) {
    int col = col0 + wn * 32 + nt * 16 + l16;
    #pragma unroll
    for (int mt = 0; mt < 4; mt++) {
      int rowb = row0 + wm * 64 + mt * 16 + quad * 4;
      #pragma unroll
      for (int i = 0; i < 4; i++)
        outb[(size_t)(rowb + i) * 512 + col] = (bf16)acc[mt][nt][i];
    }
  }
}

// ---------------- GEMM 128x128 tile (bf16 out; FFN1) ----------------
__global__ __launch_bounds__(256) void gemm_bt(
    const bf16* __restrict__ A, const bf16* __restrict__ Bt,
    const float* __restrict__ bias, bf16* __restrict__ outb,
    int M, int N, int K, int relu)
{
  __shared__ bf16 As[128 * 32];
  __shared__ bf16 Bs[128 * 32];
  const int tid = threadIdx.x;
  const int wave = tid >> 6, lane = tid & 63, quad = lane >> 4, l16 = lane & 15;
  const int row0 = blockIdx.x * 128, col0 = blockIdx.y * 128;
  const int wm = wave >> 1, wn = wave & 1;
  f32x4 acc[4][4] = {};

  for (int kk = 0; kk < K; kk += 32) {
    __syncthreads();
    #pragma unroll
    for (int r = 0; r < 2; r++) {
      int c = r * 256 + tid;
      gload_lds16(A + (size_t)(row0 + (c >> 2)) * K + kk + (c & 3) * 8, As + c * 8);
    }
    #pragma unroll
    for (int r = 0; r < 2; r++) {
      int c = r * 256 + tid;
      gload_lds16(Bt + (size_t)(col0 + (c >> 2)) * K + kk + (c & 3) * 8, Bs + c * 8);
    }
    __syncthreads();
    bf16x8 af[4], bfr[4];
    #pragma unroll
    for (int i = 0; i < 4; i++)
      af[i] = *(const bf16x8*)(As + (wm * 64 + i * 16 + l16) * 32 + quad * 8);
    #pragma unroll
    for (int i = 0; i < 4; i++)
      bfr[i] = *(const bf16x8*)(Bs + (wn * 64 + i * 16 + l16) * 32 + quad * 8);
    #pragma unroll
    for (int mt = 0; mt < 4; mt++)
      #pragma unroll
      for (int nt = 0; nt < 4; nt++)
        acc[mt][nt] = __builtin_amdgcn_mfma_f32_16x16x32_bf16(af[mt], bfr[nt], acc[mt][nt], 0, 0, 0);
  }

  #pragma unroll
  for (int nt = 0; nt < 4; nt++) {
    int col = col0 + wn * 64 + nt * 16 + l16;
    float bv = bias[col];
    #pragma unroll
    for (int mt = 0; mt < 4; mt++) {
      int rowb = row0 + wm * 64 + mt * 16 + quad * 4;
      #pragma unroll
      for (int i = 0; i < 4; i++) {
        float v = acc[mt][nt][i] + bv;
        if (relu) v = fmaxf(v, 0.f);
        outb[(size_t)(rowb + i) * N + col] = (bf16)v;
      }
    }
  }
}

// ---------------- QKV GEMM: N=1536, writes qk f16[row][1024] + Vt f16[bh][dv][2048] ----------------
__global__ __launch_bounds__(256) void gemm_qkv(
    const bf16* __restrict__ A, const bf16* __restrict__ Bt,
    const float* __restrict__ bias, f16* __restrict__ qk, f16* __restrict__ Vt)
{
  __shared__ bf16 As[128 * 32];
  __shared__ bf16 Bs[128 * 32];
  const int tid = threadIdx.x;
  const int wave = tid >> 6, lane = tid & 63, quad = lane >> 4, l16 = lane & 15;
  const int row0 = blockIdx.x * 128, col0 = blockIdx.y * 128;
  const int wm = wave >> 1, wn = wave & 1;
  f32x4 acc[4][4] = {};

  for (int kk = 0; kk < 512; kk += 32) {
    __syncthreads();
    #pragma unroll
    for (int r = 0; r < 2; r++) {
      int c = r * 256 + tid;
      gload_lds16(A + (size_t)(row0 + (c >> 2)) * 512 + kk + (c & 3) * 8, As + c * 8);
    }
    #pragma unroll
    for (int r = 0; r < 2; r++) {
      int c = r * 256 + tid;
      gload_lds16(Bt + (size_t)(col0 + (c >> 2)) * 512 + kk + (c & 3) * 8, Bs + c * 8);
    }
    __syncthreads();
    bf16x8 af[4], bfr[4];
    #pragma unroll
    for (int i = 0; i < 4; i++)
      af[i] = *(const bf16x8*)(As + (wm * 64 + i * 16 + l16) * 32 + quad * 8);
    #pragma unroll
    for (int i = 0; i < 4; i++)
      bfr[i] = *(const bf16x8*)(Bs + (wn * 64 + i * 16 + l16) * 32 + quad * 8);
    #pragma unroll
    for (int mt = 0; mt < 4; mt++)
      #pragma unroll
      for (int nt = 0; nt < 4; nt++)
        acc[mt][nt] = __builtin_amdgcn_mfma_f32_16x16x32_bf16(af[mt], bfr[nt], acc[mt][nt], 0, 0, 0);
  }

  #pragma unroll
  for (int nt = 0; nt < 4; nt++) {
    int col = col0 + wn * 64 + nt * 16 + l16;
    float bv = bias[col];
    if (col < 1024) {
      #pragma unroll
      for (int mt = 0; mt < 4; mt++) {
        int rowb = row0 + wm * 64 + mt * 16 + quad * 4;
        #pragma unroll
        for (int i = 0; i < 4; i++)
          qk[(size_t)(rowb + i) * 1024 + col] = (f16)(acc[mt][nt][i] + bv);
      }
    } else {
      int h = (col - 1024) >> 6, dv = col & 63;
      #pragma unroll
      for (int mt = 0; mt < 4; mt++) {
        int rowb = row0 + wm * 64 + mt * 16 + quad * 4;
        int b = rowb >> 11, s = rowb & 2047;
        f16x4 vv;
        #pragma unroll
        for (int i = 0; i < 4; i++) vv[i] = (f16)(acc[mt][nt][i] + bv);
        *(f16x4*)(Vt + ((size_t)((b * 8 + h) * 64 + dv)) * 2048 + s) = vv;
      }
    }
  }
}

// ---------------- split-K partial GEMM (raw f32 partials, no epilogue) ----------------
__global__ __launch_bounds__(256) void gemm_part(
    const bf16* __restrict__ A, const bf16* __restrict__ Bt,
    float* __restrict__ Pa, float* __restrict__ Pb, int N, int K, int Kh)
{
  __shared__ bf16 As[128 * 32];
  __shared__ bf16 Bs[128 * 32];
  const int tid = threadIdx.x;
  const int wave = tid >> 6, lane = tid & 63, quad = lane >> 4, l16 = lane & 15;
  const int row0 = blockIdx.x * 128, col0 = blockIdx.y * 128;
  const int wm = wave >> 1, wn = wave & 1;
  const int kk0 = blockIdx.z * Kh;
  float* P = blockIdx.z ? Pb : Pa;
  f32x4 acc[4][4] = {};

  for (int kk = kk0; kk < kk0 + Kh; kk += 32) {
    __syncthreads();
    #pragma unroll
    for (int r = 0; r < 2; r++) {
      int c = r * 256 + tid;
      gload_lds16(A + (size_t)(row0 + (c >> 2)) * K + kk + (c & 3) * 8, As + c * 8);
    }
    #pragma unroll
    for (int r = 0; r < 2; r++) {
      int c = r * 256 + tid;
      gload_lds16(Bt + (size_t)(col0 + (c >> 2)) * K + kk + (c & 3) * 8, Bs + c * 8);
    }
    __syncthreads();
    bf16x8 af[4], bfr[4];
    #pragma unroll
    for (int i = 0; i < 4; i++)
      af[i] = *(const bf16x8*)(As + (wm * 64 + i * 16 + l16) * 32 + quad * 8);
    #pragma unroll
    for (int i = 0; i < 4; i++)
      bfr[i] = *(const bf16x8*)(Bs + (wn * 64 + i * 16 + l16) * 32 + quad * 8);
    #pragma unroll
    for (int mt = 0; mt < 4; mt++)
      #pragma unroll
      for (int nt = 0; nt < 4; nt++)
        acc[mt][nt] = __builtin_amdgcn_mfma_f32_16x16x32_bf16(af[mt], bfr[nt], acc[mt][nt], 0, 0, 0);
  }

  #pragma unroll
  for (int nt = 0; nt < 4; nt++) {
    int col = col0 + wn * 64 + nt * 16 + l16;
    #pragma unroll
    for (int mt = 0; mt < 4; mt++) {
      int rowb = row0 + wm * 64 + mt * 16 + quad * 4;
      #pragma unroll
      for (int i = 0; i < 4; i++)
        P[(size_t)(rowb + i) * N + col] = acc[mt][nt][i];
    }
  }
}

// ---------------- flash attention: 32 q/wave, split-K 2, dbuf, rsum via MFMA ----------------
// qk: [8192][1024] f16; Vt: [32 bh][64 dv][2048 s] f16. Grid (16 qtile, 32 bh, 2 half).
__global__ __launch_bounds__(256) void flash_attn(
    const f16* __restrict__ qk, const f16* __restrict__ Vt,
    bf16* __restrict__ Op, float* __restrict__ Rp)
{
  __shared__ f16 Ks[2][4096];   // [key][dk], 16B chunks XOR-swizzled by row&7
  __shared__ f16 Vs[2][4096];   // [dv][key], same swizzle
  const int bh = blockIdx.y, b = bh >> 3, h = bh & 7;
  const int q0 = blockIdx.x * 128;
  const int half = blockIdx.z;
  const int tid = threadIdx.x;
  const int wave = tid >> 6, lane = tid & 63, quad = lane >> 4, l16 = lane & 15;

  const f16* Qb = qk + ((size_t)b * S_LEN) * 1024 + h * 64;
  const f16* Kb = Qb + 512;
  const f16* Vtb = Vt + ((size_t)bh * 64) * 2048;
  const int key0 = half * 1024;

  f16x8 qf[2][2];
  #pragma unroll
  for (int f = 0; f < 2; f++) {
    int qrow = q0 + wave * 32 + f * 16 + l16;
    #pragma unroll
    for (int kh = 0; kh < 2; kh++)
      qf[f][kh] = *(const f16x8*)(Qb + (size_t)qrow * 1024 + kh * 32 + quad * 8);
  }

  f32x4 O[2][4] = {};            // [f][mt]: O^T row=dv, col=q
  f32x4 Osum[2] = {};            // rsum accumulator via ones-MFMA (all rows identical)
  const f16x4 onesA = {(f16)1.f, (f16)1.f, (f16)1.f, (f16)1.f};
  const int swz = l16 & 7;

  f16x8 kreg[2], vreg[2];
  const int srow = tid >> 3, soff = tid & 7;
  const int srow1 = srow + 32;

  {
    int kb = key0;
    kreg[0] = *(const f16x8*)(Kb + (size_t)(kb + srow) * 1024 + soff * 8);
    vreg[0] = *(const f16x8*)(Vtb + (size_t)srow * 2048 + kb + soff * 8);
    kreg[1] = *(const f16x8*)(Kb + (size_t)(kb + srow1) * 1024 + soff * 8);
    vreg[1] = *(const f16x8*)(Vtb + (size_t)srow1 * 2048 + kb + soff * 8);
  }

  for (int c = 0; c < 16; c++) {
    f16* KsB = Ks[c & 1];
    f16* VsB = Vs[c & 1];
    *(f16x8*)(KsB + srow * 64 + ((soff ^ (srow & 7)) * 8)) = kreg[0];
    *(f16x8*)(VsB + srow * 64 + ((soff ^ (srow & 7)) * 8)) = vreg[0];
    *(f16x8*)(KsB + srow1 * 64 + ((soff ^ (srow1 & 7)) * 8)) = kreg[1];
    *(f16x8*)(VsB + srow1 * 64 + ((soff ^ (srow1 & 7)) * 8)) = vreg[1];
    __syncthreads();
    if (c < 15) {
      int kb = key0 + (c + 1) * 64;
      kreg[0] = *(const f16x8*)(Kb + (size_t)(kb + srow) * 1024 + soff * 8);
      vreg[0] = *(const f16x8*)(Vtb + (size_t)srow * 2048 + kb + soff * 8);
      kreg[1] = *(const f16x8*)(Kb + (size_t)(kb + srow1) * 1024 + soff * 8);
      vreg[1] = *(const f16x8*)(Vtb + (size_t)srow1 * 2048 + kb + soff * 8);
    }

    #pragma unroll
    for (int nt = 0; nt < 4; nt++) {
      const f16* kp = KsB + (nt * 16 + l16) * 64;
      f16x8 kf0 = *(const f16x8*)(kp + ((quad ^ swz) * 8));
      f16x8 kf1 = *(const f16x8*)(kp + (((4 + quad) ^ swz) * 8));
      f16x4 pf[2];
      #pragma unroll
      for (int f = 0; f < 2; f++) {
        f32x4 a = {};
        a = __builtin_amdgcn_mfma_f32_16x16x32_f16(kf0, qf[f][0], a, 0, 0, 0);
        a = __builtin_amdgcn_mfma_f32_16x16x32_f16(kf1, qf[f][1], a, 0, 0, 0);
        float e0 = exp2f(a[0] - FIXEDMAX);
        float e1 = exp2f(a[1] - FIXEDMAX);
        float e2 = exp2f(a[2] - FIXEDMAX);
        float e3 = exp2f(a[3] - FIXEDMAX);
        h16x2 lo = __builtin_amdgcn_cvt_pkrtz(e0, e1);
        h16x2 hi = __builtin_amdgcn_cvt_pkrtz(e2, e3);
        f16x2 lo2 = __builtin_bit_cast(f16x2, lo);
        f16x2 hi2 = __builtin_bit_cast(f16x2, hi);
        pf[f] = __builtin_shufflevector(lo2, hi2, 0, 1, 2, 3);
        // denominator: ones^T * P via MFMA (all output rows identical = key-sum per q)
        Osum[f] = __builtin_amdgcn_mfma_f32_16x16x16f16(onesA, pf[f], Osum[f], 0, 0, 0);
      }
      int vchunk = nt * 2 + (quad >> 1);
      #pragma unroll
      for (int mt = 0; mt < 4; mt++) {
        const f16* vp = VsB + (mt * 16 + l16) * 64 + ((vchunk ^ swz) * 8) + (quad & 1) * 4;
        f16x4 vf = *(const f16x4*)vp;
        #pragma unroll
        for (int f = 0; f < 2; f++)
          O[f][mt] = __builtin_amdgcn_mfma_f32_16x16x16f16(vf, pf[f], O[f][mt], 0, 0, 0);
      }
    }
    __syncthreads();
  }

  // store un-normalized partials (transpose through padded per-wave LDS regions)
  #pragma unroll
  for (int f = 0; f < 2; f++) {
    bf16* ob = (f == 0 ? (bf16*)&Ks[0][0] : (bf16*)&Vs[0][0]) + wave * 1152;  // 16 rows x 72
    #pragma unroll
    for (int mt = 0; mt < 4; mt++)
      #pragma unroll
      for (int i = 0; i < 4; i++)
        ob[l16 * 72 + mt * 16 + quad * 4 + i] = (bf16)O[f][mt][i];
  }
  asm volatile("s_waitcnt lgkmcnt(0)" ::: "memory");
  const size_t obase = (size_t)(half * 32 + bh) * 2048;
  #pragma unroll
  for (int f = 0; f < 2; f++) {
    bf16* ob = (f == 0 ? (bf16*)&Ks[0][0] : (bf16*)&Vs[0][0]) + wave * 1152;
    int row = lane >> 2, dvb = (lane & 3) * 16;
    bf16x8 o0 = *(const bf16x8*)(ob + row * 72 + dvb);
    bf16x8 o1 = *(const bf16x8*)(ob + row * 72 + dvb + 8);
    size_t g = (obase + q0 + wave * 32 + f * 16 + row) * 64 + dvb;
    *(bf16x8*)(Op + g) = o0;
    *(bf16x8*)(Op + g + 8) = o1;
    if (quad == f)
      Rp[obase + q0 + wave * 32 + f * 16 + l16] = Osum[f][0];
  }
}

// ---------------- attention partial merge (2-way) -> concat bf16 ----------------
__global__ __launch_bounds__(256) void attn_merge(const bf16* __restrict__ Op,
    const float* __restrict__ Rp, bf16* __restrict__ concat)
{
  int t = blockIdx.x * 256 + threadIdx.x;   // 32bh * 2048s * 16(dv4)
  int dv4 = t & 15, s = (t >> 4) & 2047, bh = t >> 15;
  int rb = bh * 2048 + s;
  float r = Rp[rb] + Rp[65536 + rb];
  float inv = 1.f / r;
  size_t ia = ((size_t)bh * 2048 + s) * 64 + dv4 * 4;
  bf16x4 a = *(const bf16x4*)(Op + ia);
  bf16x4 c = *(const bf16x4*)(Op + 4194304ull + ia);
  bf16x4 o;
  #pragma unroll
  for (int i = 0; i < 4; i++) o[i] = (bf16)(((float)a[i] + (float)c[i]) * inv);
  int b = bh >> 3, h = bh & 7;
  *(bf16x4*)(concat + ((size_t)(b * 2048 + s)) * 512 + h * 64 + dv4 * 4) = o;
}

// ---------------- LN with partial merge: (Pa+Pb+badd+resid) -> LN -> outf(+outb)(+relu) ----------------
__global__ __launch_bounds__(256) void ln_merge(const float* __restrict__ Pa,
    const float* __restrict__ Pb, const float* __restrict__ badd,
    const float* __restrict__ resid, const float* __restrict__ gamma,
    const float* __restrict__ beta, float* __restrict__ outf,
    bf16* __restrict__ outb, int relu)
{
  const int row = blockIdx.x * 4 + (threadIdx.x >> 6);
  const int lane = threadIdx.x & 63;
  const size_t base = (size_t)row * 512;
  const float4* pa = (const float4*)(Pa + base);
  const float4* pb = (const float4*)(Pb + base);
  const float4* rr = (const float4*)(resid + base);
  const float4* bb = (const float4*)badd;
  float4 A0 = pa[lane], A1 = pa[lane + 64];
  float4 B0 = pb[lane], B1 = pb[lane + 64];
  float4 R0 = rr[lane], R1 = rr[lane + 64];
  float4 C0 = bb[lane], C1 = bb[lane + 64];
  float4 v0 = {A0.x+B0.x+R0.x+C0.x, A0.y+B0.y+R0.y+C0.y, A0.z+B0.z+R0.z+C0.z, A0.w+B0.w+R0.w+C0.w};
  float4 v1 = {A1.x+B1.x+R1.x+C1.x, A1.y+B1.y+R1.y+C1.y, A1.z+B1.z+R1.z+C1.z, A1.w+B1.w+R1.w+C1.w};
  float s = v0.x + v0.y + v0.z + v0.w + v1.x + v1.y + v1.z + v1.w;
  #pragma unroll
  for (int m = 1; m < 64; m <<= 1) s += __shfl_xor(s, m, 64);
  float mu = s * (1.f / 512.f);
  float d0 = v0.x - mu, d1 = v0.y - mu, d2 = v0.z - mu, d3 = v0.w - mu;
  float d4 = v1.x - mu, d5 = v1.y - mu, d6 = v1.z - mu, d7 = v1.w - mu;
  float q = d0*d0 + d1*d1 + d2*d2 + d3*d3 + d4*d4 + d5*d5 + d6*d6 + d7*d7;
  #pragma unroll
  for (int m = 1; m < 64; m <<= 1) q += __shfl_xor(q, m, 64);
  float rs = rsqrtf(q * (1.f / 512.f) + 1e-5f);
  const float4* gp = (const float4*)gamma;
  const float4* bp = (const float4*)beta;
  float4 g0 = gp[lane], g1 = gp[lane + 64];
  float4 b0 = bp[lane], b1 = bp[lane + 64];
  float y0 = d0 * rs * g0.x + b0.x, y1 = d1 * rs * g0.y + b0.y;
  float y2 = d2 * rs * g0.z + b0.z, y3 = d3 * rs * g0.w + b0.w;
  float y4 = d4 * rs * g1.x + b1.x, y5 = d5 * rs * g1.y + b1.y;
  float y6 = d6 * rs * g1.z + b1.z, y7 = d7 * rs * g1.w + b1.w;
  if (relu) {
    y0 = fmaxf(y0, 0.f); y1 = fmaxf(y1, 0.f); y2 = fmaxf(y2, 0.f); y3 = fmaxf(y3, 0.f);
    y4 = fmaxf(y4, 0.f); y5 = fmaxf(y5, 0.f); y6 = fmaxf(y6, 0.f); y7 = fmaxf(y7, 0.f);
  }
  float4* op = (float4*)(outf + base);
  float4 o0 = {y0, y1, y2, y3}, o1 = {y4, y5, y6, y7};
  op[lane] = o0;
  op[lane + 64] = o1;
  if (outb) {
    bf16x4 c0 = {(bf16)y0, (bf16)y1, (bf16)y2, (bf16)y3};
    bf16x4 c1 = {(bf16)y4, (bf16)y5, (bf16)y6, (bf16)y7};
    *(bf16x4*)(outb + base + lane * 4) = c0;
    *(bf16x4*)(outb + base + 256 + lane * 4) = c1;
  }
}

extern "C" void kernel_launch(void* const* d_in, const int* in_sizes, int n_in,
                              void* d_out, int out_size, void* d_ws, size_t ws_size,
                              hipStream_t stream)
{
  const int*   x    = (const int*)  d_in[0];
  const float* emb  = (const float*)d_in[1];
  const float* WfQ  = (const float*)d_in[2];
  const float* bfQv = (const float*)d_in[3];
  const float* WfK  = (const float*)d_in[4];
  const float* bfKv = (const float*)d_in[5];
  const float* WfV  = (const float*)d_in[6];
  const float* bfVv = (const float*)d_in[7];
  const float* WQ   = (const float*)d_in[8];
  const float* bQ   = (const float*)d_in[9];
  const float* WK   = (const float*)d_in[10];
  const float* bK   = (const float*)d_in[11];
  const float* WV   = (const float*)d_in[12];
  const float* bV   = (const float*)d_in[13];
  const float* Wo   = (const float*)d_in[14];
  const float* bo   = (const float*)d_in[15];
  const float* W1   = (const float*)d_in[16];
  const float* b1   = (const float*)d_in[17];
  const float* W2   = (const float*)d_in[18];
  const float* b2   = (const float*)d_in[19];
  const float* gamma= (const float*)d_in[20];
  const float* beta = (const float*)d_in[21];
  float* out = (float*)d_out;

  char* ws = (char*)d_ws;
  const size_t MB = 1024ull * 1024;
  float* zf   = (float*)(ws);              // 0-16: z fp32, then a fp32
  bf16*  bz   = (bf16*) (ws + 16 * MB);    // 16-24: z bf16, then a bf16
  f16*   qkh  = (f16*)  (ws + 24 * MB);    // 24-40 (dead after flash)
  f16*   Vt   = (f16*)  (ws + 40 * MB);    // 40-48 (dead after flash)
  bf16*  Op   = (bf16*) (ws + 48 * MB);    // 48-64: flash O partials x2
  float* Rp   = (float*)(ws + 80 * MB);    // 80-81
  bf16*  concat = (bf16*)(ws + 82 * MB);   // 82-90
  float* PaW  = (float*)(ws + 48 * MB);
  float* PbW  = (float*)(ws + 64 * MB);
  bf16*  ffn1 = (bf16*) (ws + 24 * MB);    // 24-56 (after ln1)
  float* Pa2  = (float*)(ws + 56 * MB);
  float* Pb2  = (float*)(ws + 72 * MB);
  char* wp = ws + 90 * MB;
  bf16* wfqp = (bf16*)(wp);
  bf16* wfkp = (bf16*)(wp + 512 * 1024);
  bf16* wfvp = (bf16*)(wp + 1024 * 1024);
  bf16* wqt  = (bf16*)(wp + 1536 * 1024);
  bf16* wkt  = (bf16*)(wp + 2048 * 1024);
  bf16* wvt  = (bf16*)(wp + 2560 * 1024);
  bf16* wc   = (bf16*)(wp + 3072 * 1024);
  bf16* wot  = (bf16*)(wp + 4608 * 1024);
  bf16* w1t  = (bf16*)(wp + 5120 * 1024);
  bf16* w2t  = (bf16*)(wp + 7168 * 1024);
  float* bc  = (float*)(wp + 9216 * 1024);

  conv_all<<<dim3(4096, 9), 256, 0, stream>>>(WfQ, WfK, WfV, WQ, WK, WV, Wo, W1, W2,
                                              wfqp, wfkp, wfvp, wqt, wkt, wvt, wot, w1t, w2t);
  bias_comb<<<384, 256, 0, stream>>>(bfQv, bfKv, bfVv, WQ, WK, WV, bQ, bK, bV, bc);
  gemm_comb<<<dim3(4, 8, 3), 256, 0, stream>>>(wqt, wkt, wvt, wfqp, wfkp, wfvp, wc);

  embed_pe<<<8192, 256, 0, stream>>>(x, emb, zf, bz);

  gemm_qkv<<<dim3(64, 12), 256, 0, stream>>>(bz, wc, bc, qkh, Vt);
  flash_attn<<<dim3(16, 32, 2), 256, 0, stream>>>(qkh, Vt, Op, Rp);
  attn_merge<<<4096, 256, 0, stream>>>(Op, Rp, concat);

  gemm_part<<<dim3(64, 4, 2), 256, 0, stream>>>(concat, wot, PaW, PbW, 512, 512, 256);
  ln_merge<<<2048, 256, 0, stream>>>(PaW, PbW, bo, zf, gamma, beta, zf, bz, 0);
  gemm_bt<<<dim3(64, 16), 256, 0, stream>>>(bz, w1t, b1, ffn1, 8192, 2048, 512, 1);
  gemm_part<<<dim3(64, 4, 2), 256, 0, stream>>>(ffn1, w2t, Pa2, Pb2, 512, 2048, 1024);
  ln_merge<<<2048, 256, 0, stream>>>(Pa2, Pb2, b2, zf, gamma, beta, out, nullptr, 1);
}

// Round 8
// 358.530 us; speedup vs baseline: 1.6045x; 1.0492x over previous
//
#include <hip/hip_runtime.h>
#include <math.h>

typedef __bf16 bf16;
typedef __bf16 bf16x8 __attribute__((ext_vector_type(8)));
typedef __bf16 bf16x4 __attribute__((ext_vector_type(4)));
typedef _Float16 f16;
typedef _Float16 f16x8 __attribute__((ext_vector_type(8)));
typedef _Float16 f16x4 __attribute__((ext_vector_type(4)));
typedef _Float16 f16x2 __attribute__((ext_vector_type(2)));
typedef __fp16 h16x2 __attribute__((ext_vector_type(2)));
typedef float f32x4 __attribute__((ext_vector_type(4)));
typedef unsigned int u32;

#define S_LEN 2048
#define QSCALE 0.18033688011112042f   // (1/8)*log2(e), folded into Q weights+bias

__device__ __forceinline__ void gload_lds16(const void* g, void* l) {
  __builtin_amdgcn_global_load_lds((const __attribute__((address_space(1))) u32*)g,
                                   (__attribute__((address_space(3))) u32*)l, 16, 0, 0);
}

// ---------------- embedding + sinusoidal PE ----------------
__global__ __launch_bounds__(256) void embed_pe(const int* __restrict__ x,
    const float* __restrict__ emb, float* __restrict__ zf, bf16* __restrict__ zb)
{
  const int row = blockIdx.x;
  const int s = row & (S_LEN - 1);
  const int tok = x[row];
  const float* e = emb + (size_t)tok * 512;
  float* zr = zf + (size_t)row * 512;
  bf16* zbr = zb + (size_t)row * 512;
  for (int i = threadIdx.x; i < 512; i += 256) {
    float invf = __expf((float)i * (-9.210340371976184f / 512.0f));
    float ang = (float)s * invf;
    float pe = (i & 1) ? __cosf(ang) : __sinf(ang);
    float v = e[i] + pe;
    zr[i] = v;
    zbr[i] = (bf16)v;
  }
}

// ---------------- all weight conversions in one launch ----------------
__global__ __launch_bounds__(256) void conv_all(
    const float* __restrict__ WfQ, const float* __restrict__ WfK, const float* __restrict__ WfV,
    const float* __restrict__ WQ, const float* __restrict__ WK, const float* __restrict__ WV,
    const float* __restrict__ Wo, const float* __restrict__ W1, const float* __restrict__ W2,
    bf16* __restrict__ wfqp, bf16* __restrict__ wfkp, bf16* __restrict__ wfvp,
    bf16* __restrict__ wqt, bf16* __restrict__ wkt, bf16* __restrict__ wvt,
    bf16* __restrict__ wot, bf16* __restrict__ w1t, bf16* __restrict__ w2t)
{
  int gid = blockIdx.x * 256 + threadIdx.x;
  int y = blockIdx.y;
  if (y < 3) {
    if (gid >= 262144) return;
    const float* in = y == 0 ? WfQ : (y == 1 ? WfK : WfV);
    bf16* out = y == 0 ? wfqp : (y == 1 ? wfkp : wfvp);
    out[gid] = (bf16)in[gid];
  } else if (y < 6) {
    if (gid >= 262144) return;
    const float* in = y == 3 ? WQ : (y == 4 ? WK : WV);
    bf16* out = y == 3 ? wqt : (y == 4 ? wkt : wvt);
    float scale = y == 3 ? QSCALE : 1.0f;
    int r = gid & 511, t = gid >> 9, c = t & 63, h = t >> 6;
    out[gid] = (bf16)(in[((size_t)(h * 512 + r)) * 64 + c] * scale);
  } else if (y == 6) {
    if (gid >= 262144) return;
    int r = gid & 511, c = gid >> 9;
    wot[gid] = (bf16)Wo[r * 512 + c];
  } else if (y == 7) {
    int r = gid & 511, c = gid >> 9;
    w1t[gid] = (bf16)W1[r * 2048 + c];
  } else {
    int r = gid & 2047, c = gid >> 11;
    w2t[gid] = (bf16)W2[r * 512 + c];
  }
}

// ---------------- combined bias ----------------
__global__ __launch_bounds__(256) void bias_comb(
    const float* __restrict__ bfQ, const float* __restrict__ bfK, const float* __restrict__ bfV,
    const float* __restrict__ WQ, const float* __restrict__ WK, const float* __restrict__ WV,
    const float* __restrict__ bQ, const float* __restrict__ bK, const float* __restrict__ bV,
    float* __restrict__ bc)
{
  int n = blockIdx.x * 4 + (threadIdx.x >> 6);
  int lane = threadIdx.x & 63;
  int z = n >> 9, hk = n & 511, h = hk >> 6, k = hk & 63;
  const float* bf = z == 0 ? bfQ : (z == 1 ? bfK : bfV);
  const float* W  = z == 0 ? WQ  : (z == 1 ? WK  : WV);
  const float* bH = z == 0 ? bQ  : (z == 1 ? bK  : bV);
  float s = 0.f;
  for (int e = lane; e < 512; e += 64)
    s += bf[e] * W[((size_t)h * 512 + e) * 64 + k];
  #pragma unroll
  for (int m = 1; m < 64; m <<= 1) s += __shfl_xor(s, m, 64);
  if (lane == 0) {
    float v = s + bH[h * 64 + k];
    if (z == 0) v *= QSCALE;
    bc[n] = v;
  }
}

// ---------------- weight-combine GEMMs (3 in one launch, 128x64 tiles) ----------------
__global__ __launch_bounds__(256) void gemm_comb(
    const bf16* __restrict__ wqt, const bf16* __restrict__ wkt, const bf16* __restrict__ wvt,
    const bf16* __restrict__ wfqp, const bf16* __restrict__ wfkp, const bf16* __restrict__ wfvp,
    bf16* __restrict__ wc)
{
  __shared__ bf16 As[128 * 32];
  __shared__ bf16 Bs[64 * 32];
  const int z = blockIdx.z;
  const bf16* A  = z == 0 ? wqt : (z == 1 ? wkt : wvt);
  const bf16* Bt = z == 0 ? wfqp : (z == 1 ? wfkp : wfvp);
  bf16* outb = wc + (size_t)z * 262144;
  const int tid = threadIdx.x;
  const int wave = tid >> 6, lane = tid & 63, quad = lane >> 4, l16 = lane & 15;
  const int row0 = blockIdx.x * 128, col0 = blockIdx.y * 64;
  const int wm = wave >> 1, wn = wave & 1;
  f32x4 acc[4][2] = {};

  for (int kk = 0; kk < 512; kk += 32) {
    __syncthreads();
    #pragma unroll
    for (int r = 0; r < 2; r++) {
      int c = r * 256 + tid;
      gload_lds16(A + (size_t)(row0 + (c >> 2)) * 512 + kk + (c & 3) * 8, As + c * 8);
    }
    gload_lds16(Bt + (size_t)(col0 + (tid >> 2)) * 512 + kk + (tid & 3) * 8, Bs + tid * 8);
    __syncthreads();
    bf16x8 af[4], bfr[2];
    #pragma unroll
    for (int i = 0; i < 4; i++)
      af[i] = *(const bf16x8*)(As + (wm * 64 + i * 16 + l16) * 32 + quad * 8);
    #pragma unroll
    for (int i = 0; i < 2; i++)
      bfr[i] = *(const bf16x8*)(Bs + (wn * 32 + i * 16 + l16) * 32 + quad * 8);
    #pragma unroll
    for (int mt = 0; mt < 4; mt++)
      #pragma unroll
      for (int nt = 0; nt < 2; nt++)
        acc[mt][nt] = __builtin_amdgcn_mfma_f32_16x16x32_bf16(af[mt], bfr[nt], acc[mt][nt], 0, 0, 0);
  }
  #pragma unroll
  for (int nt = 0; nt < 2; nt++) {
    int col = col0 + wn * 32 + nt * 16 + l16;
    #pragma unroll
    for (int mt = 0; mt < 4; mt++) {
      int rowb = row0 + wm * 64 + mt * 16 + quad * 4;
      #pragma unroll
      for (int i = 0; i < 4; i++)
        outb[(size_t)(rowb + i) * 512 + col] = (bf16)acc[mt][nt][i];
    }
  }
}

// ======== dbuf reg-prefetch GEMM core (128x128 tile, BK=32, 1 barrier/iter) ========
// Staging: thread tid owns chunks c0=tid, c1=256+tid; chunk c -> row c>>2, koff (c&3)*8.
#define GEMM_CORE(A_, Bt_, K_, KK0_, ITERS_)                                            \
  bf16x8 ar0, ar1, br0, br1;                                                            \
  const int c0 = tid, c1 = 256 + tid;                                                   \
  const size_t aoff0 = (size_t)(row0 + (c0 >> 2)) * (K_) + (c0 & 3) * 8;                \
  const size_t aoff1 = (size_t)(row0 + (c1 >> 2)) * (K_) + (c1 & 3) * 8;                \
  const size_t boff0 = (size_t)(col0 + (c0 >> 2)) * (K_) + (c0 & 3) * 8;                \
  const size_t boff1 = (size_t)(col0 + (c1 >> 2)) * (K_) + (c1 & 3) * 8;                \
  ar0 = *(const bf16x8*)((A_) + aoff0 + (KK0_));                                        \
  ar1 = *(const bf16x8*)((A_) + aoff1 + (KK0_));                                        \
  br0 = *(const bf16x8*)((Bt_) + boff0 + (KK0_));                                       \
  br1 = *(const bf16x8*)((Bt_) + boff1 + (KK0_));                                       \
  for (int it = 0; it < (ITERS_); it++) {                                               \
    bf16* AsB = As[it & 1];                                                             \
    bf16* BsB = Bs[it & 1];                                                             \
    *(bf16x8*)(AsB + c0 * 8) = ar0;                                                     \
    *(bf16x8*)(AsB + c1 * 8) = ar1;                                                     \
    *(bf16x8*)(BsB + c0 * 8) = br0;                                                     \
    *(bf16x8*)(BsB + c1 * 8) = br1;                                                     \
    __syncthreads();                                                                    \
    if (it + 1 < (ITERS_)) {                                                            \
      int kk = (KK0_) + (it + 1) * 32;                                                  \
      ar0 = *(const bf16x8*)((A_) + aoff0 + kk);                                        \
      ar1 = *(const bf16x8*)((A_) + aoff1 + kk);                                        \
      br0 = *(const bf16x8*)((Bt_) + boff0 + kk);                                       \
      br1 = *(const bf16x8*)((Bt_) + boff1 + kk);                                       \
    }                                                                                   \
    bf16x8 af[4], bfr[4];                                                               \
    _Pragma("unroll")                                                                   \
    for (int i = 0; i < 4; i++)                                                         \
      af[i] = *(const bf16x8*)(AsB + (wm * 64 + i * 16 + l16) * 32 + quad * 8);         \
    _Pragma("unroll")                                                                   \
    for (int i = 0; i < 4; i++)                                                         \
      bfr[i] = *(const bf16x8*)(BsB + (wn * 64 + i * 16 + l16) * 32 + quad * 8);        \
    _Pragma("unroll")                                                                   \
    for (int mt = 0; mt < 4; mt++)                                                      \
      _Pragma("unroll")                                                                 \
      for (int nt = 0; nt < 4; nt++)                                                    \
        acc[mt][nt] = __builtin_amdgcn_mfma_f32_16x16x32_bf16(af[mt], bfr[nt], acc[mt][nt], 0, 0, 0); \
  }

// ---------------- GEMM 128x128 (bias, optional relu, bf16 out; FFN1) ----------------
__global__ __launch_bounds__(256) void gemm_bt(
    const bf16* __restrict__ A, const bf16* __restrict__ Bt,
    const float* __restrict__ bias, bf16* __restrict__ outb,
    int M, int N, int K, int relu)
{
  __shared__ bf16 As[2][4096];
  __shared__ bf16 Bs[2][4096];
  const int tid = threadIdx.x;
  const int wave = tid >> 6, lane = tid & 63, quad = lane >> 4, l16 = lane & 15;
  const int row0 = blockIdx.x * 128, col0 = blockIdx.y * 128;
  const int wm = wave >> 1, wn = wave & 1;
  f32x4 acc[4][4] = {};
  GEMM_CORE(A, Bt, K, 0, K / 32)

  #pragma unroll
  for (int nt = 0; nt < 4; nt++) {
    int col = col0 + wn * 64 + nt * 16 + l16;
    float bv = bias[col];
    #pragma unroll
    for (int mt = 0; mt < 4; mt++) {
      int rowb = row0 + wm * 64 + mt * 16 + quad * 4;
      #pragma unroll
      for (int i = 0; i < 4; i++) {
        float v = acc[mt][nt][i] + bv;
        if (relu) v = fmaxf(v, 0.f);
        outb[(size_t)(rowb + i) * N + col] = (bf16)v;
      }
    }
  }
}

// ---------------- QKV GEMM: N=1536, writes qk f16[row][1024] + Vt f16[bh][dv][2048] ----------------
__global__ __launch_bounds__(256) void gemm_qkv(
    const bf16* __restrict__ A, const bf16* __restrict__ Bt,
    const float* __restrict__ bias, f16* __restrict__ qk, f16* __restrict__ Vt)
{
  __shared__ bf16 As[2][4096];
  __shared__ bf16 Bs[2][4096];
  const int tid = threadIdx.x;
  const int wave = tid >> 6, lane = tid & 63, quad = lane >> 4, l16 = lane & 15;
  const int row0 = blockIdx.x * 128, col0 = blockIdx.y * 128;
  const int wm = wave >> 1, wn = wave & 1;
  f32x4 acc[4][4] = {};
  GEMM_CORE(A, Bt, 512, 0, 16)

  #pragma unroll
  for (int nt = 0; nt < 4; nt++) {
    int col = col0 + wn * 64 + nt * 16 + l16;
    float bv = bias[col];
    if (col < 1024) {
      #pragma unroll
      for (int mt = 0; mt < 4; mt++) {
        int rowb = row0 + wm * 64 + mt * 16 + quad * 4;
        #pragma unroll
        for (int i = 0; i < 4; i++)
          qk[(size_t)(rowb + i) * 1024 + col] = (f16)(acc[mt][nt][i] + bv);
      }
    } else {
      int h = (col - 1024) >> 6, dv = col & 63;
      #pragma unroll
      for (int mt = 0; mt < 4; mt++) {
        int rowb = row0 + wm * 64 + mt * 16 + quad * 4;
        int b = rowb >> 11, s = rowb & 2047;
        f16x4 vv;
        #pragma unroll
        for (int i = 0; i < 4; i++) vv[i] = (f16)(acc[mt][nt][i] + bv);
        *(f16x4*)(Vt + ((size_t)((b * 8 + h) * 64 + dv)) * 2048 + s) = vv;
      }
    }
  }
}

// ---------------- split-K partial GEMM -> bf16 partials ----------------
__global__ __launch_bounds__(256) void gemm_part(
    const bf16* __restrict__ A, const bf16* __restrict__ Bt,
    bf16* __restrict__ Pa, bf16* __restrict__ Pb, int N, int K, int Kh)
{
  __shared__ bf16 As[2][4096];
  __shared__ bf16 Bs[2][4096];
  const int tid = threadIdx.x;
  const int wave = tid >> 6, lane = tid & 63, quad = lane >> 4, l16 = lane & 15;
  const int row0 = blockIdx.x * 128, col0 = blockIdx.y * 128;
  const int wm = wave >> 1, wn = wave & 1;
  const int kk0 = blockIdx.z * Kh;
  bf16* P = blockIdx.z ? Pb : Pa;
  f32x4 acc[4][4] = {};
  GEMM_CORE(A, Bt, K, kk0, Kh / 32)

  #pragma unroll
  for (int nt = 0; nt < 4; nt++) {
    int col = col0 + wn * 64 + nt * 16 + l16;
    #pragma unroll
    for (int mt = 0; mt < 4; mt++) {
      int rowb = row0 + wm * 64 + mt * 16 + quad * 4;
      #pragma unroll
      for (int i = 0; i < 4; i++)
        P[(size_t)(rowb + i) * N + col] = (bf16)acc[mt][nt][i];
    }
  }
}

// ---------------- flash attention: 32 q/wave, split-K 2, dbuf, rsum via MFMA ----------------
// qk: [8192][1024] f16; Vt: [32 bh][64 dv][2048 s] f16. Grid (16 qtile, 32 bh, 2 half).
__global__ __launch_bounds__(256) void flash_attn(
    const f16* __restrict__ qk, const f16* __restrict__ Vt,
    bf16* __restrict__ Op, float* __restrict__ Rp)
{
  __shared__ f16 Ks[2][4096];   // [key][dk], 16B chunks XOR-swizzled by row&7
  __shared__ f16 Vs[2][4096];   // [dv][key], same swizzle
  const int bh = blockIdx.y, b = bh >> 3, h = bh & 7;
  const int q0 = blockIdx.x * 128;
  const int half = blockIdx.z;
  const int tid = threadIdx.x;
  const int wave = tid >> 6, lane = tid & 63, quad = lane >> 4, l16 = lane & 15;

  const f16* Qb = qk + ((size_t)b * S_LEN) * 1024 + h * 64;
  const f16* Kb = Qb + 512;
  const f16* Vtb = Vt + ((size_t)bh * 64) * 2048;
  const int key0 = half * 1024;

  f16x8 qf[2][2];
  #pragma unroll
  for (int f = 0; f < 2; f++) {
    int qrow = q0 + wave * 32 + f * 16 + l16;
    #pragma unroll
    for (int kh = 0; kh < 2; kh++)
      qf[f][kh] = *(const f16x8*)(Qb + (size_t)qrow * 1024 + kh * 32 + quad * 8);
  }

  f32x4 O[2][4] = {};            // [f][mt]: O^T row=dv, col=q
  f32x4 Osum[2] = {};            // rsum accumulator via ones-MFMA
  const f16x4 onesA = {(f16)1.f, (f16)1.f, (f16)1.f, (f16)1.f};
  const int swz = l16 & 7;

  f16x8 kreg[2], vreg[2];
  const int srow = tid >> 3, soff = tid & 7;
  const int srow1 = srow + 32;

  {
    int kb = key0;
    kreg[0] = *(const f16x8*)(Kb + (size_t)(kb + srow) * 1024 + soff * 8);
    vreg[0] = *(const f16x8*)(Vtb + (size_t)srow * 2048 + kb + soff * 8);
    kreg[1] = *(const f16x8*)(Kb + (size_t)(kb + srow1) * 1024 + soff * 8);
    vreg[1] = *(const f16x8*)(Vtb + (size_t)srow1 * 2048 + kb + soff * 8);
  }

  for (int c = 0; c < 16; c++) {
    f16* KsB = Ks[c & 1];
    f16* VsB = Vs[c & 1];
    *(f16x8*)(KsB + srow * 64 + ((soff ^ (srow & 7)) * 8)) = kreg[0];
    *(f16x8*)(VsB + srow * 64 + ((soff ^ (srow & 7)) * 8)) = vreg[0];
    *(f16x8*)(KsB + srow1 * 64 + ((soff ^ (srow1 & 7)) * 8)) = kreg[1];
    *(f16x8*)(VsB + srow1 * 64 + ((soff ^ (srow1 & 7)) * 8)) = vreg[1];
    __syncthreads();
    if (c < 15) {
      int kb = key0 + (c + 1) * 64;
      kreg[0] = *(const f16x8*)(Kb + (size_t)(kb + srow) * 1024 + soff * 8);
      vreg[0] = *(const f16x8*)(Vtb + (size_t)srow * 2048 + kb + soff * 8);
      kreg[1] = *(const f16x8*)(Kb + (size_t)(kb + srow1) * 1024 + soff * 8);
      vreg[1] = *(const f16x8*)(Vtb + (size_t)srow1 * 2048 + kb + soff * 8);
    }

    #pragma unroll
    for (int nt = 0; nt < 4; nt++) {
      const f16* kp = KsB + (nt * 16 + l16) * 64;
      f16x8 kf0 = *(const f16x8*)(kp + ((quad ^ swz) * 8));
      f16x8 kf1 = *(const f16x8*)(kp + (((4 + quad) ^ swz) * 8));
      f16x4 pf[2];
      #pragma unroll
      for (int f = 0; f < 2; f++) {
        f32x4 a = {};
        a = __builtin_amdgcn_mfma_f32_16x16x32_f16(kf0, qf[f][0], a, 0, 0, 0);
        a = __builtin_amdgcn_mfma_f32_16x16x32_f16(kf1, qf[f][1], a, 0, 0, 0);
        // p = exp2(a); scores bounded (~9 max) so p <= ~2^9, safe in f16; norm cancels
        float e0 = exp2f(a[0]);
        float e1 = exp2f(a[1]);
        float e2 = exp2f(a[2]);
        float e3 = exp2f(a[3]);
        h16x2 lo = __builtin_amdgcn_cvt_pkrtz(e0, e1);
        h16x2 hi = __builtin_amdgcn_cvt_pkrtz(e2, e3);
        f16x2 lo2 = __builtin_bit_cast(f16x2, lo);
        f16x2 hi2 = __builtin_bit_cast(f16x2, hi);
        pf[f] = __builtin_shufflevector(lo2, hi2, 0, 1, 2, 3);
        Osum[f] = __builtin_amdgcn_mfma_f32_16x16x16f16(onesA, pf[f], Osum[f], 0, 0, 0);
      }
      int vchunk = nt * 2 + (quad >> 1);
      #pragma unroll
      for (int mt = 0; mt < 4; mt++) {
        const f16* vp = VsB + (mt * 16 + l16) * 64 + ((vchunk ^ swz) * 8) + (quad & 1) * 4;
        f16x4 vf = *(const f16x4*)vp;
        #pragma unroll
        for (int f = 0; f < 2; f++)
          O[f][mt] = __builtin_amdgcn_mfma_f32_16x16x16f16(vf, pf[f], O[f][mt], 0, 0, 0);
      }
    }
    __syncthreads();
  }

  // store un-normalized partials (transpose through padded per-wave LDS regions)
  #pragma unroll
  for (int f = 0; f < 2; f++) {
    bf16* ob = (f == 0 ? (bf16*)&Ks[0][0] : (bf16*)&Vs[0][0]) + wave * 1152;  // 16 x 72
    #pragma unroll
    for (int mt = 0; mt < 4; mt++)
      #pragma unroll
      for (int i = 0; i < 4; i++)
        ob[l16 * 72 + mt * 16 + quad * 4 + i] = (bf16)O[f][mt][i];
  }
  asm volatile("s_waitcnt lgkmcnt(0)" ::: "memory");
  const size_t obase = (size_t)(half * 32 + bh) * 2048;
  #pragma unroll
  for (int f = 0; f < 2; f++) {
    bf16* ob = (f == 0 ? (bf16*)&Ks[0][0] : (bf16*)&Vs[0][0]) + wave * 1152;
    int row = lane >> 2, dvb = (lane & 3) * 16;
    bf16x8 o0 = *(const bf16x8*)(ob + row * 72 + dvb);
    bf16x8 o1 = *(const bf16x8*)(ob + row * 72 + dvb + 8);
    size_t g = (obase + q0 + wave * 32 + f * 16 + row) * 64 + dvb;
    *(bf16x8*)(Op + g) = o0;
    *(bf16x8*)(Op + g + 8) = o1;
    if (quad == f)
      Rp[obase + q0 + wave * 32 + f * 16 + l16] = Osum[f][0];
  }
}

// ---------------- attention partial merge (2-way) -> concat bf16 ----------------
__global__ __launch_bounds__(256) void attn_merge(const bf16* __restrict__ Op,
    const float* __restrict__ Rp, bf16* __restrict__ concat)
{
  int t = blockIdx.x * 256 + threadIdx.x;   // 32bh * 2048s * 16(dv4)
  int dv4 = t & 15, s = (t >> 4) & 2047, bh = t >> 15;
  int rb = bh * 2048 + s;
  float r = Rp[rb] + Rp[65536 + rb];
  float inv = 1.f / r;
  size_t ia = ((size_t)bh * 2048 + s) * 64 + dv4 * 4;
  bf16x4 a = *(const bf16x4*)(Op + ia);
  bf16x4 c = *(const bf16x4*)(Op + 4194304ull + ia);
  bf16x4 o;
  #pragma unroll
  for (int i = 0; i < 4; i++) o[i] = (bf16)(((float)a[i] + (float)c[i]) * inv);
  int b = bh >> 3, h = bh & 7;
  *(bf16x4*)(concat + ((size_t)(b * 2048 + s)) * 512 + h * 64 + dv4 * 4) = o;
}

// ---------------- LN with bf16-partial merge: (Pa+Pb+badd+resid) -> LN ----------------
__global__ __launch_bounds__(256) void ln_merge(const bf16* __restrict__ Pa,
    const bf16* __restrict__ Pb, const float* __restrict__ badd,
    const float* __restrict__ resid, const float* __restrict__ gamma,
    const float* __restrict__ beta, float* __restrict__ outf,
    bf16* __restrict__ outb, int relu)
{
  const int row = blockIdx.x * 4 + (threadIdx.x >> 6);
  const int lane = threadIdx.x & 63;
  const size_t base = (size_t)row * 512;
  const int e0 = lane * 8;
  bf16x8 pa = *(const bf16x8*)(Pa + base + e0);
  bf16x8 pb = *(const bf16x8*)(Pb + base + e0);
  float4 R0 = *(const float4*)(resid + base + e0);
  float4 R1 = *(const float4*)(resid + base + e0 + 4);
  float4 C0 = *(const float4*)(badd + e0);
  float4 C1 = *(const float4*)(badd + e0 + 4);
  float v[8];
  v[0] = (float)pa[0] + (float)pb[0] + R0.x + C0.x;
  v[1] = (float)pa[1] + (float)pb[1] + R0.y + C0.y;
  v[2] = (float)pa[2] + (float)pb[2] + R0.z + C0.z;
  v[3] = (float)pa[3] + (float)pb[3] + R0.w + C0.w;
  v[4] = (float)pa[4] + (float)pb[4] + R1.x + C1.x;
  v[5] = (float)pa[5] + (float)pb[5] + R1.y + C1.y;
  v[6] = (float)pa[6] + (float)pb[6] + R1.z + C1.z;
  v[7] = (float)pa[7] + (float)pb[7] + R1.w + C1.w;
  float s = 0.f;
  #pragma unroll
  for (int i = 0; i < 8; i++) s += v[i];
  #pragma unroll
  for (int m = 1; m < 64; m <<= 1) s += __shfl_xor(s, m, 64);
  float mu = s * (1.f / 512.f);
  float d[8], q = 0.f;
  #pragma unroll
  for (int i = 0; i < 8; i++) { d[i] = v[i] - mu; q += d[i] * d[i]; }
  #pragma unroll
  for (int m = 1; m < 64; m <<= 1) q += __shfl_xor(q, m, 64);
  float rs = rsqrtf(q * (1.f / 512.f) + 1e-5f);
  float4 g0 = *(const float4*)(gamma + e0);
  float4 g1 = *(const float4*)(gamma + e0 + 4);
  float4 b0 = *(const float4*)(beta + e0);
  float4 b1 = *(const float4*)(beta + e0 + 4);
  float y[8];
  y[0] = d[0] * rs * g0.x + b0.x; y[1] = d[1] * rs * g0.y + b0.y;
  y[2] = d[2] * rs * g0.z + b0.z; y[3] = d[3] * rs * g0.w + b0.w;
  y[4] = d[4] * rs * g1.x + b1.x; y[5] = d[5] * rs * g1.y + b1.y;
  y[6] = d[6] * rs * g1.z + b1.z; y[7] = d[7] * rs * g1.w + b1.w;
  if (relu) {
    #pragma unroll
    for (int i = 0; i < 8; i++) y[i] = fmaxf(y[i], 0.f);
  }
  float4 o0 = {y[0], y[1], y[2], y[3]}, o1 = {y[4], y[5], y[6], y[7]};
  *(float4*)(outf + base + e0) = o0;
  *(float4*)(outf + base + e0 + 4) = o1;
  if (outb) {
    bf16x8 ob;
    #pragma unroll
    for (int i = 0; i < 8; i++) ob[i] = (bf16)y[i];
    *(bf16x8*)(outb + base + e0) = ob;
  }
}

extern "C" void kernel_launch(void* const* d_in, const int* in_sizes, int n_in,
                              void* d_out, int out_size, void* d_ws, size_t ws_size,
                              hipStream_t stream)
{
  const int*   x    = (const int*)  d_in[0];
  const float* emb  = (const float*)d_in[1];
  const float* WfQ  = (const float*)d_in[2];
  const float* bfQv = (const float*)d_in[3];
  const float* WfK  = (const float*)d_in[4];
  const float* bfKv = (const float*)d_in[5];
  const float* WfV  = (const float*)d_in[6];
  const float* bfVv = (const float*)d_in[7];
  const float* WQ   = (const float*)d_in[8];
  const float* bQ   = (const float*)d_in[9];
  const float* WK   = (const float*)d_in[10];
  const float* bK   = (const float*)d_in[11];
  const float* WV   = (const float*)d_in[12];
  const float* bV   = (const float*)d_in[13];
  const float* Wo   = (const float*)d_in[14];
  const float* bo   = (const float*)d_in[15];
  const float* W1   = (const float*)d_in[16];
  const float* b1   = (const float*)d_in[17];
  const float* W2   = (const float*)d_in[18];
  const float* b2   = (const float*)d_in[19];
  const float* gamma= (const float*)d_in[20];
  const float* beta = (const float*)d_in[21];
  float* out = (float*)d_out;

  char* ws = (char*)d_ws;
  const size_t MB = 1024ull * 1024;
  float* zf   = (float*)(ws);              // 0-16: z fp32, then a fp32
  bf16*  bz   = (bf16*) (ws + 16 * MB);    // 16-24: z bf16, then a bf16
  f16*   qkh  = (f16*)  (ws + 24 * MB);    // 24-40 (dead after flash)
  f16*   Vt   = (f16*)  (ws + 40 * MB);    // 40-48 (dead after flash)
  bf16*  Op   = (bf16*) (ws + 48 * MB);    // 48-64: flash O partials x2
  float* Rp   = (float*)(ws + 80 * MB);    // 80-81
  bf16*  concat = (bf16*)(ws + 82 * MB);   // 82-90
  bf16*  PaW  = (bf16*) (ws + 48 * MB);    // Wo bf16 partials (reuse Op region)
  bf16*  PbW  = (bf16*) (ws + 56 * MB);
  bf16*  ffn1 = (bf16*) (ws + 24 * MB);    // 24-56 (after ln1)
  bf16*  Pa2  = (bf16*) (ws + 56 * MB);    // FFN2 bf16 partials 56-64, 64-72
  bf16*  Pb2  = (bf16*) (ws + 64 * MB);
  char* wp = ws + 90 * MB;
  bf16* wfqp = (bf16*)(wp);
  bf16* wfkp = (bf16*)(wp + 512 * 1024);
  bf16* wfvp = (bf16*)(wp + 1024 * 1024);
  bf16* wqt  = (bf16*)(wp + 1536 * 1024);
  bf16* wkt  = (bf16*)(wp + 2048 * 1024);
  bf16* wvt  = (bf16*)(wp + 2560 * 1024);
  bf16* wc   = (bf16*)(wp + 3072 * 1024);
  bf16* wot  = (bf16*)(wp + 4608 * 1024);
  bf16* w1t  = (bf16*)(wp + 5120 * 1024);
  bf16* w2t  = (bf16*)(wp + 7168 * 1024);
  float* bc  = (float*)(wp + 9216 * 1024);

  conv_all<<<dim3(4096, 9), 256, 0, stream>>>(WfQ, WfK, WfV, WQ, WK, WV, Wo, W1, W2,
                                              wfqp, wfkp, wfvp, wqt, wkt, wvt, wot, w1t, w2t);
  bias_comb<<<384, 256, 0, stream>>>(bfQv, bfKv, bfVv, WQ, WK, WV, bQ, bK, bV, bc);
  gemm_comb<<<dim3(4, 8, 3), 256, 0, stream>>>(wqt, wkt, wvt, wfqp, wfkp, wfvp, wc);

  embed_pe<<<8192, 256, 0, stream>>>(x, emb, zf, bz);

  gemm_qkv<<<dim3(64, 12), 256, 0, stream>>>(bz, wc, bc, qkh, Vt);
  flash_attn<<<dim3(16, 32, 2), 256, 0, stream>>>(qkh, Vt, Op, Rp);
  attn_merge<<<4096, 256, 0, stream>>>(Op, Rp, concat);

  gemm_part<<<dim3(64, 4, 2), 256, 0, stream>>>(concat, wot, PaW, PbW, 512, 512, 256);
  ln_merge<<<2048, 256, 0, stream>>>(PaW, PbW, bo, zf, gamma, beta, zf, bz, 0);
  gemm_bt<<<dim3(64, 16), 256, 0, stream>>>(bz, w1t, b1, ffn1, 8192, 2048, 512, 1);
  gemm_part<<<dim3(64, 4, 2), 256, 0, stream>>>(ffn1, w2t, Pa2, Pb2, 512, 2048, 1024);
  ln_merge<<<2048, 256, 0, stream>>>(Pa2, Pb2, b2, zf, gamma, beta, out, nullptr, 1);
}

// Round 9
// 348.155 us; speedup vs baseline: 1.6523x; 1.0298x over previous
//
#include <hip/hip_runtime.h>
#include <math.h>

typedef __bf16 bf16;
typedef __bf16 bf16x8 __attribute__((ext_vector_type(8)));
typedef __bf16 bf16x4 __attribute__((ext_vector_type(4)));
typedef _Float16 f16;
typedef _Float16 f16x8 __attribute__((ext_vector_type(8)));
typedef _Float16 f16x4 __attribute__((ext_vector_type(4)));
typedef _Float16 f16x2 __attribute__((ext_vector_type(2)));
typedef __fp16 h16x2 __attribute__((ext_vector_type(2)));
typedef float f32x4 __attribute__((ext_vector_type(4)));
typedef unsigned int u32;

#define S_LEN 2048
#define QSCALE 0.18033688011112042f   // (1/8)*log2(e), folded into Q weights+bias

__device__ __forceinline__ void gload_lds16(const void* g, void* l) {
  __builtin_amdgcn_global_load_lds((const __attribute__((address_space(1))) u32*)g,
                                   (__attribute__((address_space(3))) u32*)l, 16, 0, 0);
}

// ---------------- embedding + sinusoidal PE (bf16 out only) ----------------
__global__ __launch_bounds__(256) void embed_pe(const int* __restrict__ x,
    const float* __restrict__ emb, bf16* __restrict__ zb)
{
  const int row = blockIdx.x;
  const int s = row & (S_LEN - 1);
  const int tok = x[row];
  const float* e = emb + (size_t)tok * 512;
  bf16* zbr = zb + (size_t)row * 512;
  for (int i = threadIdx.x; i < 512; i += 256) {
    float invf = __expf((float)i * (-9.210340371976184f / 512.0f));
    float ang = (float)s * invf;
    float pe = (i & 1) ? __cosf(ang) : __sinf(ang);
    zbr[i] = (bf16)(e[i] + pe);
  }
}

// ---------------- all weight conversions in one launch ----------------
__global__ __launch_bounds__(256) void conv_all(
    const float* __restrict__ WfQ, const float* __restrict__ WfK, const float* __restrict__ WfV,
    const float* __restrict__ WQ, const float* __restrict__ WK, const float* __restrict__ WV,
    const float* __restrict__ Wo, const float* __restrict__ W1, const float* __restrict__ W2,
    bf16* __restrict__ wfqp, bf16* __restrict__ wfkp, bf16* __restrict__ wfvp,
    bf16* __restrict__ wqt, bf16* __restrict__ wkt, bf16* __restrict__ wvt,
    bf16* __restrict__ wot, bf16* __restrict__ w1t, bf16* __restrict__ w2t)
{
  int gid = blockIdx.x * 256 + threadIdx.x;
  int y = blockIdx.y;
  if (y < 3) {
    if (gid >= 262144) return;
    const float* in = y == 0 ? WfQ : (y == 1 ? WfK : WfV);
    bf16* out = y == 0 ? wfqp : (y == 1 ? wfkp : wfvp);
    out[gid] = (bf16)in[gid];
  } else if (y < 6) {
    if (gid >= 262144) return;
    const float* in = y == 3 ? WQ : (y == 4 ? WK : WV);
    bf16* out = y == 3 ? wqt : (y == 4 ? wkt : wvt);
    float scale = y == 3 ? QSCALE : 1.0f;
    int r = gid & 511, t = gid >> 9, c = t & 63, h = t >> 6;
    out[gid] = (bf16)(in[((size_t)(h * 512 + r)) * 64 + c] * scale);
  } else if (y == 6) {
    if (gid >= 262144) return;
    int r = gid & 511, c = gid >> 9;
    wot[gid] = (bf16)Wo[r * 512 + c];
  } else if (y == 7) {
    int r = gid & 511, c = gid >> 9;
    w1t[gid] = (bf16)W1[r * 2048 + c];
  } else {
    int r = gid & 2047, c = gid >> 11;
    w2t[gid] = (bf16)W2[r * 512 + c];
  }
}

// ---------------- combined bias ----------------
__global__ __launch_bounds__(256) void bias_comb(
    const float* __restrict__ bfQ, const float* __restrict__ bfK, const float* __restrict__ bfV,
    const float* __restrict__ WQ, const float* __restrict__ WK, const float* __restrict__ WV,
    const float* __restrict__ bQ, const float* __restrict__ bK, const float* __restrict__ bV,
    float* __restrict__ bc)
{
  int n = blockIdx.x * 4 + (threadIdx.x >> 6);
  int lane = threadIdx.x & 63;
  int z = n >> 9, hk = n & 511, h = hk >> 6, k = hk & 63;
  const float* bf = z == 0 ? bfQ : (z == 1 ? bfK : bfV);
  const float* W  = z == 0 ? WQ  : (z == 1 ? WK  : WV);
  const float* bH = z == 0 ? bQ  : (z == 1 ? bK  : bV);
  float s = 0.f;
  for (int e = lane; e < 512; e += 64)
    s += bf[e] * W[((size_t)h * 512 + e) * 64 + k];
  #pragma unroll
  for (int m = 1; m < 64; m <<= 1) s += __shfl_xor(s, m, 64);
  if (lane == 0) {
    float v = s + bH[h * 64 + k];
    if (z == 0) v *= QSCALE;
    bc[n] = v;
  }
}

// ---------------- weight-combine GEMMs (3 in one launch, 128x64 tiles) ----------------
__global__ __launch_bounds__(256) void gemm_comb(
    const bf16* __restrict__ wqt, const bf16* __restrict__ wkt, const bf16* __restrict__ wvt,
    const bf16* __restrict__ wfqp, const bf16* __restrict__ wfkp, const bf16* __restrict__ wfvp,
    bf16* __restrict__ wc)
{
  __shared__ bf16 As[128 * 32];
  __shared__ bf16 Bs[64 * 32];
  const int z = blockIdx.z;
  const bf16* A  = z == 0 ? wqt : (z == 1 ? wkt : wvt);
  const bf16* Bt = z == 0 ? wfqp : (z == 1 ? wfkp : wfvp);
  bf16* outb = wc + (size_t)z * 262144;
  const int tid = threadIdx.x;
  const int wave = tid >> 6, lane = tid & 63, quad = lane >> 4, l16 = lane & 15;
  const int row0 = blockIdx.x * 128, col0 = blockIdx.y * 64;
  const int wm = wave >> 1, wn = wave & 1;
  f32x4 acc[4][2] = {};

  for (int kk = 0; kk < 512; kk += 32) {
    __syncthreads();
    #pragma unroll
    for (int r = 0; r < 2; r++) {
      int c = r * 256 + tid;
      gload_lds16(A + (size_t)(row0 + (c >> 2)) * 512 + kk + (c & 3) * 8, As + c * 8);
    }
    gload_lds16(Bt + (size_t)(col0 + (tid >> 2)) * 512 + kk + (tid & 3) * 8, Bs + tid * 8);
    __syncthreads();
    bf16x8 af[4], bfr[2];
    #pragma unroll
    for (int i = 0; i < 4; i++)
      af[i] = *(const bf16x8*)(As + (wm * 64 + i * 16 + l16) * 32 + quad * 8);
    #pragma unroll
    for (int i = 0; i < 2; i++)
      bfr[i] = *(const bf16x8*)(Bs + (wn * 32 + i * 16 + l16) * 32 + quad * 8);
    #pragma unroll
    for (int mt = 0; mt < 4; mt++)
      #pragma unroll
      for (int nt = 0; nt < 2; nt++)
        acc[mt][nt] = __builtin_amdgcn_mfma_f32_16x16x32_bf16(af[mt], bfr[nt], acc[mt][nt], 0, 0, 0);
  }
  #pragma unroll
  for (int nt = 0; nt < 2; nt++) {
    int col = col0 + wn * 32 + nt * 16 + l16;
    #pragma unroll
    for (int mt = 0; mt < 4; mt++) {
      int rowb = row0 + wm * 64 + mt * 16 + quad * 4;
      #pragma unroll
      for (int i = 0; i < 4; i++)
        outb[(size_t)(rowb + i) * 512 + col] = (bf16)acc[mt][nt][i];
    }
  }
}

// ======== dbuf reg-prefetch GEMM core (128x128 tile, BK=32, 1 barrier/iter) ========
#define GEMM_CORE(A_, Bt_, K_, KK0_, ITERS_)                                            \
  bf16x8 ar0, ar1, br0, br1;                                                            \
  const int c0 = tid, c1 = 256 + tid;                                                   \
  const size_t aoff0 = (size_t)(row0 + (c0 >> 2)) * (K_) + (c0 & 3) * 8;                \
  const size_t aoff1 = (size_t)(row0 + (c1 >> 2)) * (K_) + (c1 & 3) * 8;                \
  const size_t boff0 = (size_t)(col0 + (c0 >> 2)) * (K_) + (c0 & 3) * 8;                \
  const size_t boff1 = (size_t)(col0 + (c1 >> 2)) * (K_) + (c1 & 3) * 8;                \
  ar0 = *(const bf16x8*)((A_) + aoff0 + (KK0_));                                        \
  ar1 = *(const bf16x8*)((A_) + aoff1 + (KK0_));                                        \
  br0 = *(const bf16x8*)((Bt_) + boff0 + (KK0_));                                       \
  br1 = *(const bf16x8*)((Bt_) + boff1 + (KK0_));                                       \
  for (int it = 0; it < (ITERS_); it++) {                                               \
    bf16* AsB = As[it & 1];                                                             \
    bf16* BsB = Bs[it & 1];                                                             \
    *(bf16x8*)(AsB + c0 * 8) = ar0;                                                     \
    *(bf16x8*)(AsB + c1 * 8) = ar1;                                                     \
    *(bf16x8*)(BsB + c0 * 8) = br0;                                                     \
    *(bf16x8*)(BsB + c1 * 8) = br1;                                                     \
    __syncthreads();                                                                    \
    if (it + 1 < (ITERS_)) {                                                            \
      int kk = (KK0_) + (it + 1) * 32;                                                  \
      ar0 = *(const bf16x8*)((A_) + aoff0 + kk);                                        \
      ar1 = *(const bf16x8*)((A_) + aoff1 + kk);                                        \
      br0 = *(const bf16x8*)((Bt_) + boff0 + kk);                                       \
      br1 = *(const bf16x8*)((Bt_) + boff1 + kk);                                       \
    }                                                                                   \
    bf16x8 af[4], bfr[4];                                                               \
    _Pragma("unroll")                                                                   \
    for (int i = 0; i < 4; i++)                                                         \
      af[i] = *(const bf16x8*)(AsB + (wm * 64 + i * 16 + l16) * 32 + quad * 8);         \
    _Pragma("unroll")                                                                   \
    for (int i = 0; i < 4; i++)                                                         \
      bfr[i] = *(const bf16x8*)(BsB + (wn * 64 + i * 16 + l16) * 32 + quad * 8);        \
    _Pragma("unroll")                                                                   \
    for (int mt = 0; mt < 4; mt++)                                                      \
      _Pragma("unroll")                                                                 \
      for (int nt = 0; nt < 4; nt++)                                                    \
        acc[mt][nt] = __builtin_amdgcn_mfma_f32_16x16x32_bf16(af[mt], bfr[nt], acc[mt][nt], 0, 0, 0); \
  }

// ---------------- GEMM 128x128 (bias, optional relu, bf16 out; FFN1) ----------------
__global__ __launch_bounds__(256) void gemm_bt(
    const bf16* __restrict__ A, const bf16* __restrict__ Bt,
    const float* __restrict__ bias, bf16* __restrict__ outb,
    int M, int N, int K, int relu)
{
  __shared__ bf16 As[2][4096];
  __shared__ bf16 Bs[2][4096];
  const int tid = threadIdx.x;
  const int wave = tid >> 6, lane = tid & 63, quad = lane >> 4, l16 = lane & 15;
  const int row0 = blockIdx.x * 128, col0 = blockIdx.y * 128;
  const int wm = wave >> 1, wn = wave & 1;
  f32x4 acc[4][4] = {};
  GEMM_CORE(A, Bt, K, 0, K / 32)

  #pragma unroll
  for (int nt = 0; nt < 4; nt++) {
    int col = col0 + wn * 64 + nt * 16 + l16;
    float bv = bias[col];
    #pragma unroll
    for (int mt = 0; mt < 4; mt++) {
      int rowb = row0 + wm * 64 + mt * 16 + quad * 4;
      #pragma unroll
      for (int i = 0; i < 4; i++) {
        float v = acc[mt][nt][i] + bv;
        if (relu) v = fmaxf(v, 0.f);
        outb[(size_t)(rowb + i) * N + col] = (bf16)v;
      }
    }
  }
}

// ---------------- QKV GEMM: N=1536, writes qk f16[row][1024] + Vt f16[bh][dv][2048] ----------------
__global__ __launch_bounds__(256) void gemm_qkv(
    const bf16* __restrict__ A, const bf16* __restrict__ Bt,
    const float* __restrict__ bias, f16* __restrict__ qk, f16* __restrict__ Vt)
{
  __shared__ bf16 As[2][4096];
  __shared__ bf16 Bs[2][4096];
  const int tid = threadIdx.x;
  const int wave = tid >> 6, lane = tid & 63, quad = lane >> 4, l16 = lane & 15;
  const int row0 = blockIdx.x * 128, col0 = blockIdx.y * 128;
  const int wm = wave >> 1, wn = wave & 1;
  f32x4 acc[4][4] = {};
  GEMM_CORE(A, Bt, 512, 0, 16)

  #pragma unroll
  for (int nt = 0; nt < 4; nt++) {
    int col = col0 + wn * 64 + nt * 16 + l16;
    float bv = bias[col];
    if (col < 1024) {
      #pragma unroll
      for (int mt = 0; mt < 4; mt++) {
        int rowb = row0 + wm * 64 + mt * 16 + quad * 4;
        #pragma unroll
        for (int i = 0; i < 4; i++)
          qk[(size_t)(rowb + i) * 1024 + col] = (f16)(acc[mt][nt][i] + bv);
      }
    } else {
      int h = (col - 1024) >> 6, dv = col & 63;
      #pragma unroll
      for (int mt = 0; mt < 4; mt++) {
        int rowb = row0 + wm * 64 + mt * 16 + quad * 4;
        int b = rowb >> 11, s = rowb & 2047;
        f16x4 vv;
        #pragma unroll
        for (int i = 0; i < 4; i++) vv[i] = (f16)(acc[mt][nt][i] + bv);
        *(f16x4*)(Vt + ((size_t)((b * 8 + h) * 64 + dv)) * 2048 + s) = vv;
      }
    }
  }
}

// ---------------- split-K partial GEMM -> bf16 partials ----------------
__global__ __launch_bounds__(256) void gemm_part(
    const bf16* __restrict__ A, const bf16* __restrict__ Bt,
    bf16* __restrict__ Pa, bf16* __restrict__ Pb, int N, int K, int Kh)
{
  __shared__ bf16 As[2][4096];
  __shared__ bf16 Bs[2][4096];
  const int tid = threadIdx.x;
  const int wave = tid >> 6, lane = tid & 63, quad = lane >> 4, l16 = lane & 15;
  const int row0 = blockIdx.x * 128, col0 = blockIdx.y * 128;
  const int wm = wave >> 1, wn = wave & 1;
  const int kk0 = blockIdx.z * Kh;
  bf16* P = blockIdx.z ? Pb : Pa;
  f32x4 acc[4][4] = {};
  GEMM_CORE(A, Bt, K, kk0, Kh / 32)

  #pragma unroll
  for (int nt = 0; nt < 4; nt++) {
    int col = col0 + wn * 64 + nt * 16 + l16;
    #pragma unroll
    for (int mt = 0; mt < 4; mt++) {
      int rowb = row0 + wm * 64 + mt * 16 + quad * 4;
      #pragma unroll
      for (int i = 0; i < 4; i++)
        P[(size_t)(rowb + i) * N + col] = (bf16)acc[mt][nt][i];
    }
  }
}

// ---------------- flash attention: 32 q/wave, split-K 4, dbuf, rsum via MFMA ----------------
// qk: [8192][1024] f16; Vt: [32 bh][64 dv][2048 s] f16. Grid (16 qtile, 32 bh, 4 quarter).
__global__ __launch_bounds__(256) void flash_attn(
    const f16* __restrict__ qk, const f16* __restrict__ Vt,
    bf16* __restrict__ Op, float* __restrict__ Rp)
{
  __shared__ f16 Ks[2][4096];   // [key][dk], 16B chunks XOR-swizzled by row&7
  __shared__ f16 Vs[2][4096];   // [dv][key], same swizzle
  const int bh = blockIdx.y, b = bh >> 3, h = bh & 7;
  const int q0 = blockIdx.x * 128;
  const int quarter = blockIdx.z;
  const int tid = threadIdx.x;
  const int wave = tid >> 6, lane = tid & 63, quad = lane >> 4, l16 = lane & 15;

  const f16* Qb = qk + ((size_t)b * S_LEN) * 1024 + h * 64;
  const f16* Kb = Qb + 512;
  const f16* Vtb = Vt + ((size_t)bh * 64) * 2048;
  const int key0 = quarter * 512;

  f16x8 qf[2][2];
  #pragma unroll
  for (int f = 0; f < 2; f++) {
    int qrow = q0 + wave * 32 + f * 16 + l16;
    #pragma unroll
    for (int kh = 0; kh < 2; kh++)
      qf[f][kh] = *(const f16x8*)(Qb + (size_t)qrow * 1024 + kh * 32 + quad * 8);
  }

  f32x4 O[2][4] = {};            // [f][mt]: O^T row=dv, col=q
  f32x4 Osum[2] = {};            // rsum accumulator via ones-MFMA
  const f16x4 onesA = {(f16)1.f, (f16)1.f, (f16)1.f, (f16)1.f};
  const int swz = l16 & 7;

  f16x8 kreg[2], vreg[2];
  const int srow = tid >> 3, soff = tid & 7;
  const int srow1 = srow + 32;

  {
    int kb = key0;
    kreg[0] = *(const f16x8*)(Kb + (size_t)(kb + srow) * 1024 + soff * 8);
    vreg[0] = *(const f16x8*)(Vtb + (size_t)srow * 2048 + kb + soff * 8);
    kreg[1] = *(const f16x8*)(Kb + (size_t)(kb + srow1) * 1024 + soff * 8);
    vreg[1] = *(const f16x8*)(Vtb + (size_t)srow1 * 2048 + kb + soff * 8);
  }

  for (int c = 0; c < 8; c++) {
    f16* KsB = Ks[c & 1];
    f16* VsB = Vs[c & 1];
    *(f16x8*)(KsB + srow * 64 + ((soff ^ (srow & 7)) * 8)) = kreg[0];
    *(f16x8*)(VsB + srow * 64 + ((soff ^ (srow & 7)) * 8)) = vreg[0];
    *(f16x8*)(KsB + srow1 * 64 + ((soff ^ (srow1 & 7)) * 8)) = kreg[1];
    *(f16x8*)(VsB + srow1 * 64 + ((soff ^ (srow1 & 7)) * 8)) = vreg[1];
    __syncthreads();
    if (c < 7) {
      int kb = key0 + (c + 1) * 64;
      kreg[0] = *(const f16x8*)(Kb + (size_t)(kb + srow) * 1024 + soff * 8);
      vreg[0] = *(const f16x8*)(Vtb + (size_t)srow * 2048 + kb + soff * 8);
      kreg[1] = *(const f16x8*)(Kb + (size_t)(kb + srow1) * 1024 + soff * 8);
      vreg[1] = *(const f16x8*)(Vtb + (size_t)srow1 * 2048 + kb + soff * 8);
    }

    #pragma unroll
    for (int nt = 0; nt < 4; nt++) {
      const f16* kp = KsB + (nt * 16 + l16) * 64;
      f16x8 kf0 = *(const f16x8*)(kp + ((quad ^ swz) * 8));
      f16x8 kf1 = *(const f16x8*)(kp + (((4 + quad) ^ swz) * 8));
      f16x4 pf[2];
      #pragma unroll
      for (int f = 0; f < 2; f++) {
        f32x4 a = {};
        a = __builtin_amdgcn_mfma_f32_16x16x32_f16(kf0, qf[f][0], a, 0, 0, 0);
        a = __builtin_amdgcn_mfma_f32_16x16x32_f16(kf1, qf[f][1], a, 0, 0, 0);
        float e0 = exp2f(a[0]);
        float e1 = exp2f(a[1]);
        float e2 = exp2f(a[2]);
        float e3 = exp2f(a[3]);
        h16x2 lo = __builtin_amdgcn_cvt_pkrtz(e0, e1);
        h16x2 hi = __builtin_amdgcn_cvt_pkrtz(e2, e3);
        f16x2 lo2 = __builtin_bit_cast(f16x2, lo);
        f16x2 hi2 = __builtin_bit_cast(f16x2, hi);
        pf[f] = __builtin_shufflevector(lo2, hi2, 0, 1, 2, 3);
        Osum[f] = __builtin_amdgcn_mfma_f32_16x16x16f16(onesA, pf[f], Osum[f], 0, 0, 0);
      }
      int vchunk = nt * 2 + (quad >> 1);
      #pragma unroll
      for (int mt = 0; mt < 4; mt++) {
        const f16* vp = VsB + (mt * 16 + l16) * 64 + ((vchunk ^ swz) * 8) + (quad & 1) * 4;
        f16x4 vf = *(const f16x4*)vp;
        #pragma unroll
        for (int f = 0; f < 2; f++)
          O[f][mt] = __builtin_amdgcn_mfma_f32_16x16x16f16(vf, pf[f], O[f][mt], 0, 0, 0);
      }
    }
    __syncthreads();
  }

  // store un-normalized partials (transpose through padded per-wave LDS regions)
  #pragma unroll
  for (int f = 0; f < 2; f++) {
    bf16* ob = (f == 0 ? (bf16*)&Ks[0][0] : (bf16*)&Vs[0][0]) + wave * 1152;  // 16 x 72
    #pragma unroll
    for (int mt = 0; mt < 4; mt++)
      #pragma unroll
      for (int i = 0; i < 4; i++)
        ob[l16 * 72 + mt * 16 + quad * 4 + i] = (bf16)O[f][mt][i];
  }
  asm volatile("s_waitcnt lgkmcnt(0)" ::: "memory");
  const size_t obase = (size_t)(quarter * 32 + bh) * 2048;
  #pragma unroll
  for (int f = 0; f < 2; f++) {
    bf16* ob = (f == 0 ? (bf16*)&Ks[0][0] : (bf16*)&Vs[0][0]) + wave * 1152;
    int row = lane >> 2, dvb = (lane & 3) * 16;
    bf16x8 o0 = *(const bf16x8*)(ob + row * 72 + dvb);
    bf16x8 o1 = *(const bf16x8*)(ob + row * 72 + dvb + 8);
    size_t g = (obase + q0 + wave * 32 + f * 16 + row) * 64 + dvb;
    *(bf16x8*)(Op + g) = o0;
    *(bf16x8*)(Op + g + 8) = o1;
    if (quad == f)
      Rp[obase + q0 + wave * 32 + f * 16 + l16] = Osum[f][0];
  }
}

// ---------------- attention partial merge (4-way) -> concat bf16 ----------------
__global__ __launch_bounds__(256) void attn_merge(const bf16* __restrict__ Op,
    const float* __restrict__ Rp, bf16* __restrict__ concat)
{
  int t = blockIdx.x * 256 + threadIdx.x;   // 32bh * 2048s * 16(dv4)
  int dv4 = t & 15, s = (t >> 4) & 2047, bh = t >> 15;
  int rb = bh * 2048 + s;
  float r = (Rp[rb] + Rp[65536 + rb]) + (Rp[131072 + rb] + Rp[196608 + rb]);
  float inv = 1.f / r;
  size_t ia = ((size_t)bh * 2048 + s) * 64 + dv4 * 4;
  bf16x4 p0 = *(const bf16x4*)(Op + ia);
  bf16x4 p1 = *(const bf16x4*)(Op + 4194304ull + ia);
  bf16x4 p2 = *(const bf16x4*)(Op + 8388608ull + ia);
  bf16x4 p3 = *(const bf16x4*)(Op + 12582912ull + ia);
  bf16x4 o;
  #pragma unroll
  for (int i = 0; i < 4; i++)
    o[i] = (bf16)((((float)p0[i] + (float)p1[i]) + ((float)p2[i] + (float)p3[i])) * inv);
  int b = bh >> 3, h = bh & 7;
  *(bf16x4*)(concat + ((size_t)(b * 2048 + s)) * 512 + h * 64 + dv4 * 4) = o;
}

// ---------------- LN merge: (Pa+Pb+badd+resid[bf16]) -> LN -> outf? outb? relu? ----------------
__global__ __launch_bounds__(256) void ln_merge(const bf16* __restrict__ Pa,
    const bf16* __restrict__ Pb, const float* __restrict__ badd,
    const bf16* __restrict__ resid, const float* __restrict__ gamma,
    const float* __restrict__ beta, float* __restrict__ outf,
    bf16* __restrict__ outb, int relu)
{
  const int row = blockIdx.x * 4 + (threadIdx.x >> 6);
  const int lane = threadIdx.x & 63;
  const size_t base = (size_t)row * 512;
  const int e0 = lane * 8;
  bf16x8 pa = *(const bf16x8*)(Pa + base + e0);
  bf16x8 pb = *(const bf16x8*)(Pb + base + e0);
  bf16x8 rr = *(const bf16x8*)(resid + base + e0);
  float4 C0 = *(const float4*)(badd + e0);
  float4 C1 = *(const float4*)(badd + e0 + 4);
  float v[8];
  v[0] = (float)pa[0] + (float)pb[0] + (float)rr[0] + C0.x;
  v[1] = (float)pa[1] + (float)pb[1] + (float)rr[1] + C0.y;
  v[2] = (float)pa[2] + (float)pb[2] + (float)rr[2] + C0.z;
  v[3] = (float)pa[3] + (float)pb[3] + (float)rr[3] + C0.w;
  v[4] = (float)pa[4] + (float)pb[4] + (float)rr[4] + C1.x;
  v[5] = (float)pa[5] + (float)pb[5] + (float)rr[5] + C1.y;
  v[6] = (float)pa[6] + (float)pb[6] + (float)rr[6] + C1.z;
  v[7] = (float)pa[7] + (float)pb[7] + (float)rr[7] + C1.w;
  float s = 0.f;
  #pragma unroll
  for (int i = 0; i < 8; i++) s += v[i];
  #pragma unroll
  for (int m = 1; m < 64; m <<= 1) s += __shfl_xor(s, m, 64);
  float mu = s * (1.f / 512.f);
  float d[8], q = 0.f;
  #pragma unroll
  for (int i = 0; i < 8; i++) { d[i] = v[i] - mu; q += d[i] * d[i]; }
  #pragma unroll
  for (int m = 1; m < 64; m <<= 1) q += __shfl_xor(q, m, 64);
  float rs = rsqrtf(q * (1.f / 512.f) + 1e-5f);
  float4 g0 = *(const float4*)(gamma + e0);
  float4 g1 = *(const float4*)(gamma + e0 + 4);
  float4 b0 = *(const float4*)(beta + e0);
  float4 b1 = *(const float4*)(beta + e0 + 4);
  float y[8];
  y[0] = d[0] * rs * g0.x + b0.x; y[1] = d[1] * rs * g0.y + b0.y;
  y[2] = d[2] * rs * g0.z + b0.z; y[3] = d[3] * rs * g0.w + b0.w;
  y[4] = d[4] * rs * g1.x + b1.x; y[5] = d[5] * rs * g1.y + b1.y;
  y[6] = d[6] * rs * g1.z + b1.z; y[7] = d[7] * rs * g1.w + b1.w;
  if (relu) {
    #pragma unroll
    for (int i = 0; i < 8; i++) y[i] = fmaxf(y[i], 0.f);
  }
  if (outf) {
    float4 o0 = {y[0], y[1], y[2], y[3]}, o1 = {y[4], y[5], y[6], y[7]};
    *(float4*)(outf + base + e0) = o0;
    *(float4*)(outf + base + e0 + 4) = o1;
  }
  if (outb) {
    bf16x8 ob;
    #pragma unroll
    for (int i = 0; i < 8; i++) ob[i] = (bf16)y[i];
    *(bf16x8*)(outb + base + e0) = ob;
  }
}

extern "C" void kernel_launch(void* const* d_in, const int* in_sizes, int n_in,
                              void* d_out, int out_size, void* d_ws, size_t ws_size,
                              hipStream_t stream)
{
  const int*   x    = (const int*)  d_in[0];
  const float* emb  = (const float*)d_in[1];
  const float* WfQ  = (const float*)d_in[2];
  const float* bfQv = (const float*)d_in[3];
  const float* WfK  = (const float*)d_in[4];
  const float* bfKv = (const float*)d_in[5];
  const float* WfV  = (const float*)d_in[6];
  const float* bfVv = (const float*)d_in[7];
  const float* WQ   = (const float*)d_in[8];
  const float* bQ   = (const float*)d_in[9];
  const float* WK   = (const float*)d_in[10];
  const float* bK   = (const float*)d_in[11];
  const float* WV   = (const float*)d_in[12];
  const float* bV   = (const float*)d_in[13];
  const float* Wo   = (const float*)d_in[14];
  const float* bo   = (const float*)d_in[15];
  const float* W1   = (const float*)d_in[16];
  const float* b1   = (const float*)d_in[17];
  const float* W2   = (const float*)d_in[18];
  const float* b2   = (const float*)d_in[19];
  const float* gamma= (const float*)d_in[20];
  const float* beta = (const float*)d_in[21];
  float* out = (float*)d_out;

  char* ws = (char*)d_ws;
  const size_t MB = 1024ull * 1024;
  bf16*  bz   = (bf16*) (ws);              // 0-8: z bf16, then a bf16
  f16*   qkh  = (f16*)  (ws + 8 * MB);     // 8-24 (dead after flash)
  f16*   Vt   = (f16*)  (ws + 24 * MB);    // 24-32 (dead after flash)
  bf16*  Op   = (bf16*) (ws + 32 * MB);    // 32-64: flash O partials x4
  float* Rp   = (float*)(ws + 64 * MB);    // 64-65: row sums x4 (1MB)
  bf16*  concat = (bf16*)(ws + 66 * MB);   // 66-74
  bf16*  PaW  = (bf16*) (ws + 32 * MB);    // Wo bf16 partials (reuse Op)
  bf16*  PbW  = (bf16*) (ws + 40 * MB);
  bf16*  ffn1 = (bf16*) (ws + 8 * MB);     // 8-40 (qkh/Vt dead after flash)
  bf16*  Pa2  = (bf16*) (ws + 40 * MB);    // FFN2 partials 40-48, 48-56
  bf16*  Pb2  = (bf16*) (ws + 48 * MB);
  char* wp = ws + 74 * MB;
  bf16* wfqp = (bf16*)(wp);
  bf16* wfkp = (bf16*)(wp + 512 * 1024);
  bf16* wfvp = (bf16*)(wp + 1024 * 1024);
  bf16* wqt  = (bf16*)(wp + 1536 * 1024);
  bf16* wkt  = (bf16*)(wp + 2048 * 1024);
  bf16* wvt  = (bf16*)(wp + 2560 * 1024);
  bf16* wc   = (bf16*)(wp + 3072 * 1024);
  bf16* wot  = (bf16*)(wp + 4608 * 1024);
  bf16* w1t  = (bf16*)(wp + 5120 * 1024);
  bf16* w2t  = (bf16*)(wp + 7168 * 1024);
  float* bc  = (float*)(wp + 9216 * 1024);

  conv_all<<<dim3(4096, 9), 256, 0, stream>>>(WfQ, WfK, WfV, WQ, WK, WV, Wo, W1, W2,
                                              wfqp, wfkp, wfvp, wqt, wkt, wvt, wot, w1t, w2t);
  bias_comb<<<384, 256, 0, stream>>>(bfQv, bfKv, bfVv, WQ, WK, WV, bQ, bK, bV, bc);
  gemm_comb<<<dim3(4, 8, 3), 256, 0, stream>>>(wqt, wkt, wvt, wfqp, wfkp, wfvp, wc);

  embed_pe<<<8192, 256, 0, stream>>>(x, emb, bz);

  gemm_qkv<<<dim3(64, 12), 256, 0, stream>>>(bz, wc, bc, qkh, Vt);
  flash_attn<<<dim3(16, 32, 4), 256, 0, stream>>>(qkh, Vt, Op, Rp);
  attn_merge<<<4096, 256, 0, stream>>>(Op, Rp, concat);

  // Wo partials must not clobber Op before attn_merge finishes (stream-ordered: OK after)
  gemm_part<<<dim3(64, 4, 2), 256, 0, stream>>>(concat, wot, PaW, PbW, 512, 512, 256);
  ln_merge<<<2048, 256, 0, stream>>>(PaW, PbW, bo, bz, gamma, beta, nullptr, bz, 0);
  gemm_bt<<<dim3(64, 16), 256, 0, stream>>>(bz, w1t, b1, ffn1, 8192, 2048, 512, 1);
  gemm_part<<<dim3(64, 4, 2), 256, 0, stream>>>(ffn1, w2t, Pa2, Pb2, 512, 2048, 1024);
  ln_merge<<<2048, 256, 0, stream>>>(Pa2, Pb2, b2, bz, gamma, beta, out, nullptr, 1);
}